// Round 2
// baseline (785.491 us; speedup 1.0000x reference)
//
#include <hip/hip_runtime.h>

#define NN   40000
#define EE   640000
#define EE2  680000    // EE + NN self loops
#define IND  5
#define ED   11
#define HIDD 128
#define F1   512       // 4 heads * 128

typedef unsigned short u16;
typedef unsigned int   u32;

__device__ __forceinline__ float bf2f(u16 u) { return __uint_as_float(((u32)u) << 16); }
__device__ __forceinline__ u16 f2bf(float f) {
    u32 u = __float_as_uint(f);
    return (u16)((u + 0x7FFFu + ((u >> 16) & 1u)) >> 16);   // RNE
}

__device__ __forceinline__ float wsum(float v) {
#pragma unroll
    for (int o = 32; o; o >>= 1) v += __shfl_xor(v, o, 64);
    return v;
}
__device__ __forceinline__ float wmaxr(float v) {
#pragma unroll
    for (int o = 32; o; o >>= 1) v = fmaxf(v, __shfl_xor(v, o, 64));
    return v;
}

// ---------------- init: zero consts + per-dst counters ----------------
__global__ void k_init(float* __restrict__ consts, int* __restrict__ cursor) {
    int i = blockIdx.x * blockDim.x + threadIdx.x;
    if (i < 256) consts[i] = 0.f;
    if (i < NN) cursor[i] = 0;
}

// ---------------- consts: ea column means ----------------
// consts layout (floats): [0..10] ea_mean, [16..59] Be1[k*4+h], [64..74] Be2[k],
//                         [80..83] self1[h], [96] self2
__global__ void k_mean(const float* __restrict__ ea, float* __restrict__ consts) {
    float s[ED];
#pragma unroll
    for (int k = 0; k < ED; ++k) s[k] = 0.f;
    int stride = gridDim.x * blockDim.x;
    for (int r = blockIdx.x * blockDim.x + threadIdx.x; r < EE; r += stride) {
        const float* p = ea + (size_t)r * ED;
#pragma unroll
        for (int k = 0; k < ED; ++k) s[k] += p[k];
    }
    __shared__ float ls[256];
    for (int k = 0; k < ED; ++k) {
        ls[threadIdx.x] = s[k];
        __syncthreads();
        for (int o = 128; o; o >>= 1) {
            if (threadIdx.x < o) ls[threadIdx.x] += ls[threadIdx.x + o];
            __syncthreads();
        }
        if (threadIdx.x == 0) atomicAdd(&consts[k], ls[0]);
        __syncthreads();
    }
}

__global__ void k_consts(float* __restrict__ consts,
                         const float* __restrict__ We1, const float* __restrict__ ae1,
                         const float* __restrict__ We2, const float* __restrict__ ae2) {
    int t = threadIdx.x;  // 64 threads
    if (t < ED) consts[t] *= (1.0f / (float)EE);
    if (t < 44) {
        int k = t >> 2, h = t & 3;
        float s = 0.f;
        for (int c = 0; c < HIDD; ++c)
            s += We1[k * F1 + h * HIDD + c] * ae1[h * HIDD + c];
        consts[16 + t] = s;
    }
    if (t >= 48 && t < 48 + ED) {
        int k = t - 48;
        float s = 0.f;
        for (int c = 0; c < HIDD; ++c)
            s += We2[k * HIDD + c] * ae2[c];
        consts[64 + k] = s;
    }
    __syncthreads();
    if (t < 4) {
        float s = 0.f;
        for (int k = 0; k < ED; ++k) s += consts[k] * consts[16 + k * 4 + t];
        consts[80 + t] = s;
    }
    if (t == 8) {
        float s = 0.f;
        for (int k = 0; k < ED; ++k) s += consts[k] * consts[64 + k];
        consts[96] = s;
    }
}

// ---------------- CSR build (sorted by dst), shared by both layers ----------------
__global__ void k_count(const int* __restrict__ ei, int* __restrict__ counts) {
    int i = blockIdx.x * blockDim.x + threadIdx.x;
    if (i >= EE2) return;
    int dst = (i < EE) ? ei[EE + i] : (i - EE);
    atomicAdd(&counts[dst], 1);
}

#define SCAN_T 256
#define SCAN_C 157    // 256*157 = 40192 >= NN
__global__ void __launch_bounds__(SCAN_T) k_scan(const int* __restrict__ counts,
                                                 int* __restrict__ row_off,
                                                 int* __restrict__ cur) {
    __shared__ int sh[SCAN_T];
    int t = threadIdx.x;
    int base = t * SCAN_C;
    int s = 0;
    for (int j = 0; j < SCAN_C; ++j) {
        int idx = base + j;
        if (idx < NN) s += counts[idx];
    }
    sh[t] = s;
    __syncthreads();
    for (int o = 1; o < SCAN_T; o <<= 1) {
        int v = (t >= o) ? sh[t - o] : 0;
        __syncthreads();
        sh[t] += v;
        __syncthreads();
    }
    int run = sh[t] - s;  // exclusive prefix
    for (int j = 0; j < SCAN_C; ++j) {
        int idx = base + j;
        if (idx < NN) {
            int c = counts[idx];     // read before overwrite (counts==cur buffer)
            row_off[idx] = run;
            cur[idx] = run;
            run += c;
        }
    }
    if (t == 0) row_off[NN] = EE2;
}

__global__ void k_scatter(const int* __restrict__ ei, int* __restrict__ cur,
                          int* __restrict__ perm, int* __restrict__ ssrc) {
    int i = blockIdx.x * blockDim.x + threadIdx.x;
    if (i >= EE2) return;
    int s, d;
    if (i < EE) { s = ei[i]; d = ei[EE + i]; }
    else        { s = d = i - EE; }
    int pos = atomicAdd(&cur[d], 1);
    perm[pos] = i;
    ssrc[pos] = s;
}

// ---------------- layer 1: xh1 = x@W1 (store bf16), a_src/a_dst dots ----------------
__global__ void __launch_bounds__(512) k_xh1(const float* __restrict__ x,
                                             const float* __restrict__ W1,
                                             const float* __restrict__ as1,
                                             const float* __restrict__ ad1,
                                             u16* __restrict__ xh1,
                                             float* __restrict__ aS1,
                                             float* __restrict__ aD1) {
    int n = blockIdx.x;
    int t = threadIdx.x;
    int h = t >> 7, c = t & 127;
    __shared__ float xs[IND];
    if (t < IND) xs[t] = x[n * IND + t];
    __syncthreads();
    float v = 0.f;
#pragma unroll
    for (int k = 0; k < IND; ++k) v += xs[k] * W1[k * F1 + h * HIDD + c];
    xh1[(size_t)n * F1 + h * HIDD + c] = f2bf(v);
    float p = v * as1[h * HIDD + c];
    float q = v * ad1[h * HIDD + c];
    p = wsum(p); q = wsum(q);
    __shared__ float rp[8], rq[8];
    int w = t >> 6;
    if ((t & 63) == 0) { rp[w] = p; rq[w] = q; }
    __syncthreads();
    if (c == 0) {
        aS1[n * 4 + h] = rp[2 * h] + rp[2 * h + 1];
        aD1[n * 4 + h] = rq[2 * h] + rq[2 * h + 1];
    }
}

// ---------------- layer 1: per-edge scores (sorted order) ----------------
__global__ void k_score1(const int* __restrict__ perm, const int* __restrict__ ei,
                         const float* __restrict__ ea, const float* __restrict__ consts,
                         const float* __restrict__ aS1, const float* __restrict__ aD1,
                         float* __restrict__ alpha1) {
    int i = blockIdx.x * blockDim.x + threadIdx.x;
    if (i >= EE2) return;
    int e = perm[i];
    int s, d;
    float e0, e1, e2, e3;
    if (e < EE) {
        s = ei[e]; d = ei[EE + e];
        e0 = e1 = e2 = e3 = 0.f;
        const float* p = ea + (size_t)e * ED;
#pragma unroll
        for (int k = 0; k < ED; ++k) {
            float a = p[k];
            e0 += a * consts[16 + k * 4 + 0];
            e1 += a * consts[16 + k * 4 + 1];
            e2 += a * consts[16 + k * 4 + 2];
            e3 += a * consts[16 + k * 4 + 3];
        }
    } else {
        s = d = e - EE;
        e0 = consts[80]; e1 = consts[81]; e2 = consts[82]; e3 = consts[83];
    }
    float4 vs = *(const float4*)(aS1 + (size_t)s * 4);
    float4 vd = *(const float4*)(aD1 + (size_t)d * 4);
    float t0 = vs.x + vd.x + e0, t1 = vs.y + vd.y + e1;
    float t2 = vs.z + vd.z + e2, t3 = vs.w + vd.w + e3;
    t0 = t0 > 0.f ? t0 : 0.2f * t0;
    t1 = t1 > 0.f ? t1 : 0.2f * t1;
    t2 = t2 > 0.f ? t2 : 0.2f * t2;
    t3 = t3 > 0.f ? t3 : 0.2f * t3;
    *(float4*)(alpha1 + (size_t)i * 4) = make_float4(t0, t1, t2, t3);
}

// ---------------- layer 1: softmax + gather-aggregate, 1 wave per dst ----------------
__global__ void __launch_bounds__(64) k_agg1(const int* __restrict__ row_off,
                                             const int* __restrict__ ssrc,
                                             const float* __restrict__ alpha1,
                                             const u16* __restrict__ xh1,
                                             const float* __restrict__ b1,
                                             u16* __restrict__ h1) {
    int n = blockIdx.x, t = threadIdx.x;
    int s0 = row_off[n], s1 = row_off[n + 1];
    float m0 = -1e30f, m1 = -1e30f, m2 = -1e30f, m3 = -1e30f;
    for (int i = s0 + t; i < s1; i += 64) {
        float4 a = *(const float4*)(alpha1 + (size_t)i * 4);
        m0 = fmaxf(m0, a.x); m1 = fmaxf(m1, a.y);
        m2 = fmaxf(m2, a.z); m3 = fmaxf(m3, a.w);
    }
    m0 = wmaxr(m0); m1 = wmaxr(m1); m2 = wmaxr(m2); m3 = wmaxr(m3);
    float z0 = 0.f, z1 = 0.f, z2 = 0.f, z3 = 0.f;
    for (int i = s0 + t; i < s1; i += 64) {
        float4 a = *(const float4*)(alpha1 + (size_t)i * 4);
        z0 += __expf(a.x - m0); z1 += __expf(a.y - m1);
        z2 += __expf(a.z - m2); z3 += __expf(a.w - m3);
    }
    z0 = wsum(z0); z1 = wsum(z1); z2 = wsum(z2); z3 = wsum(z3);
    float i0 = 1.f / (z0 + 1e-16f), i1 = 1.f / (z1 + 1e-16f);
    float i2 = 1.f / (z2 + 1e-16f), i3 = 1.f / (z3 + 1e-16f);
    int c0 = t * 8, h = t >> 4;
    float mh = (h == 0) ? m0 : (h == 1) ? m1 : (h == 2) ? m2 : m3;
    float ih = (h == 0) ? i0 : (h == 1) ? i1 : (h == 2) ? i2 : i3;
    float acc[8];
#pragma unroll
    for (int j = 0; j < 8; ++j) acc[j] = 0.f;
    for (int i = s0; i < s1; ++i) {
        float w = __expf(alpha1[(size_t)i * 4 + h] - mh) * ih;
        uint4 q = *(const uint4*)(xh1 + (size_t)ssrc[i] * F1 + c0);  // 8 bf16
        acc[0] += w * bf2f((u16)(q.x & 0xFFFF)); acc[1] += w * bf2f((u16)(q.x >> 16));
        acc[2] += w * bf2f((u16)(q.y & 0xFFFF)); acc[3] += w * bf2f((u16)(q.y >> 16));
        acc[4] += w * bf2f((u16)(q.z & 0xFFFF)); acc[5] += w * bf2f((u16)(q.z >> 16));
        acc[6] += w * bf2f((u16)(q.w & 0xFFFF)); acc[7] += w * bf2f((u16)(q.w >> 16));
    }
#pragma unroll
    for (int j = 0; j < 8; ++j) {
        float o = fmaxf(acc[j] + b1[c0 + j], 0.f);
        h1[(size_t)n * F1 + c0 + j] = f2bf(o);
    }
}

// ---------------- layer 2 GEMM: xh2[N,128] = h1[N,512](bf16) @ W2[512,128](f32) ----------------
#define BN7 128
#define KT7 32
__global__ void __launch_bounds__(256) k_gemm(const u16* __restrict__ h1,
                                              const float* __restrict__ W2,
                                              float* __restrict__ xh2) {
    __shared__ float Ah[BN7][KT7 + 1];
    __shared__ float Bw[KT7][HIDD];
    int tid = threadIdx.x;
    int cg = tid & 15;   // cols cg + 16*c
    int ng = tid >> 4;   // nodes ng*8 + r
    int n0 = blockIdx.x * BN7;
    float acc[8][8];
#pragma unroll
    for (int r = 0; r < 8; ++r)
#pragma unroll
        for (int c = 0; c < 8; ++c) acc[r][c] = 0.f;

    for (int k0 = 0; k0 < F1; k0 += KT7) {
#pragma unroll
        for (int j = 0; j < 4; ++j) {
            int f = j * 256 + tid;           // 1024 groups of 4 elems
            int node = f >> 3;
            int kk = (f & 7) * 4;
            int n = n0 + node;
            ushort4 r4 = make_ushort4(0, 0, 0, 0);
            if (n < NN) r4 = *(const ushort4*)(h1 + (size_t)n * F1 + k0 + kk);
            Ah[node][kk + 0] = bf2f(r4.x); Ah[node][kk + 1] = bf2f(r4.y);
            Ah[node][kk + 2] = bf2f(r4.z); Ah[node][kk + 3] = bf2f(r4.w);
        }
#pragma unroll
        for (int j = 0; j < 16; ++j) {
            int e = j * 256 + tid;           // 4096 floats
            int row = e >> 7, col = e & 127;
            Bw[row][col] = W2[(size_t)(k0 + row) * HIDD + col];
        }
        __syncthreads();
#pragma unroll
        for (int kk = 0; kk < KT7; ++kk) {
            float wv[8], hv[8];
#pragma unroll
            for (int c = 0; c < 8; ++c) wv[c] = Bw[kk][cg + 16 * c];
#pragma unroll
            for (int r = 0; r < 8; ++r) hv[r] = Ah[ng * 8 + r][kk];
#pragma unroll
            for (int r = 0; r < 8; ++r)
#pragma unroll
                for (int c = 0; c < 8; ++c) acc[r][c] = fmaf(hv[r], wv[c], acc[r][c]);
        }
        __syncthreads();
    }
#pragma unroll
    for (int r = 0; r < 8; ++r) {
        int n = n0 + ng * 8 + r;
        if (n < NN) {
#pragma unroll
            for (int c = 0; c < 8; ++c) xh2[(size_t)n * HIDD + cg + 16 * c] = acc[r][c];
        }
    }
}

// ---------------- layer 2: a_src/a_dst dots ----------------
__global__ void __launch_bounds__(64) k_sd2(const float* __restrict__ xh2,
                                            const float* __restrict__ as2,
                                            const float* __restrict__ ad2,
                                            float* __restrict__ aS2, float* __restrict__ aD2) {
    int n = blockIdx.x, t = threadIdx.x;
    float2 v = *(const float2*)(xh2 + (size_t)n * HIDD + t * 2);
    float p = v.x * as2[t * 2] + v.y * as2[t * 2 + 1];
    float q = v.x * ad2[t * 2] + v.y * ad2[t * 2 + 1];
    p = wsum(p); q = wsum(q);
    if (t == 0) { aS2[n] = p; aD2[n] = q; }
}

// ---------------- layer 2: per-edge scores ----------------
__global__ void k_score2(const int* __restrict__ perm, const int* __restrict__ ei,
                         const float* __restrict__ ea, const float* __restrict__ consts,
                         const float* __restrict__ aS2, const float* __restrict__ aD2,
                         float* __restrict__ alpha2) {
    int i = blockIdx.x * blockDim.x + threadIdx.x;
    if (i >= EE2) return;
    int e = perm[i];
    int s, d;
    float et;
    if (e < EE) {
        s = ei[e]; d = ei[EE + e];
        et = 0.f;
        const float* p = ea + (size_t)e * ED;
#pragma unroll
        for (int k = 0; k < ED; ++k) et += p[k] * consts[64 + k];
    } else {
        s = d = e - EE;
        et = consts[96];
    }
    float t0 = aS2[s] + aD2[d] + et;
    alpha2[i] = t0 > 0.f ? t0 : 0.2f * t0;
}

// ---------------- layer 2: softmax + aggregate ----------------
__global__ void __launch_bounds__(64) k_agg2(const int* __restrict__ row_off,
                                             const int* __restrict__ ssrc,
                                             const float* __restrict__ alpha2,
                                             const float* __restrict__ xh2,
                                             const float* __restrict__ bias2,
                                             float* __restrict__ h2) {
    int n = blockIdx.x, t = threadIdx.x;
    int s0 = row_off[n], s1 = row_off[n + 1];
    float m = -1e30f;
    for (int i = s0 + t; i < s1; i += 64) m = fmaxf(m, alpha2[i]);
    m = wmaxr(m);
    float z = 0.f;
    for (int i = s0 + t; i < s1; i += 64) z += __expf(alpha2[i] - m);
    z = wsum(z);
    float inv = 1.f / (z + 1e-16f);
    int c0 = t * 2;
    float a0 = 0.f, a1 = 0.f;
    for (int i = s0; i < s1; ++i) {
        float w = __expf(alpha2[i] - m) * inv;
        float2 u = *(const float2*)(xh2 + (size_t)ssrc[i] * HIDD + c0);
        a0 += w * u.x; a1 += w * u.y;
    }
    float2 o;
    o.x = fmaxf(a0 + bias2[c0], 0.f);
    o.y = fmaxf(a1 + bias2[c0 + 1], 0.f);
    *(float2*)(h2 + (size_t)n * HIDD + c0) = o;
}

// ---------------- final FC + sigmoid ----------------
__global__ void __launch_bounds__(64) k_final(const float* __restrict__ h2,
                                              const float* __restrict__ Wfc,
                                              const float* __restrict__ bfc,
                                              float* __restrict__ out) {
    int n = blockIdx.x, t = threadIdx.x;
    float2 v = *(const float2*)(h2 + (size_t)n * HIDD + t * 2);
    float p = v.x * Wfc[t * 2] + v.y * Wfc[t * 2 + 1];
    p = wsum(p);
    if (t == 0) {
        float logit = p + bfc[0];
        out[n] = 1.f / (1.f + __expf(-logit));
    }
}

extern "C" void kernel_launch(void* const* d_in, const int* in_sizes, int n_in,
                              void* d_out, int out_size, void* d_ws, size_t ws_size,
                              hipStream_t stream) {
    (void)in_sizes; (void)n_in; (void)out_size; (void)ws_size;
    const float* x   = (const float*)d_in[0];
    const int*   ei  = (const int*)d_in[1];
    const float* ea  = (const float*)d_in[2];
    const float* W1  = (const float*)d_in[3];
    const float* We1 = (const float*)d_in[4];
    const float* as1 = (const float*)d_in[5];
    const float* ad1 = (const float*)d_in[6];
    const float* ae1 = (const float*)d_in[7];
    const float* b1  = (const float*)d_in[8];
    const float* W2  = (const float*)d_in[9];
    const float* We2 = (const float*)d_in[10];
    const float* as2 = (const float*)d_in[11];
    const float* ad2 = (const float*)d_in[12];
    const float* ae2 = (const float*)d_in[13];
    const float* b2v = (const float*)d_in[14];
    const float* Wfc = (const float*)d_in[15];
    const float* bfc = (const float*)d_in[16];
    float* out = (float*)d_out;

    char* ws = (char*)d_ws;
    size_t off = 0;
    auto take = [&](size_t nb) {
        size_t r = off;
        off += (nb + 255) & ~(size_t)255;
        return r;
    };
    float* consts = (float*)(ws + take(1024));
    int* row_off  = (int*)(ws + take((size_t)(NN + 1) * 4));
    int* cursor   = (int*)(ws + take((size_t)NN * 4));
    int* perm     = (int*)(ws + take((size_t)EE2 * 4));
    int* ssrc     = (int*)(ws + take((size_t)EE2 * 4));
    float* alpha1 = (float*)(ws + take((size_t)EE2 * 16));
    float* alpha2 = (float*)(ws + take((size_t)EE2 * 4));
    float* aS1    = (float*)(ws + take((size_t)NN * 16));
    float* aD1    = (float*)(ws + take((size_t)NN * 16));
    float* aS2    = (float*)(ws + take((size_t)NN * 4));
    float* aD2    = (float*)(ws + take((size_t)NN * 4));
    u16* xh1      = (u16*)(ws + take((size_t)NN * F1 * 2));
    u16* h1       = (u16*)(ws + take((size_t)NN * F1 * 2));
    float* xh2    = (float*)(ws + take((size_t)NN * HIDD * 4));
    float* h2     = (float*)(ws + take((size_t)NN * HIDD * 4));

    k_init<<<(NN + 255) / 256, 256, 0, stream>>>(consts, cursor);
    k_mean<<<512, 256, 0, stream>>>(ea, consts);
    k_consts<<<1, 64, 0, stream>>>(consts, We1, ae1, We2, ae2);
    k_count<<<(EE2 + 255) / 256, 256, 0, stream>>>(ei, cursor);
    k_scan<<<1, SCAN_T, 0, stream>>>(cursor, row_off, cursor);
    k_scatter<<<(EE2 + 255) / 256, 256, 0, stream>>>(ei, cursor, perm, ssrc);

    k_xh1<<<NN, 512, 0, stream>>>(x, W1, as1, ad1, xh1, aS1, aD1);
    k_score1<<<(EE2 + 255) / 256, 256, 0, stream>>>(perm, ei, ea, consts, aS1, aD1, alpha1);
    k_agg1<<<NN, 64, 0, stream>>>(row_off, ssrc, alpha1, xh1, b1, h1);

    k_gemm<<<(NN + BN7 - 1) / BN7, 256, 0, stream>>>(h1, W2, xh2);
    k_sd2<<<NN, 64, 0, stream>>>(xh2, as2, ad2, aS2, aD2);
    k_score2<<<(EE2 + 255) / 256, 256, 0, stream>>>(perm, ei, ea, consts, aS2, aD2, alpha2);
    k_agg2<<<NN, 64, 0, stream>>>(row_off, ssrc, alpha2, xh2, b2v, h2);

    k_final<<<NN, 64, 0, stream>>>(h2, Wfc, bfc, out);
}

// Round 3
// 716.669 us; speedup vs baseline: 1.0960x; 1.0960x over previous
//
#include <hip/hip_runtime.h>

#define NN   40000
#define EE   640000
#define EE2  680000    // EE + NN self loops
#define IND  5
#define ED   11
#define HIDD 128
#define F1   512       // 4 heads * 128

typedef unsigned short u16;
typedef unsigned int   u32;
typedef __attribute__((ext_vector_type(8))) short bf16x8;
typedef __attribute__((ext_vector_type(4))) float f32x4;

__device__ __forceinline__ float bf2f(u16 u) { return __uint_as_float(((u32)u) << 16); }
__device__ __forceinline__ u16 f2bf(float f) {
    u32 u = __float_as_uint(f);
    return (u16)((u + 0x7FFFu + ((u >> 16) & 1u)) >> 16);   // RNE
}

__device__ __forceinline__ float wsum(float v) {
#pragma unroll
    for (int o = 32; o; o >>= 1) v += __shfl_xor(v, o, 64);
    return v;
}
__device__ __forceinline__ float wmaxr(float v) {
#pragma unroll
    for (int o = 32; o; o >>= 1) v = fmaxf(v, __shfl_xor(v, o, 64));
    return v;
}

// ---------------- init: zero consts + per-dst counters ----------------
__global__ void k_init(float* __restrict__ consts, int* __restrict__ cursor) {
    int i = blockIdx.x * blockDim.x + threadIdx.x;
    if (i < 256) consts[i] = 0.f;
    if (i < NN) cursor[i] = 0;
}

// ---------------- consts: ea column means ----------------
// consts layout (floats): [0..10] ea_mean, [16..59] Be1[k*4+h], [64..74] Be2[k],
//                         [80..83] self1[h], [96] self2
__global__ void k_mean(const float* __restrict__ ea, float* __restrict__ consts) {
    float s[ED];
#pragma unroll
    for (int k = 0; k < ED; ++k) s[k] = 0.f;
    int stride = gridDim.x * blockDim.x;
    for (int r = blockIdx.x * blockDim.x + threadIdx.x; r < EE; r += stride) {
        const float* p = ea + (size_t)r * ED;
#pragma unroll
        for (int k = 0; k < ED; ++k) s[k] += p[k];
    }
    __shared__ float ls[256];
    for (int k = 0; k < ED; ++k) {
        ls[threadIdx.x] = s[k];
        __syncthreads();
        for (int o = 128; o; o >>= 1) {
            if (threadIdx.x < o) ls[threadIdx.x] += ls[threadIdx.x + o];
            __syncthreads();
        }
        if (threadIdx.x == 0) atomicAdd(&consts[k], ls[0]);
        __syncthreads();
    }
}

__global__ void k_consts(float* __restrict__ consts,
                         const float* __restrict__ We1, const float* __restrict__ ae1,
                         const float* __restrict__ We2, const float* __restrict__ ae2) {
    int t = threadIdx.x;  // 64 threads
    if (t < ED) consts[t] *= (1.0f / (float)EE);
    if (t < 44) {
        int k = t >> 2, h = t & 3;
        float s = 0.f;
        for (int c = 0; c < HIDD; ++c)
            s += We1[k * F1 + h * HIDD + c] * ae1[h * HIDD + c];
        consts[16 + t] = s;
    }
    if (t >= 48 && t < 48 + ED) {
        int k = t - 48;
        float s = 0.f;
        for (int c = 0; c < HIDD; ++c)
            s += We2[k * HIDD + c] * ae2[c];
        consts[64 + k] = s;
    }
    __syncthreads();
    if (t < 4) {
        float s = 0.f;
        for (int k = 0; k < ED; ++k) s += consts[k] * consts[16 + k * 4 + t];
        consts[80 + t] = s;
    }
    if (t == 8) {
        float s = 0.f;
        for (int k = 0; k < ED; ++k) s += consts[k] * consts[64 + k];
        consts[96] = s;
    }
}

// ---------------- W2 pre-swizzle into MFMA B-fragment order, split hi/lo bf16 ----
// B frag for tile nt (cols nt*16..+15), k-step ks (k = ks*32 + quad*8 + j):
//   idx = ((nt*16 + ks)*64 + lane)*8 + j ; element = W2[k*128 + nt*16 + (lane&15)]
__global__ void k_wswz(const float* __restrict__ W2,
                       u16* __restrict__ bhi, u16* __restrict__ blo) {
    int t = blockIdx.x * blockDim.x + threadIdx.x;   // 8192 = 8nt * 16ks * 64lane
    if (t >= 8192) return;
    int lane = t & 63, ks = (t >> 6) & 15, nt = t >> 10;
    int kbase = ks * 32 + (lane >> 4) * 8;
    int n = nt * 16 + (lane & 15);
    size_t dst = (size_t)t * 8;
#pragma unroll
    for (int j = 0; j < 8; ++j) {
        float v = W2[(size_t)(kbase + j) * HIDD + n];
        u16 h = f2bf(v);
        float resid = v - bf2f(h);
        bhi[dst + j] = h;
        blo[dst + j] = f2bf(resid);
    }
}

// ---------------- CSR build (sorted by dst), shared by both layers ----------------
__global__ void k_count(const int* __restrict__ ei, int* __restrict__ counts) {
    int i = blockIdx.x * blockDim.x + threadIdx.x;
    if (i >= EE2) return;
    int dst = (i < EE) ? ei[EE + i] : (i - EE);
    atomicAdd(&counts[dst], 1);
}

#define SCAN_T 256
#define SCAN_C 157    // 256*157 = 40192 >= NN
__global__ void __launch_bounds__(SCAN_T) k_scan(const int* __restrict__ counts,
                                                 int* __restrict__ row_off,
                                                 int* __restrict__ cur) {
    __shared__ int sh[SCAN_T];
    int t = threadIdx.x;
    int base = t * SCAN_C;
    int s = 0;
    for (int j = 0; j < SCAN_C; ++j) {
        int idx = base + j;
        if (idx < NN) s += counts[idx];
    }
    sh[t] = s;
    __syncthreads();
    for (int o = 1; o < SCAN_T; o <<= 1) {
        int v = (t >= o) ? sh[t - o] : 0;
        __syncthreads();
        sh[t] += v;
        __syncthreads();
    }
    int run = sh[t] - s;  // exclusive prefix
    for (int j = 0; j < SCAN_C; ++j) {
        int idx = base + j;
        if (idx < NN) {
            int c = counts[idx];     // read before overwrite (counts==cur buffer)
            row_off[idx] = run;
            cur[idx] = run;
            run += c;
        }
    }
    if (t == 0) row_off[NN] = EE2;
}

__global__ void k_scatter(const int* __restrict__ ei, int* __restrict__ cur,
                          int* __restrict__ perm, int* __restrict__ ssrc) {
    int i = blockIdx.x * blockDim.x + threadIdx.x;
    if (i >= EE2) return;
    int s, d;
    if (i < EE) { s = ei[i]; d = ei[EE + i]; }
    else        { s = d = i - EE; }
    int pos = atomicAdd(&cur[d], 1);
    perm[pos] = i;
    ssrc[pos] = s;
}

// ---------------- layer 1: xh1 = x@W1 (store bf16), a_src/a_dst dots ----------------
__global__ void __launch_bounds__(512) k_xh1(const float* __restrict__ x,
                                             const float* __restrict__ W1,
                                             const float* __restrict__ as1,
                                             const float* __restrict__ ad1,
                                             u16* __restrict__ xh1,
                                             float* __restrict__ aS1,
                                             float* __restrict__ aD1) {
    int n = blockIdx.x;
    int t = threadIdx.x;
    int h = t >> 7, c = t & 127;
    __shared__ float xs[IND];
    if (t < IND) xs[t] = x[n * IND + t];
    __syncthreads();
    float v = 0.f;
#pragma unroll
    for (int k = 0; k < IND; ++k) v += xs[k] * W1[k * F1 + h * HIDD + c];
    xh1[(size_t)n * F1 + h * HIDD + c] = f2bf(v);
    float p = v * as1[h * HIDD + c];
    float q = v * ad1[h * HIDD + c];
    p = wsum(p); q = wsum(q);
    __shared__ float rp[8], rq[8];
    int w = t >> 6;
    if ((t & 63) == 0) { rp[w] = p; rq[w] = q; }
    __syncthreads();
    if (c == 0) {
        aS1[n * 4 + h] = rp[2 * h] + rp[2 * h + 1];
        aD1[n * 4 + h] = rq[2 * h] + rq[2 * h + 1];
    }
}

// ---------------- layer 1: per-edge scores (sorted order) ----------------
__global__ void k_score1(const int* __restrict__ perm, const int* __restrict__ ei,
                         const float* __restrict__ ea, const float* __restrict__ consts,
                         const float* __restrict__ aS1, const float* __restrict__ aD1,
                         float* __restrict__ alpha1) {
    int i = blockIdx.x * blockDim.x + threadIdx.x;
    if (i >= EE2) return;
    int e = perm[i];
    int s, d;
    float e0, e1, e2, e3;
    if (e < EE) {
        s = ei[e]; d = ei[EE + e];
        e0 = e1 = e2 = e3 = 0.f;
        const float* p = ea + (size_t)e * ED;
#pragma unroll
        for (int k = 0; k < ED; ++k) {
            float a = p[k];
            e0 += a * consts[16 + k * 4 + 0];
            e1 += a * consts[16 + k * 4 + 1];
            e2 += a * consts[16 + k * 4 + 2];
            e3 += a * consts[16 + k * 4 + 3];
        }
    } else {
        s = d = e - EE;
        e0 = consts[80]; e1 = consts[81]; e2 = consts[82]; e3 = consts[83];
    }
    float4 vs = *(const float4*)(aS1 + (size_t)s * 4);
    float4 vd = *(const float4*)(aD1 + (size_t)d * 4);
    float t0 = vs.x + vd.x + e0, t1 = vs.y + vd.y + e1;
    float t2 = vs.z + vd.z + e2, t3 = vs.w + vd.w + e3;
    t0 = t0 > 0.f ? t0 : 0.2f * t0;
    t1 = t1 > 0.f ? t1 : 0.2f * t1;
    t2 = t2 > 0.f ? t2 : 0.2f * t2;
    t3 = t3 > 0.f ? t3 : 0.2f * t3;
    *(float4*)(alpha1 + (size_t)i * 4) = make_float4(t0, t1, t2, t3);
}

// ---------------- layer 1: softmax + gather-aggregate, 1 wave per dst ----------------
__global__ void __launch_bounds__(64) k_agg1(const int* __restrict__ row_off,
                                             const int* __restrict__ ssrc,
                                             const float* __restrict__ alpha1,
                                             const u16* __restrict__ xh1,
                                             const float* __restrict__ b1,
                                             u16* __restrict__ h1) {
    int n = blockIdx.x, t = threadIdx.x;
    int s0 = row_off[n], s1 = row_off[n + 1];
    float m0 = -1e30f, m1 = -1e30f, m2 = -1e30f, m3 = -1e30f;
    for (int i = s0 + t; i < s1; i += 64) {
        float4 a = *(const float4*)(alpha1 + (size_t)i * 4);
        m0 = fmaxf(m0, a.x); m1 = fmaxf(m1, a.y);
        m2 = fmaxf(m2, a.z); m3 = fmaxf(m3, a.w);
    }
    m0 = wmaxr(m0); m1 = wmaxr(m1); m2 = wmaxr(m2); m3 = wmaxr(m3);
    float z0 = 0.f, z1 = 0.f, z2 = 0.f, z3 = 0.f;
    for (int i = s0 + t; i < s1; i += 64) {
        float4 a = *(const float4*)(alpha1 + (size_t)i * 4);
        z0 += __expf(a.x - m0); z1 += __expf(a.y - m1);
        z2 += __expf(a.z - m2); z3 += __expf(a.w - m3);
    }
    z0 = wsum(z0); z1 = wsum(z1); z2 = wsum(z2); z3 = wsum(z3);
    float i0 = 1.f / (z0 + 1e-16f), i1 = 1.f / (z1 + 1e-16f);
    float i2 = 1.f / (z2 + 1e-16f), i3 = 1.f / (z3 + 1e-16f);
    int c0 = t * 8, h = t >> 4;
    float mh = (h == 0) ? m0 : (h == 1) ? m1 : (h == 2) ? m2 : m3;
    float ih = (h == 0) ? i0 : (h == 1) ? i1 : (h == 2) ? i2 : i3;
    float acc[8];
#pragma unroll
    for (int j = 0; j < 8; ++j) acc[j] = 0.f;
    for (int i = s0; i < s1; ++i) {
        float w = __expf(alpha1[(size_t)i * 4 + h] - mh) * ih;
        uint4 q = *(const uint4*)(xh1 + (size_t)ssrc[i] * F1 + c0);  // 8 bf16
        acc[0] += w * bf2f((u16)(q.x & 0xFFFF)); acc[1] += w * bf2f((u16)(q.x >> 16));
        acc[2] += w * bf2f((u16)(q.y & 0xFFFF)); acc[3] += w * bf2f((u16)(q.y >> 16));
        acc[4] += w * bf2f((u16)(q.z & 0xFFFF)); acc[5] += w * bf2f((u16)(q.z >> 16));
        acc[6] += w * bf2f((u16)(q.w & 0xFFFF)); acc[7] += w * bf2f((u16)(q.w >> 16));
    }
#pragma unroll
    for (int j = 0; j < 8; ++j) {
        float o = fmaxf(acc[j] + b1[c0 + j], 0.f);
        h1[(size_t)n * F1 + c0 + j] = f2bf(o);
    }
}

// ---------------- layer 2 GEMM (MFMA): xh2[N,128] = h1[N,512](bf16) @ W2 ----------
// W2 pre-swizzled split hi/lo. Fused a_src2/a_dst2 epilogue (replaces k_sd2).
// 2500 row tiles of 16, 4 waves/block -> 625 blocks.
__global__ void __launch_bounds__(256) k_gemm2(const u16* __restrict__ h1,
                                               const u16* __restrict__ bhi,
                                               const u16* __restrict__ blo,
                                               const float* __restrict__ as2,
                                               const float* __restrict__ ad2,
                                               float* __restrict__ xh2,
                                               float* __restrict__ aS2,
                                               float* __restrict__ aD2) {
    int tid = threadIdx.x;
    int wv = tid >> 6, lane = tid & 63;
    int tile = blockIdx.x * 4 + wv;
    if (tile >= 2500) return;
    int n0 = tile * 16;
    int mrow = lane & 15, quad = lane >> 4;
    const u16* aptr = h1 + (size_t)(n0 + mrow) * F1 + quad * 8;
    f32x4 acc[8];
#pragma unroll
    for (int nt = 0; nt < 8; ++nt) acc[nt] = (f32x4){0.f, 0.f, 0.f, 0.f};

    for (int ks = 0; ks < 16; ++ks) {
        bf16x8 af = *(const bf16x8*)(aptr + ks * 32);
#pragma unroll
        for (int nt = 0; nt < 8; ++nt) {
            size_t o = (size_t)nt * 8192 + ks * 512 + lane * 8;
            bf16x8 bh = *(const bf16x8*)(bhi + o);
            bf16x8 bl = *(const bf16x8*)(blo + o);
            acc[nt] = __builtin_amdgcn_mfma_f32_16x16x32_bf16(af, bh, acc[nt], 0, 0, 0);
            acc[nt] = __builtin_amdgcn_mfma_f32_16x16x32_bf16(af, bl, acc[nt], 0, 0, 0);
        }
    }
    // C layout: col = nt*16 + mrow, row = quad*4 + r   (m89-verified)
    float ps[4] = {0.f, 0.f, 0.f, 0.f}, pd[4] = {0.f, 0.f, 0.f, 0.f};
#pragma unroll
    for (int nt = 0; nt < 8; ++nt) {
        int col = nt * 16 + mrow;
        float sa = as2[col], da = ad2[col];
#pragma unroll
        for (int r = 0; r < 4; ++r) {
            float v = acc[nt][r];
            xh2[(size_t)(n0 + quad * 4 + r) * HIDD + col] = v;
            ps[r] += v * sa; pd[r] += v * da;
        }
    }
#pragma unroll
    for (int r = 0; r < 4; ++r) {
#pragma unroll
        for (int o = 1; o <= 8; o <<= 1) {
            ps[r] += __shfl_xor(ps[r], o, 64);
            pd[r] += __shfl_xor(pd[r], o, 64);
        }
        if (mrow == 0) {
            aS2[n0 + quad * 4 + r] = ps[r];
            aD2[n0 + quad * 4 + r] = pd[r];
        }
    }
}

// ---------------- layer 2: per-edge scores ----------------
__global__ void k_score2(const int* __restrict__ perm, const int* __restrict__ ei,
                         const float* __restrict__ ea, const float* __restrict__ consts,
                         const float* __restrict__ aS2, const float* __restrict__ aD2,
                         float* __restrict__ alpha2) {
    int i = blockIdx.x * blockDim.x + threadIdx.x;
    if (i >= EE2) return;
    int e = perm[i];
    int s, d;
    float et;
    if (e < EE) {
        s = ei[e]; d = ei[EE + e];
        et = 0.f;
        const float* p = ea + (size_t)e * ED;
#pragma unroll
        for (int k = 0; k < ED; ++k) et += p[k] * consts[64 + k];
    } else {
        s = d = e - EE;
        et = consts[96];
    }
    float t0 = aS2[s] + aD2[d] + et;
    alpha2[i] = t0 > 0.f ? t0 : 0.2f * t0;
}

// ---------------- layer 2: softmax + aggregate ----------------
__global__ void __launch_bounds__(64) k_agg2(const int* __restrict__ row_off,
                                             const int* __restrict__ ssrc,
                                             const float* __restrict__ alpha2,
                                             const float* __restrict__ xh2,
                                             const float* __restrict__ bias2,
                                             float* __restrict__ h2) {
    int n = blockIdx.x, t = threadIdx.x;
    int s0 = row_off[n], s1 = row_off[n + 1];
    float m = -1e30f;
    for (int i = s0 + t; i < s1; i += 64) m = fmaxf(m, alpha2[i]);
    m = wmaxr(m);
    float z = 0.f;
    for (int i = s0 + t; i < s1; i += 64) z += __expf(alpha2[i] - m);
    z = wsum(z);
    float inv = 1.f / (z + 1e-16f);
    int c0 = t * 2;
    float a0 = 0.f, a1 = 0.f;
    for (int i = s0; i < s1; ++i) {
        float w = __expf(alpha2[i] - m) * inv;
        float2 u = *(const float2*)(xh2 + (size_t)ssrc[i] * HIDD + c0);
        a0 += w * u.x; a1 += w * u.y;
    }
    float2 o;
    o.x = fmaxf(a0 + bias2[c0], 0.f);
    o.y = fmaxf(a1 + bias2[c0 + 1], 0.f);
    *(float2*)(h2 + (size_t)n * HIDD + c0) = o;
}

// ---------------- final FC + sigmoid ----------------
__global__ void __launch_bounds__(64) k_final(const float* __restrict__ h2,
                                              const float* __restrict__ Wfc,
                                              const float* __restrict__ bfc,
                                              float* __restrict__ out) {
    int n = blockIdx.x, t = threadIdx.x;
    float2 v = *(const float2*)(h2 + (size_t)n * HIDD + t * 2);
    float p = v.x * Wfc[t * 2] + v.y * Wfc[t * 2 + 1];
    p = wsum(p);
    if (t == 0) {
        float logit = p + bfc[0];
        out[n] = 1.f / (1.f + __expf(-logit));
    }
}

extern "C" void kernel_launch(void* const* d_in, const int* in_sizes, int n_in,
                              void* d_out, int out_size, void* d_ws, size_t ws_size,
                              hipStream_t stream) {
    (void)in_sizes; (void)n_in; (void)out_size; (void)ws_size;
    const float* x   = (const float*)d_in[0];
    const int*   ei  = (const int*)d_in[1];
    const float* ea  = (const float*)d_in[2];
    const float* W1  = (const float*)d_in[3];
    const float* We1 = (const float*)d_in[4];
    const float* as1 = (const float*)d_in[5];
    const float* ad1 = (const float*)d_in[6];
    const float* ae1 = (const float*)d_in[7];
    const float* b1  = (const float*)d_in[8];
    const float* W2  = (const float*)d_in[9];
    const float* We2 = (const float*)d_in[10];
    const float* as2 = (const float*)d_in[11];
    const float* ad2 = (const float*)d_in[12];
    const float* ae2 = (const float*)d_in[13];
    const float* b2v = (const float*)d_in[14];
    const float* Wfc = (const float*)d_in[15];
    const float* bfc = (const float*)d_in[16];
    float* out = (float*)d_out;

    char* ws = (char*)d_ws;
    size_t off = 0;
    auto take = [&](size_t nb) {
        size_t r = off;
        off += (nb + 255) & ~(size_t)255;
        return r;
    };
    float* consts = (float*)(ws + take(1024));
    int* row_off  = (int*)(ws + take((size_t)(NN + 1) * 4));
    int* cursor   = (int*)(ws + take((size_t)NN * 4));
    int* perm     = (int*)(ws + take((size_t)EE2 * 4));
    int* ssrc     = (int*)(ws + take((size_t)EE2 * 4));
    float* alpha1 = (float*)(ws + take((size_t)EE2 * 16));
    float* alpha2 = (float*)(ws + take((size_t)EE2 * 4));
    float* aS1    = (float*)(ws + take((size_t)NN * 16));
    float* aD1    = (float*)(ws + take((size_t)NN * 16));
    float* aS2    = (float*)(ws + take((size_t)NN * 4));
    float* aD2    = (float*)(ws + take((size_t)NN * 4));
    u16* xh1      = (u16*)(ws + take((size_t)NN * F1 * 2));
    u16* h1       = (u16*)(ws + take((size_t)NN * F1 * 2));
    float* xh2    = (float*)(ws + take((size_t)NN * HIDD * 4));
    float* h2     = (float*)(ws + take((size_t)NN * HIDD * 4));
    u16* w2hi     = (u16*)(ws + take((size_t)65536 * 2));
    u16* w2lo     = (u16*)(ws + take((size_t)65536 * 2));

    k_init<<<(NN + 255) / 256, 256, 0, stream>>>(consts, cursor);
    k_mean<<<512, 256, 0, stream>>>(ea, consts);
    k_consts<<<1, 64, 0, stream>>>(consts, We1, ae1, We2, ae2);
    k_wswz<<<32, 256, 0, stream>>>(W2, w2hi, w2lo);
    k_count<<<(EE2 + 255) / 256, 256, 0, stream>>>(ei, cursor);
    k_scan<<<1, SCAN_T, 0, stream>>>(cursor, row_off, cursor);
    k_scatter<<<(EE2 + 255) / 256, 256, 0, stream>>>(ei, cursor, perm, ssrc);

    k_xh1<<<NN, 512, 0, stream>>>(x, W1, as1, ad1, xh1, aS1, aD1);
    k_score1<<<(EE2 + 255) / 256, 256, 0, stream>>>(perm, ei, ea, consts, aS1, aD1, alpha1);
    k_agg1<<<NN, 64, 0, stream>>>(row_off, ssrc, alpha1, xh1, b1, h1);

    k_gemm2<<<625, 256, 0, stream>>>(h1, w2hi, w2lo, as2, ad2, xh2, aS2, aD2);
    k_score2<<<(EE2 + 255) / 256, 256, 0, stream>>>(perm, ei, ea, consts, aS2, aD2, alpha2);
    k_agg2<<<NN, 64, 0, stream>>>(row_off, ssrc, alpha2, xh2, b2v, h2);

    k_final<<<NN, 64, 0, stream>>>(h2, Wfc, bfc, out);
}

// Round 4
// 622.016 us; speedup vs baseline: 1.2628x; 1.1522x over previous
//
#include <hip/hip_runtime.h>

#define NN   40000
#define EE   640000
#define EE2  680000    // EE + NN self loops
#define IND  5
#define ED   11
#define HIDD 128
#define F1   512       // 4 heads * 128

typedef unsigned short u16;
typedef unsigned int   u32;
typedef __attribute__((ext_vector_type(8))) short bf16x8;
typedef __attribute__((ext_vector_type(4))) float f32x4;

__device__ __forceinline__ float bf2f(u16 u) { return __uint_as_float(((u32)u) << 16); }
__device__ __forceinline__ u16 f2bf(float f) {
    u32 u = __float_as_uint(f);
    return (u16)((u + 0x7FFFu + ((u >> 16) & 1u)) >> 16);   // RNE
}

__device__ __forceinline__ float wsum(float v) {
#pragma unroll
    for (int o = 32; o; o >>= 1) v += __shfl_xor(v, o, 64);
    return v;
}
__device__ __forceinline__ float wmaxr(float v) {
#pragma unroll
    for (int o = 32; o; o >>= 1) v = fmaxf(v, __shfl_xor(v, o, 64));
    return v;
}

// ---------------- init: zero consts + per-dst counters ----------------
__global__ void k_init(float* __restrict__ consts, int* __restrict__ cursor) {
    int i = blockIdx.x * blockDim.x + threadIdx.x;
    if (i < 256) consts[i] = 0.f;
    if (i < NN) cursor[i] = 0;
}

// ---------------- consts: ea column means ----------------
// consts layout (floats): [0..10] ea_mean, [16..59] Be1[k*4+h], [64..74] Be2[k],
//                         [80..83] self1[h], [96] self2
__global__ void k_mean(const float* __restrict__ ea, float* __restrict__ consts) {
    float s[ED];
#pragma unroll
    for (int k = 0; k < ED; ++k) s[k] = 0.f;
    int stride = gridDim.x * blockDim.x;
    for (int r = blockIdx.x * blockDim.x + threadIdx.x; r < EE; r += stride) {
        const float* p = ea + (size_t)r * ED;
#pragma unroll
        for (int k = 0; k < ED; ++k) s[k] += p[k];
    }
    __shared__ float ls[256];
    for (int k = 0; k < ED; ++k) {
        ls[threadIdx.x] = s[k];
        __syncthreads();
        for (int o = 128; o; o >>= 1) {
            if (threadIdx.x < o) ls[threadIdx.x] += ls[threadIdx.x + o];
            __syncthreads();
        }
        if (threadIdx.x == 0) atomicAdd(&consts[k], ls[0]);
        __syncthreads();
    }
}

__global__ void k_consts(float* __restrict__ consts,
                         const float* __restrict__ We1, const float* __restrict__ ae1,
                         const float* __restrict__ We2, const float* __restrict__ ae2) {
    int t = threadIdx.x;  // 64 threads
    if (t < ED) consts[t] *= (1.0f / (float)EE);
    if (t < 44) {
        int k = t >> 2, h = t & 3;
        float s = 0.f;
        for (int c = 0; c < HIDD; ++c)
            s += We1[k * F1 + h * HIDD + c] * ae1[h * HIDD + c];
        consts[16 + t] = s;
    }
    if (t >= 48 && t < 48 + ED) {
        int k = t - 48;
        float s = 0.f;
        for (int c = 0; c < HIDD; ++c)
            s += We2[k * HIDD + c] * ae2[c];
        consts[64 + k] = s;
    }
    __syncthreads();
    if (t < 4) {
        float s = 0.f;
        for (int k = 0; k < ED; ++k) s += consts[k] * consts[16 + k * 4 + t];
        consts[80 + t] = s;
    }
    if (t == 8) {
        float s = 0.f;
        for (int k = 0; k < ED; ++k) s += consts[k] * consts[64 + k];
        consts[96] = s;
    }
}

// ---------------- W2 pre-swizzle into MFMA B-fragment order, split hi/lo bf16 ----
__global__ void k_wswz(const float* __restrict__ W2,
                       u16* __restrict__ bhi, u16* __restrict__ blo) {
    int t = blockIdx.x * blockDim.x + threadIdx.x;   // 8192 = 8nt * 16ks * 64lane
    if (t >= 8192) return;
    int lane = t & 63, ks = (t >> 6) & 15, nt = t >> 10;
    int kbase = ks * 32 + (lane >> 4) * 8;
    int n = nt * 16 + (lane & 15);
    size_t dst = (size_t)t * 8;
#pragma unroll
    for (int j = 0; j < 8; ++j) {
        float v = W2[(size_t)(kbase + j) * HIDD + n];
        u16 h = f2bf(v);
        float resid = v - bf2f(h);
        bhi[dst + j] = h;
        blo[dst + j] = f2bf(resid);
    }
}

// ---------------- CSR build (sorted by dst), shared by both layers ----------------
__global__ void k_count(const int* __restrict__ ei, int* __restrict__ counts) {
    int i = blockIdx.x * blockDim.x + threadIdx.x;
    if (i >= EE2) return;
    int dst = (i < EE) ? ei[EE + i] : (i - EE);
    atomicAdd(&counts[dst], 1);
}

// 3-phase hierarchical exclusive scan of counts[NN] -> row_off/cursor
#define SBLK 256
#define SGRID ((NN + SBLK - 1) / SBLK)   // 157
__global__ void __launch_bounds__(SBLK) k_scanA(const int* __restrict__ counts,
                                                int* __restrict__ local_ex,
                                                int* __restrict__ bsum) {
    __shared__ int sh[SBLK];
    int t = threadIdx.x;
    int i = blockIdx.x * SBLK + t;
    int v = (i < NN) ? counts[i] : 0;
    sh[t] = v;
    __syncthreads();
    for (int o = 1; o < SBLK; o <<= 1) {
        int u = (t >= o) ? sh[t - o] : 0;
        __syncthreads();
        sh[t] += u;
        __syncthreads();
    }
    if (i < NN) local_ex[i] = sh[t] - v;
    if (t == SBLK - 1) bsum[blockIdx.x] = sh[t];
}

__global__ void __launch_bounds__(SBLK) k_scanB(int* __restrict__ bsum,
                                                int* __restrict__ boff) {
    __shared__ int sh[SBLK];
    int t = threadIdx.x;
    int v = (t < SGRID) ? bsum[t] : 0;
    sh[t] = v;
    __syncthreads();
    for (int o = 1; o < SBLK; o <<= 1) {
        int u = (t >= o) ? sh[t - o] : 0;
        __syncthreads();
        sh[t] += u;
        __syncthreads();
    }
    if (t < SGRID) boff[t] = sh[t] - v;
}

__global__ void __launch_bounds__(SBLK) k_scanC(const int* __restrict__ local_ex,
                                                const int* __restrict__ boff,
                                                int* __restrict__ row_off,
                                                int* __restrict__ cur) {
    int t = threadIdx.x;
    int i = blockIdx.x * SBLK + t;
    if (i < NN) {
        int v = local_ex[i] + boff[blockIdx.x];
        row_off[i] = v;
        cur[i] = v;
    }
    if (i == 0) row_off[NN] = EE2;
}

__global__ void k_scatter(const int* __restrict__ ei, int* __restrict__ cur,
                          int* __restrict__ perm, int* __restrict__ ssrc) {
    int i = blockIdx.x * blockDim.x + threadIdx.x;
    if (i >= EE2) return;
    int s, d;
    if (i < EE) { s = ei[i]; d = ei[EE + i]; }
    else        { s = d = i - EE; }
    int pos = atomicAdd(&cur[d], 1);
    perm[pos] = i;
    ssrc[pos] = s;
}

// ---------------- layer 1: xh1 = x@W1 (store bf16), a_src/a_dst dots ----------------
__global__ void __launch_bounds__(512) k_xh1(const float* __restrict__ x,
                                             const float* __restrict__ W1,
                                             const float* __restrict__ as1,
                                             const float* __restrict__ ad1,
                                             u16* __restrict__ xh1,
                                             float* __restrict__ aS1,
                                             float* __restrict__ aD1) {
    int n = blockIdx.x;
    int t = threadIdx.x;
    int h = t >> 7, c = t & 127;
    __shared__ float xs[IND];
    if (t < IND) xs[t] = x[n * IND + t];
    __syncthreads();
    float v = 0.f;
#pragma unroll
    for (int k = 0; k < IND; ++k) v += xs[k] * W1[k * F1 + h * HIDD + c];
    xh1[(size_t)n * F1 + h * HIDD + c] = f2bf(v);
    float p = v * as1[h * HIDD + c];
    float q = v * ad1[h * HIDD + c];
    p = wsum(p); q = wsum(q);
    __shared__ float rp[8], rq[8];
    int w = t >> 6;
    if ((t & 63) == 0) { rp[w] = p; rq[w] = q; }
    __syncthreads();
    if (c == 0) {
        aS1[n * 4 + h] = rp[2 * h] + rp[2 * h + 1];
        aD1[n * 4 + h] = rq[2 * h] + rq[2 * h + 1];
    }
}

// ---------------- layer 1: per-edge scores (sorted order) ----------------
__global__ void k_score1(const int* __restrict__ perm, const int* __restrict__ ei,
                         const float* __restrict__ ea, const float* __restrict__ consts,
                         const float* __restrict__ aS1, const float* __restrict__ aD1,
                         float* __restrict__ alpha1) {
    int i = blockIdx.x * blockDim.x + threadIdx.x;
    if (i >= EE2) return;
    int e = perm[i];
    int s, d;
    float e0, e1, e2, e3;
    if (e < EE) {
        s = ei[e]; d = ei[EE + e];
        e0 = e1 = e2 = e3 = 0.f;
        const float* p = ea + (size_t)e * ED;
#pragma unroll
        for (int k = 0; k < ED; ++k) {
            float a = p[k];
            e0 += a * consts[16 + k * 4 + 0];
            e1 += a * consts[16 + k * 4 + 1];
            e2 += a * consts[16 + k * 4 + 2];
            e3 += a * consts[16 + k * 4 + 3];
        }
    } else {
        s = d = e - EE;
        e0 = consts[80]; e1 = consts[81]; e2 = consts[82]; e3 = consts[83];
    }
    float4 vs = *(const float4*)(aS1 + (size_t)s * 4);
    float4 vd = *(const float4*)(aD1 + (size_t)d * 4);
    float t0 = vs.x + vd.x + e0, t1 = vs.y + vd.y + e1;
    float t2 = vs.z + vd.z + e2, t3 = vs.w + vd.w + e3;
    t0 = t0 > 0.f ? t0 : 0.2f * t0;
    t1 = t1 > 0.f ? t1 : 0.2f * t1;
    t2 = t2 > 0.f ? t2 : 0.2f * t2;
    t3 = t3 > 0.f ? t3 : 0.2f * t3;
    *(float4*)(alpha1 + (size_t)i * 4) = make_float4(t0, t1, t2, t3);
}

// ---------------- layer 1: softmax + gather-aggregate, 1 wave per dst ----------------
__global__ void __launch_bounds__(64) k_agg1(const int* __restrict__ row_off,
                                             const int* __restrict__ ssrc,
                                             const float* __restrict__ alpha1,
                                             const u16* __restrict__ xh1,
                                             const float* __restrict__ b1,
                                             u16* __restrict__ h1) {
    int n = blockIdx.x, t = threadIdx.x;
    int s0 = row_off[n], s1 = row_off[n + 1];
    float m0 = -1e30f, m1 = -1e30f, m2 = -1e30f, m3 = -1e30f;
    for (int i = s0 + t; i < s1; i += 64) {
        float4 a = *(const float4*)(alpha1 + (size_t)i * 4);
        m0 = fmaxf(m0, a.x); m1 = fmaxf(m1, a.y);
        m2 = fmaxf(m2, a.z); m3 = fmaxf(m3, a.w);
    }
    m0 = wmaxr(m0); m1 = wmaxr(m1); m2 = wmaxr(m2); m3 = wmaxr(m3);
    float z0 = 0.f, z1 = 0.f, z2 = 0.f, z3 = 0.f;
    for (int i = s0 + t; i < s1; i += 64) {
        float4 a = *(const float4*)(alpha1 + (size_t)i * 4);
        z0 += __expf(a.x - m0); z1 += __expf(a.y - m1);
        z2 += __expf(a.z - m2); z3 += __expf(a.w - m3);
    }
    z0 = wsum(z0); z1 = wsum(z1); z2 = wsum(z2); z3 = wsum(z3);
    float i0 = 1.f / (z0 + 1e-16f), i1 = 1.f / (z1 + 1e-16f);
    float i2 = 1.f / (z2 + 1e-16f), i3 = 1.f / (z3 + 1e-16f);
    int c0 = t * 8, h = t >> 4;
    float mh = (h == 0) ? m0 : (h == 1) ? m1 : (h == 2) ? m2 : m3;
    float ih = (h == 0) ? i0 : (h == 1) ? i1 : (h == 2) ? i2 : i3;
    float acc[8];
#pragma unroll
    for (int j = 0; j < 8; ++j) acc[j] = 0.f;
    for (int i = s0; i < s1; ++i) {
        float w = __expf(alpha1[(size_t)i * 4 + h] - mh) * ih;
        uint4 q = *(const uint4*)(xh1 + (size_t)ssrc[i] * F1 + c0);  // 8 bf16
        acc[0] += w * bf2f((u16)(q.x & 0xFFFF)); acc[1] += w * bf2f((u16)(q.x >> 16));
        acc[2] += w * bf2f((u16)(q.y & 0xFFFF)); acc[3] += w * bf2f((u16)(q.y >> 16));
        acc[4] += w * bf2f((u16)(q.z & 0xFFFF)); acc[5] += w * bf2f((u16)(q.z >> 16));
        acc[6] += w * bf2f((u16)(q.w & 0xFFFF)); acc[7] += w * bf2f((u16)(q.w >> 16));
    }
#pragma unroll
    for (int j = 0; j < 8; ++j) {
        float o = fmaxf(acc[j] + b1[c0 + j], 0.f);
        h1[(size_t)n * F1 + c0 + j] = f2bf(o);
    }
}

// ---------------- layer 2 GEMM (MFMA): xh2[N,128] = h1[N,512](bf16) @ W2 ----------
__global__ void __launch_bounds__(256) k_gemm2(const u16* __restrict__ h1,
                                               const u16* __restrict__ bhi,
                                               const u16* __restrict__ blo,
                                               const float* __restrict__ as2,
                                               const float* __restrict__ ad2,
                                               float* __restrict__ xh2,
                                               float* __restrict__ aS2,
                                               float* __restrict__ aD2) {
    int tid = threadIdx.x;
    int wv = tid >> 6, lane = tid & 63;
    int tile = blockIdx.x * 4 + wv;
    if (tile >= 2500) return;
    int n0 = tile * 16;
    int mrow = lane & 15, quad = lane >> 4;
    const u16* aptr = h1 + (size_t)(n0 + mrow) * F1 + quad * 8;
    f32x4 acc[8];
#pragma unroll
    for (int nt = 0; nt < 8; ++nt) acc[nt] = (f32x4){0.f, 0.f, 0.f, 0.f};

    for (int ks = 0; ks < 16; ++ks) {
        bf16x8 af = *(const bf16x8*)(aptr + ks * 32);
#pragma unroll
        for (int nt = 0; nt < 8; ++nt) {
            size_t o = (size_t)nt * 8192 + ks * 512 + lane * 8;
            bf16x8 bh = *(const bf16x8*)(bhi + o);
            bf16x8 bl = *(const bf16x8*)(blo + o);
            acc[nt] = __builtin_amdgcn_mfma_f32_16x16x32_bf16(af, bh, acc[nt], 0, 0, 0);
            acc[nt] = __builtin_amdgcn_mfma_f32_16x16x32_bf16(af, bl, acc[nt], 0, 0, 0);
        }
    }
    // C layout: col = nt*16 + mrow, row = quad*4 + r   (m89-verified)
    float ps[4] = {0.f, 0.f, 0.f, 0.f}, pd[4] = {0.f, 0.f, 0.f, 0.f};
#pragma unroll
    for (int nt = 0; nt < 8; ++nt) {
        int col = nt * 16 + mrow;
        float sa = as2[col], da = ad2[col];
#pragma unroll
        for (int r = 0; r < 4; ++r) {
            float v = acc[nt][r];
            xh2[(size_t)(n0 + quad * 4 + r) * HIDD + col] = v;
            ps[r] += v * sa; pd[r] += v * da;
        }
    }
#pragma unroll
    for (int r = 0; r < 4; ++r) {
#pragma unroll
        for (int o = 1; o <= 8; o <<= 1) {
            ps[r] += __shfl_xor(ps[r], o, 64);
            pd[r] += __shfl_xor(pd[r], o, 64);
        }
        if (mrow == 0) {
            aS2[n0 + quad * 4 + r] = ps[r];
            aD2[n0 + quad * 4 + r] = pd[r];
        }
    }
}

// ---------------- layer 2: per-edge scores ----------------
__global__ void k_score2(const int* __restrict__ perm, const int* __restrict__ ei,
                         const float* __restrict__ ea, const float* __restrict__ consts,
                         const float* __restrict__ aS2, const float* __restrict__ aD2,
                         float* __restrict__ alpha2) {
    int i = blockIdx.x * blockDim.x + threadIdx.x;
    if (i >= EE2) return;
    int e = perm[i];
    int s, d;
    float et;
    if (e < EE) {
        s = ei[e]; d = ei[EE + e];
        et = 0.f;
        const float* p = ea + (size_t)e * ED;
#pragma unroll
        for (int k = 0; k < ED; ++k) et += p[k] * consts[64 + k];
    } else {
        s = d = e - EE;
        et = consts[96];
    }
    float t0 = aS2[s] + aD2[d] + et;
    alpha2[i] = t0 > 0.f ? t0 : 0.2f * t0;
}

// ---------------- layer 2: softmax + aggregate ----------------
__global__ void __launch_bounds__(64) k_agg2(const int* __restrict__ row_off,
                                             const int* __restrict__ ssrc,
                                             const float* __restrict__ alpha2,
                                             const float* __restrict__ xh2,
                                             const float* __restrict__ bias2,
                                             float* __restrict__ h2) {
    int n = blockIdx.x, t = threadIdx.x;
    int s0 = row_off[n], s1 = row_off[n + 1];
    float m = -1e30f;
    for (int i = s0 + t; i < s1; i += 64) m = fmaxf(m, alpha2[i]);
    m = wmaxr(m);
    float z = 0.f;
    for (int i = s0 + t; i < s1; i += 64) z += __expf(alpha2[i] - m);
    z = wsum(z);
    float inv = 1.f / (z + 1e-16f);
    int c0 = t * 2;
    float a0 = 0.f, a1 = 0.f;
    for (int i = s0; i < s1; ++i) {
        float w = __expf(alpha2[i] - m) * inv;
        float2 u = *(const float2*)(xh2 + (size_t)ssrc[i] * HIDD + c0);
        a0 += w * u.x; a1 += w * u.y;
    }
    float2 o;
    o.x = fmaxf(a0 + bias2[c0], 0.f);
    o.y = fmaxf(a1 + bias2[c0 + 1], 0.f);
    *(float2*)(h2 + (size_t)n * HIDD + c0) = o;
}

// ---------------- final FC + sigmoid ----------------
__global__ void __launch_bounds__(64) k_final(const float* __restrict__ h2,
                                              const float* __restrict__ Wfc,
                                              const float* __restrict__ bfc,
                                              float* __restrict__ out) {
    int n = blockIdx.x, t = threadIdx.x;
    float2 v = *(const float2*)(h2 + (size_t)n * HIDD + t * 2);
    float p = v.x * Wfc[t * 2] + v.y * Wfc[t * 2 + 1];
    p = wsum(p);
    if (t == 0) {
        float logit = p + bfc[0];
        out[n] = 1.f / (1.f + __expf(-logit));
    }
}

extern "C" void kernel_launch(void* const* d_in, const int* in_sizes, int n_in,
                              void* d_out, int out_size, void* d_ws, size_t ws_size,
                              hipStream_t stream) {
    (void)in_sizes; (void)n_in; (void)out_size; (void)ws_size;
    const float* x   = (const float*)d_in[0];
    const int*   ei  = (const int*)d_in[1];
    const float* ea  = (const float*)d_in[2];
    const float* W1  = (const float*)d_in[3];
    const float* We1 = (const float*)d_in[4];
    const float* as1 = (const float*)d_in[5];
    const float* ad1 = (const float*)d_in[6];
    const float* ae1 = (const float*)d_in[7];
    const float* b1  = (const float*)d_in[8];
    const float* W2  = (const float*)d_in[9];
    const float* We2 = (const float*)d_in[10];
    const float* as2 = (const float*)d_in[11];
    const float* ad2 = (const float*)d_in[12];
    const float* ae2 = (const float*)d_in[13];
    const float* b2v = (const float*)d_in[14];
    const float* Wfc = (const float*)d_in[15];
    const float* bfc = (const float*)d_in[16];
    float* out = (float*)d_out;

    char* ws = (char*)d_ws;
    size_t off = 0;
    auto take = [&](size_t nb) {
        size_t r = off;
        off += (nb + 255) & ~(size_t)255;
        return r;
    };
    float* consts = (float*)(ws + take(1024));
    int* row_off  = (int*)(ws + take((size_t)(NN + 1) * 4));
    int* cursor   = (int*)(ws + take((size_t)NN * 4));
    int* local_ex = (int*)(ws + take((size_t)NN * 4));
    int* bsum     = (int*)(ws + take(1024));
    int* boff     = (int*)(ws + take(1024));
    int* perm     = (int*)(ws + take((size_t)EE2 * 4));
    int* ssrc     = (int*)(ws + take((size_t)EE2 * 4));
    float* alpha1 = (float*)(ws + take((size_t)EE2 * 16));
    float* alpha2 = (float*)(ws + take((size_t)EE2 * 4));
    float* aS1    = (float*)(ws + take((size_t)NN * 16));
    float* aD1    = (float*)(ws + take((size_t)NN * 16));
    float* aS2    = (float*)(ws + take((size_t)NN * 4));
    float* aD2    = (float*)(ws + take((size_t)NN * 4));
    u16* xh1      = (u16*)(ws + take((size_t)NN * F1 * 2));
    u16* h1       = (u16*)(ws + take((size_t)NN * F1 * 2));
    float* xh2    = (float*)(ws + take((size_t)NN * HIDD * 4));
    float* h2     = (float*)(ws + take((size_t)NN * HIDD * 4));
    u16* w2hi     = (u16*)(ws + take((size_t)65536 * 2));
    u16* w2lo     = (u16*)(ws + take((size_t)65536 * 2));

    k_init<<<(NN + 255) / 256, 256, 0, stream>>>(consts, cursor);
    k_mean<<<512, 256, 0, stream>>>(ea, consts);
    k_consts<<<1, 64, 0, stream>>>(consts, We1, ae1, We2, ae2);
    k_wswz<<<32, 256, 0, stream>>>(W2, w2hi, w2lo);
    k_count<<<(EE2 + 255) / 256, 256, 0, stream>>>(ei, cursor);
    k_scanA<<<SGRID, SBLK, 0, stream>>>(cursor, local_ex, bsum);
    k_scanB<<<1, SBLK, 0, stream>>>(bsum, boff);
    k_scanC<<<SGRID, SBLK, 0, stream>>>(local_ex, boff, row_off, cursor);
    k_scatter<<<(EE2 + 255) / 256, 256, 0, stream>>>(ei, cursor, perm, ssrc);

    k_xh1<<<NN, 512, 0, stream>>>(x, W1, as1, ad1, xh1, aS1, aD1);
    k_score1<<<(EE2 + 255) / 256, 256, 0, stream>>>(perm, ei, ea, consts, aS1, aD1, alpha1);
    k_agg1<<<NN, 64, 0, stream>>>(row_off, ssrc, alpha1, xh1, b1, h1);

    k_gemm2<<<625, 256, 0, stream>>>(h1, w2hi, w2lo, as2, ad2, xh2, aS2, aD2);
    k_score2<<<(EE2 + 255) / 256, 256, 0, stream>>>(perm, ei, ea, consts, aS2, aD2, alpha2);
    k_agg2<<<NN, 64, 0, stream>>>(row_off, ssrc, alpha2, xh2, b2v, h2);

    k_final<<<NN, 64, 0, stream>>>(h2, Wfc, bfc, out);
}

// Round 5
// 473.010 us; speedup vs baseline: 1.6606x; 1.3150x over previous
//
#include <hip/hip_runtime.h>

#define NN   40000
#define EE   640000
#define EE2  680000    // EE + NN self loops
#define IND  5
#define ED   11
#define HIDD 128
#define F1   512       // 4 heads * 128

typedef unsigned short u16;
typedef unsigned int   u32;
typedef __attribute__((ext_vector_type(8))) short bf16x8;
typedef __attribute__((ext_vector_type(4))) float f32x4;

__device__ __forceinline__ float bf2f(u16 u) { return __uint_as_float(((u32)u) << 16); }
__device__ __forceinline__ u16 f2bf(float f) {
    u32 u = __float_as_uint(f);
    return (u16)((u + 0x7FFFu + ((u >> 16) & 1u)) >> 16);   // RNE
}

__device__ __forceinline__ float wsum(float v) {
#pragma unroll
    for (int o = 32; o; o >>= 1) v += __shfl_xor(v, o, 64);
    return v;
}
__device__ __forceinline__ float wmaxr(float v) {
#pragma unroll
    for (int o = 32; o; o >>= 1) v = fmaxf(v, __shfl_xor(v, o, 64));
    return v;
}

// ---------------- init: zero consts + per-dst counters ----------------
__global__ void k_init(float* __restrict__ consts, int* __restrict__ cursor) {
    int i = blockIdx.x * blockDim.x + threadIdx.x;
    if (i < 256) consts[i] = 0.f;
    if (i < NN) cursor[i] = 0;
}

// ---------------- consts: ea column means ----------------
// consts layout (floats): [0..10] ea_mean, [16..59] Be1[k*4+h], [64..74] Be2[k],
//                         [80..83] self1[h], [96] self2
__global__ void k_mean(const float* __restrict__ ea, float* __restrict__ consts) {
    float s[ED];
#pragma unroll
    for (int k = 0; k < ED; ++k) s[k] = 0.f;
    int stride = gridDim.x * blockDim.x;
    for (int r = blockIdx.x * blockDim.x + threadIdx.x; r < EE; r += stride) {
        const float* p = ea + (size_t)r * ED;
#pragma unroll
        for (int k = 0; k < ED; ++k) s[k] += p[k];
    }
    __shared__ float ls[256];
    for (int k = 0; k < ED; ++k) {
        ls[threadIdx.x] = s[k];
        __syncthreads();
        for (int o = 128; o; o >>= 1) {
            if (threadIdx.x < o) ls[threadIdx.x] += ls[threadIdx.x + o];
            __syncthreads();
        }
        if (threadIdx.x == 0) atomicAdd(&consts[k], ls[0]);
        __syncthreads();
    }
}

__global__ void k_consts(float* __restrict__ consts,
                         const float* __restrict__ We1, const float* __restrict__ ae1,
                         const float* __restrict__ We2, const float* __restrict__ ae2) {
    int t = threadIdx.x;  // 64 threads
    if (t < ED) consts[t] *= (1.0f / (float)EE);
    if (t < 44) {
        int k = t >> 2, h = t & 3;
        float s = 0.f;
        for (int c = 0; c < HIDD; ++c)
            s += We1[k * F1 + h * HIDD + c] * ae1[h * HIDD + c];
        consts[16 + t] = s;
    }
    if (t >= 48 && t < 48 + ED) {
        int k = t - 48;
        float s = 0.f;
        for (int c = 0; c < HIDD; ++c)
            s += We2[k * HIDD + c] * ae2[c];
        consts[64 + k] = s;
    }
    __syncthreads();
    if (t < 4) {
        float s = 0.f;
        for (int k = 0; k < ED; ++k) s += consts[k] * consts[16 + k * 4 + t];
        consts[80 + t] = s;
    }
    if (t == 8) {
        float s = 0.f;
        for (int k = 0; k < ED; ++k) s += consts[k] * consts[64 + k];
        consts[96] = s;
    }
}

// ---------------- W2 pre-swizzle into MFMA B-fragment order, split hi/lo bf16 ----
__global__ void k_wswz(const float* __restrict__ W2,
                       u16* __restrict__ bhi, u16* __restrict__ blo) {
    int t = blockIdx.x * blockDim.x + threadIdx.x;   // 8192 = 8nt * 16ks * 64lane
    if (t >= 8192) return;
    int lane = t & 63, ks = (t >> 6) & 15, nt = t >> 10;
    int kbase = ks * 32 + (lane >> 4) * 8;
    int n = nt * 16 + (lane & 15);
    size_t dst = (size_t)t * 8;
#pragma unroll
    for (int j = 0; j < 8; ++j) {
        float v = W2[(size_t)(kbase + j) * HIDD + n];
        u16 h = f2bf(v);
        float resid = v - bf2f(h);
        bhi[dst + j] = h;
        blo[dst + j] = f2bf(resid);
    }
}

// ---------------- CSR build (sorted by dst), shared by both layers ----------------
__global__ void k_count(const int* __restrict__ ei, int* __restrict__ counts) {
    int i = blockIdx.x * blockDim.x + threadIdx.x;
    if (i >= EE2) return;
    int dst = (i < EE) ? ei[EE + i] : (i - EE);
    atomicAdd(&counts[dst], 1);
}

// 3-phase hierarchical exclusive scan of counts[NN] -> row_off/cursor
#define SBLK 256
#define SGRID ((NN + SBLK - 1) / SBLK)   // 157
__global__ void __launch_bounds__(SBLK) k_scanA(const int* __restrict__ counts,
                                                int* __restrict__ local_ex,
                                                int* __restrict__ bsum) {
    __shared__ int sh[SBLK];
    int t = threadIdx.x;
    int i = blockIdx.x * SBLK + t;
    int v = (i < NN) ? counts[i] : 0;
    sh[t] = v;
    __syncthreads();
    for (int o = 1; o < SBLK; o <<= 1) {
        int u = (t >= o) ? sh[t - o] : 0;
        __syncthreads();
        sh[t] += u;
        __syncthreads();
    }
    if (i < NN) local_ex[i] = sh[t] - v;
    if (t == SBLK - 1) bsum[blockIdx.x] = sh[t];
}

__global__ void __launch_bounds__(SBLK) k_scanB(int* __restrict__ bsum,
                                                int* __restrict__ boff) {
    __shared__ int sh[SBLK];
    int t = threadIdx.x;
    int v = (t < SGRID) ? bsum[t] : 0;
    sh[t] = v;
    __syncthreads();
    for (int o = 1; o < SBLK; o <<= 1) {
        int u = (t >= o) ? sh[t - o] : 0;
        __syncthreads();
        sh[t] += u;
        __syncthreads();
    }
    if (t < SGRID) boff[t] = sh[t] - v;
}

__global__ void __launch_bounds__(SBLK) k_scanC(const int* __restrict__ local_ex,
                                                const int* __restrict__ boff,
                                                int* __restrict__ row_off,
                                                int* __restrict__ cur) {
    int t = threadIdx.x;
    int i = blockIdx.x * SBLK + t;
    if (i < NN) {
        int v = local_ex[i] + boff[blockIdx.x];
        row_off[i] = v;
        cur[i] = v;
    }
    if (i == 0) row_off[NN] = EE2;
}

__global__ void k_scatter(const int* __restrict__ ei, int* __restrict__ cur,
                          int* __restrict__ perm, int* __restrict__ ssrc,
                          int* __restrict__ sdst) {
    int i = blockIdx.x * blockDim.x + threadIdx.x;
    if (i >= EE2) return;
    int s, d;
    if (i < EE) { s = ei[i]; d = ei[EE + i]; }
    else        { s = d = i - EE; }
    int pos = atomicAdd(&cur[d], 1);
    perm[pos] = i;
    ssrc[pos] = s;
    sdst[pos] = d;
}

// ---------------- layer 1: a_src/a_dst dots only (xh1 never materialized) --------
// one wave per node; lane t owns cols c0..c0+7 (head h = t>>4)
__global__ void __launch_bounds__(64) k_xh1(const float* __restrict__ x,
                                            const float* __restrict__ W1,
                                            const float* __restrict__ as1,
                                            const float* __restrict__ ad1,
                                            float* __restrict__ aS1,
                                            float* __restrict__ aD1) {
    int n = blockIdx.x, t = threadIdx.x;
    int c0 = t * 8, h = t >> 4;
    const float* xp = x + (size_t)n * IND;
    float x0 = xp[0], x1 = xp[1], x2 = xp[2], x3 = xp[3], x4 = xp[4];
    float p = 0.f, q = 0.f;
#pragma unroll
    for (int j = 0; j < 8; ++j) {
        int c = c0 + j;
        float v = x0 * W1[0 * F1 + c] + x1 * W1[1 * F1 + c] + x2 * W1[2 * F1 + c]
                + x3 * W1[3 * F1 + c] + x4 * W1[4 * F1 + c];
        p += v * as1[c];
        q += v * ad1[c];
    }
#pragma unroll
    for (int o = 1; o <= 8; o <<= 1) {     // reduce within 16-lane head group
        p += __shfl_xor(p, o, 64);
        q += __shfl_xor(q, o, 64);
    }
    if ((t & 15) == 0) {
        aS1[n * 4 + h] = p;
        aD1[n * 4 + h] = q;
    }
}

// ---------------- layer 1 scores (sorted order) + layer-2 edge-term precompute ----
__global__ void k_score1(const int* __restrict__ perm, const int* __restrict__ ssrc,
                         const int* __restrict__ sdst,
                         const float* __restrict__ ea, const float* __restrict__ consts,
                         const float* __restrict__ aS1, const float* __restrict__ aD1,
                         float* __restrict__ alpha1, float* __restrict__ et2s) {
    int i = blockIdx.x * blockDim.x + threadIdx.x;
    if (i >= EE2) return;
    int e = perm[i], s = ssrc[i], d = sdst[i];
    float e0, e1, e2, e3, et;
    if (e < EE) {
        e0 = e1 = e2 = e3 = et = 0.f;
        const float* p = ea + (size_t)e * ED;
#pragma unroll
        for (int k = 0; k < ED; ++k) {
            float a = p[k];
            e0 += a * consts[16 + k * 4 + 0];
            e1 += a * consts[16 + k * 4 + 1];
            e2 += a * consts[16 + k * 4 + 2];
            e3 += a * consts[16 + k * 4 + 3];
            et += a * consts[64 + k];
        }
    } else {
        e0 = consts[80]; e1 = consts[81]; e2 = consts[82]; e3 = consts[83];
        et = consts[96];
    }
    float4 vs = *(const float4*)(aS1 + (size_t)s * 4);
    float4 vd = *(const float4*)(aD1 + (size_t)d * 4);
    float t0 = vs.x + vd.x + e0, t1 = vs.y + vd.y + e1;
    float t2 = vs.z + vd.z + e2, t3 = vs.w + vd.w + e3;
    t0 = t0 > 0.f ? t0 : 0.2f * t0;
    t1 = t1 > 0.f ? t1 : 0.2f * t1;
    t2 = t2 > 0.f ? t2 : 0.2f * t2;
    t3 = t3 > 0.f ? t3 : 0.2f * t3;
    *(float4*)(alpha1 + (size_t)i * 4) = make_float4(t0, t1, t2, t3);
    et2s[i] = et;
}

// ---------------- layer 1 aggregate: softmax + 5-dim input-space aggregation ------
// h1[dst] = relu( (sum_e w_e * x[src_e]) @ W1 + b1 )   [linearity of attention]
__global__ void __launch_bounds__(64) k_agg1(const int* __restrict__ row_off,
                                             const int* __restrict__ ssrc,
                                             const float* __restrict__ alpha1,
                                             const float* __restrict__ x,
                                             const float* __restrict__ W1,
                                             const float* __restrict__ b1,
                                             u16* __restrict__ h1) {
    int n = blockIdx.x, t = threadIdx.x;
    int c0 = t * 8, h = t >> 4;
    int s0 = row_off[n], s1 = row_off[n + 1];
    float m0 = -1e30f, m1 = -1e30f, m2 = -1e30f, m3 = -1e30f;
    for (int i = s0 + t; i < s1; i += 64) {
        float4 a = *(const float4*)(alpha1 + (size_t)i * 4);
        m0 = fmaxf(m0, a.x); m1 = fmaxf(m1, a.y);
        m2 = fmaxf(m2, a.z); m3 = fmaxf(m3, a.w);
    }
    m0 = wmaxr(m0); m1 = wmaxr(m1); m2 = wmaxr(m2); m3 = wmaxr(m3);
    float z0 = 0.f, z1 = 0.f, z2 = 0.f, z3 = 0.f;
    for (int i = s0 + t; i < s1; i += 64) {
        float4 a = *(const float4*)(alpha1 + (size_t)i * 4);
        z0 += __expf(a.x - m0); z1 += __expf(a.y - m1);
        z2 += __expf(a.z - m2); z3 += __expf(a.w - m3);
    }
    z0 = wsum(z0); z1 = wsum(z1); z2 = wsum(z2); z3 = wsum(z3);
    float mh = (h == 0) ? m0 : (h == 1) ? m1 : (h == 2) ? m2 : m3;
    float zh = (h == 0) ? z0 : (h == 1) ? z1 : (h == 2) ? z2 : z3;
    float ih = 1.f / (zh + 1e-16f);
    float xa0 = 0.f, xa1 = 0.f, xa2 = 0.f, xa3 = 0.f, xa4 = 0.f;
    for (int i = s0; i < s1; ++i) {
        int s = ssrc[i];
        float w = __expf(alpha1[(size_t)i * 4 + h] - mh) * ih;
        const float* xp = x + (size_t)s * IND;
        xa0 += w * xp[0]; xa1 += w * xp[1]; xa2 += w * xp[2];
        xa3 += w * xp[3]; xa4 += w * xp[4];
    }
#pragma unroll
    for (int j = 0; j < 8; ++j) {
        int c = c0 + j;
        float v = xa0 * W1[0 * F1 + c] + xa1 * W1[1 * F1 + c] + xa2 * W1[2 * F1 + c]
                + xa3 * W1[3 * F1 + c] + xa4 * W1[4 * F1 + c];
        h1[(size_t)n * F1 + c] = f2bf(fmaxf(v + b1[c], 0.f));
    }
}

// ---------------- layer 2 GEMM (MFMA): xh2(bf16) = h1(bf16) @ W2, fused sd2 ------
__global__ void __launch_bounds__(256) k_gemm2(const u16* __restrict__ h1,
                                               const u16* __restrict__ bhi,
                                               const u16* __restrict__ blo,
                                               const float* __restrict__ as2,
                                               const float* __restrict__ ad2,
                                               u16* __restrict__ xh2,
                                               float* __restrict__ aS2,
                                               float* __restrict__ aD2) {
    int tid = threadIdx.x;
    int wv = tid >> 6, lane = tid & 63;
    int tile = blockIdx.x * 4 + wv;
    if (tile >= 2500) return;
    int n0 = tile * 16;
    int mrow = lane & 15, quad = lane >> 4;
    const u16* aptr = h1 + (size_t)(n0 + mrow) * F1 + quad * 8;
    f32x4 acc[8];
#pragma unroll
    for (int nt = 0; nt < 8; ++nt) acc[nt] = (f32x4){0.f, 0.f, 0.f, 0.f};

    for (int ks = 0; ks < 16; ++ks) {
        bf16x8 af = *(const bf16x8*)(aptr + ks * 32);
#pragma unroll
        for (int nt = 0; nt < 8; ++nt) {
            size_t o = (size_t)nt * 8192 + ks * 512 + lane * 8;
            bf16x8 bh = *(const bf16x8*)(bhi + o);
            bf16x8 bl = *(const bf16x8*)(blo + o);
            acc[nt] = __builtin_amdgcn_mfma_f32_16x16x32_bf16(af, bh, acc[nt], 0, 0, 0);
            acc[nt] = __builtin_amdgcn_mfma_f32_16x16x32_bf16(af, bl, acc[nt], 0, 0, 0);
        }
    }
    // C layout: col = nt*16 + mrow, row = quad*4 + r   (m89-verified)
    float ps[4] = {0.f, 0.f, 0.f, 0.f}, pd[4] = {0.f, 0.f, 0.f, 0.f};
#pragma unroll
    for (int nt = 0; nt < 8; ++nt) {
        int col = nt * 16 + mrow;
        float sa = as2[col], da = ad2[col];
#pragma unroll
        for (int r = 0; r < 4; ++r) {
            float v = acc[nt][r];
            xh2[(size_t)(n0 + quad * 4 + r) * HIDD + col] = f2bf(v);
            ps[r] += v * sa; pd[r] += v * da;
        }
    }
#pragma unroll
    for (int r = 0; r < 4; ++r) {
#pragma unroll
        for (int o = 1; o <= 8; o <<= 1) {
            ps[r] += __shfl_xor(ps[r], o, 64);
            pd[r] += __shfl_xor(pd[r], o, 64);
        }
        if (mrow == 0) {
            aS2[n0 + quad * 4 + r] = ps[r];
            aD2[n0 + quad * 4 + r] = pd[r];
        }
    }
}

// ---------------- layer 2: per-edge scores (all-sequential reads) ----------------
__global__ void k_score2(const int* __restrict__ ssrc, const int* __restrict__ sdst,
                         const float* __restrict__ et2s,
                         const float* __restrict__ aS2, const float* __restrict__ aD2,
                         float* __restrict__ alpha2) {
    int i = blockIdx.x * blockDim.x + threadIdx.x;
    if (i >= EE2) return;
    float t0 = aS2[ssrc[i]] + aD2[sdst[i]] + et2s[i];
    alpha2[i] = t0 > 0.f ? t0 : 0.2f * t0;
}

// ---------------- layer 2: softmax + aggregate + FC + sigmoid (fused final) ------
__global__ void __launch_bounds__(64) k_agg2(const int* __restrict__ row_off,
                                             const int* __restrict__ ssrc,
                                             const float* __restrict__ alpha2,
                                             const u16* __restrict__ xh2,
                                             const float* __restrict__ bias2,
                                             const float* __restrict__ Wfc,
                                             const float* __restrict__ bfc,
                                             float* __restrict__ out) {
    int n = blockIdx.x, t = threadIdx.x;
    int s0 = row_off[n], s1 = row_off[n + 1];
    float m = -1e30f;
    for (int i = s0 + t; i < s1; i += 64) m = fmaxf(m, alpha2[i]);
    m = wmaxr(m);
    float z = 0.f;
    for (int i = s0 + t; i < s1; i += 64) z += __expf(alpha2[i] - m);
    z = wsum(z);
    float inv = 1.f / (z + 1e-16f);
    int c0 = t * 2;
    float a0 = 0.f, a1 = 0.f;
    for (int i = s0; i < s1; ++i) {
        float w = __expf(alpha2[i] - m) * inv;
        u32 q = *(const u32*)(xh2 + (size_t)ssrc[i] * HIDD + c0);   // 2 bf16
        a0 += w * bf2f((u16)(q & 0xFFFF));
        a1 += w * bf2f((u16)(q >> 16));
    }
    float o0 = fmaxf(a0 + bias2[c0], 0.f);
    float o1 = fmaxf(a1 + bias2[c0 + 1], 0.f);
    float p = o0 * Wfc[c0] + o1 * Wfc[c0 + 1];
    p = wsum(p);
    if (t == 0) {
        float logit = p + bfc[0];
        out[n] = 1.f / (1.f + __expf(-logit));
    }
}

extern "C" void kernel_launch(void* const* d_in, const int* in_sizes, int n_in,
                              void* d_out, int out_size, void* d_ws, size_t ws_size,
                              hipStream_t stream) {
    (void)in_sizes; (void)n_in; (void)out_size; (void)ws_size;
    const float* x   = (const float*)d_in[0];
    const int*   ei  = (const int*)d_in[1];
    const float* ea  = (const float*)d_in[2];
    const float* W1  = (const float*)d_in[3];
    const float* We1 = (const float*)d_in[4];
    const float* as1 = (const float*)d_in[5];
    const float* ad1 = (const float*)d_in[6];
    const float* ae1 = (const float*)d_in[7];
    const float* b1  = (const float*)d_in[8];
    const float* W2  = (const float*)d_in[9];
    const float* We2 = (const float*)d_in[10];
    const float* as2 = (const float*)d_in[11];
    const float* ad2 = (const float*)d_in[12];
    const float* ae2 = (const float*)d_in[13];
    const float* b2v = (const float*)d_in[14];
    const float* Wfc = (const float*)d_in[15];
    const float* bfc = (const float*)d_in[16];
    float* out = (float*)d_out;

    char* ws = (char*)d_ws;
    size_t off = 0;
    auto take = [&](size_t nb) {
        size_t r = off;
        off += (nb + 255) & ~(size_t)255;
        return r;
    };
    float* consts = (float*)(ws + take(1024));
    int* row_off  = (int*)(ws + take((size_t)(NN + 1) * 4));
    int* cursor   = (int*)(ws + take((size_t)NN * 4));
    int* local_ex = (int*)(ws + take((size_t)NN * 4));
    int* bsum     = (int*)(ws + take(1024));
    int* boff     = (int*)(ws + take(1024));
    int* perm     = (int*)(ws + take((size_t)EE2 * 4));
    int* ssrc     = (int*)(ws + take((size_t)EE2 * 4));
    int* sdst     = (int*)(ws + take((size_t)EE2 * 4));
    float* alpha1 = (float*)(ws + take((size_t)EE2 * 16));
    float* alpha2 = (float*)(ws + take((size_t)EE2 * 4));
    float* et2s   = (float*)(ws + take((size_t)EE2 * 4));
    float* aS1    = (float*)(ws + take((size_t)NN * 16));
    float* aD1    = (float*)(ws + take((size_t)NN * 16));
    float* aS2    = (float*)(ws + take((size_t)NN * 4));
    float* aD2    = (float*)(ws + take((size_t)NN * 4));
    u16* h1       = (u16*)(ws + take((size_t)NN * F1 * 2));
    u16* xh2      = (u16*)(ws + take((size_t)NN * HIDD * 2));
    u16* w2hi     = (u16*)(ws + take((size_t)65536 * 2));
    u16* w2lo     = (u16*)(ws + take((size_t)65536 * 2));

    k_init<<<(NN + 255) / 256, 256, 0, stream>>>(consts, cursor);
    k_mean<<<512, 256, 0, stream>>>(ea, consts);
    k_consts<<<1, 64, 0, stream>>>(consts, We1, ae1, We2, ae2);
    k_wswz<<<32, 256, 0, stream>>>(W2, w2hi, w2lo);
    k_count<<<(EE2 + 255) / 256, 256, 0, stream>>>(ei, cursor);
    k_scanA<<<SGRID, SBLK, 0, stream>>>(cursor, local_ex, bsum);
    k_scanB<<<1, SBLK, 0, stream>>>(bsum, boff);
    k_scanC<<<SGRID, SBLK, 0, stream>>>(local_ex, boff, row_off, cursor);
    k_scatter<<<(EE2 + 255) / 256, 256, 0, stream>>>(ei, cursor, perm, ssrc, sdst);

    k_xh1<<<NN, 64, 0, stream>>>(x, W1, as1, ad1, aS1, aD1);
    k_score1<<<(EE2 + 255) / 256, 256, 0, stream>>>(perm, ssrc, sdst, ea, consts,
                                                    aS1, aD1, alpha1, et2s);
    k_agg1<<<NN, 64, 0, stream>>>(row_off, ssrc, alpha1, x, W1, b1, h1);

    k_gemm2<<<625, 256, 0, stream>>>(h1, w2hi, w2lo, as2, ad2, xh2, aS2, aD2);
    k_score2<<<(EE2 + 255) / 256, 256, 0, stream>>>(ssrc, sdst, et2s, aS2, aD2, alpha2);
    k_agg2<<<NN, 64, 0, stream>>>(row_off, ssrc, alpha2, xh2, b2v, Wfc, bfc, out);
}

// Round 6
// 404.016 us; speedup vs baseline: 1.9442x; 1.1708x over previous
//
#include <hip/hip_runtime.h>

#define NN   40000
#define EE   640000
#define EE2  680000    // EE + NN self loops
#define IND  5
#define ED   11
#define HIDD 128
#define F1   512       // 4 heads * 128

typedef unsigned short u16;
typedef unsigned int   u32;
typedef __attribute__((ext_vector_type(8))) short bf16x8;
typedef __attribute__((ext_vector_type(4))) float f32x4;

__device__ __forceinline__ float bf2f(u16 u) { return __uint_as_float(((u32)u) << 16); }
__device__ __forceinline__ u16 f2bf(float f) {
    u32 u = __float_as_uint(f);
    return (u16)((u + 0x7FFFu + ((u >> 16) & 1u)) >> 16);   // RNE
}

__device__ __forceinline__ float wsum(float v) {
#pragma unroll
    for (int o = 32; o; o >>= 1) v += __shfl_xor(v, o, 64);
    return v;
}
__device__ __forceinline__ float wmaxr(float v) {
#pragma unroll
    for (int o = 32; o; o >>= 1) v = fmaxf(v, __shfl_xor(v, o, 64));
    return v;
}

// ---------------- init: zero consts + per-dst counters ----------------
__global__ void k_init(float* __restrict__ consts, int* __restrict__ cursor) {
    int i = blockIdx.x * blockDim.x + threadIdx.x;
    if (i < 256) consts[i] = 0.f;
    if (i < NN) cursor[i] = 0;
}

// consts layout (floats): [0..10] ea col-sums -> means, [16..59] Be1[k*4+h],
//                         [64..74] Be2[k], [80..83] self1[h], [96] self2
__global__ void k_constsA(float* __restrict__ consts,
                          const float* __restrict__ We1, const float* __restrict__ ae1,
                          const float* __restrict__ We2, const float* __restrict__ ae2) {
    int t = threadIdx.x;  // 64 threads
    if (t < 44) {
        int k = t >> 2, h = t & 3;
        float s = 0.f;
        for (int c = 0; c < HIDD; ++c)
            s += We1[k * F1 + h * HIDD + c] * ae1[h * HIDD + c];
        consts[16 + t] = s;
    }
    if (t >= 48 && t < 48 + ED) {
        int k = t - 48;
        float s = 0.f;
        for (int c = 0; c < HIDD; ++c)
            s += We2[k * HIDD + c] * ae2[c];
        consts[64 + k] = s;
    }
}

__global__ void k_constsB(float* __restrict__ consts) {
    int t = threadIdx.x;  // 64 threads
    if (t < ED) consts[t] *= (1.0f / (float)EE);
    __syncthreads();
    if (t < 4) {
        float s = 0.f;
        for (int k = 0; k < ED; ++k) s += consts[k] * consts[16 + k * 4 + t];
        consts[80 + t] = s;
    }
    if (t == 8) {
        float s = 0.f;
        for (int k = 0; k < ED; ++k) s += consts[k] * consts[64 + k];
        consts[96] = s;
    }
}

// ---------------- W2 pre-swizzle into MFMA B-fragment order, split hi/lo bf16 ----
__global__ void k_wswz(const float* __restrict__ W2,
                       u16* __restrict__ bhi, u16* __restrict__ blo) {
    int t = blockIdx.x * blockDim.x + threadIdx.x;   // 8192 = 8nt * 16ks * 64lane
    if (t >= 8192) return;
    int lane = t & 63, ks = (t >> 6) & 15, nt = t >> 10;
    int kbase = ks * 32 + (lane >> 4) * 8;
    int n = nt * 16 + (lane & 15);
    size_t dst = (size_t)t * 8;
#pragma unroll
    for (int j = 0; j < 8; ++j) {
        float v = W2[(size_t)(kbase + j) * HIDD + n];
        u16 h = f2bf(v);
        float resid = v - bf2f(h);
        bhi[dst + j] = h;
        blo[dst + j] = f2bf(resid);
    }
}

// ---------------- CSR build (sorted by dst), shared by both layers ----------------
__global__ void k_count(const int* __restrict__ ei, int* __restrict__ counts) {
    int i = blockIdx.x * blockDim.x + threadIdx.x;
    if (i >= EE2) return;
    int dst = (i < EE) ? ei[EE + i] : (i - EE);
    atomicAdd(&counts[dst], 1);
}

// 3-phase hierarchical exclusive scan of counts[NN] -> row_off/cursor
#define SBLK 256
#define SGRID ((NN + SBLK - 1) / SBLK)   // 157
__global__ void __launch_bounds__(SBLK) k_scanA(const int* __restrict__ counts,
                                                int* __restrict__ local_ex,
                                                int* __restrict__ bsum) {
    __shared__ int sh[SBLK];
    int t = threadIdx.x;
    int i = blockIdx.x * SBLK + t;
    int v = (i < NN) ? counts[i] : 0;
    sh[t] = v;
    __syncthreads();
    for (int o = 1; o < SBLK; o <<= 1) {
        int u = (t >= o) ? sh[t - o] : 0;
        __syncthreads();
        sh[t] += u;
        __syncthreads();
    }
    if (i < NN) local_ex[i] = sh[t] - v;
    if (t == SBLK - 1) bsum[blockIdx.x] = sh[t];
}

__global__ void __launch_bounds__(SBLK) k_scanB(int* __restrict__ bsum,
                                                int* __restrict__ boff) {
    __shared__ int sh[SBLK];
    int t = threadIdx.x;
    int v = (t < SGRID) ? bsum[t] : 0;
    sh[t] = v;
    __syncthreads();
    for (int o = 1; o < SBLK; o <<= 1) {
        int u = (t >= o) ? sh[t - o] : 0;
        __syncthreads();
        sh[t] += u;
        __syncthreads();
    }
    if (t < SGRID) boff[t] = sh[t] - v;
}

__global__ void __launch_bounds__(SBLK) k_scanC(const int* __restrict__ local_ex,
                                                const int* __restrict__ boff,
                                                int* __restrict__ row_off,
                                                int* __restrict__ cur) {
    int t = threadIdx.x;
    int i = blockIdx.x * SBLK + t;
    if (i < NN) {
        int v = local_ex[i] + boff[blockIdx.x];
        row_off[i] = v;
        cur[i] = v;
    }
    if (i == 0) row_off[NN] = EE2;
}

__global__ void k_scatter(const int* __restrict__ ei, int* __restrict__ cur,
                          int* __restrict__ ssrc, int* __restrict__ sdst,
                          int* __restrict__ invp) {
    int i = blockIdx.x * blockDim.x + threadIdx.x;
    if (i >= EE2) return;
    int s, d;
    if (i < EE) { s = ei[i]; d = ei[EE + i]; }
    else        { s = d = i - EE; }
    int pos = atomicAdd(&cur[d], 1);
    ssrc[pos] = s;
    sdst[pos] = d;
    invp[i] = pos;     // sequential write (i natural order)
}

// ---------------- fused ea pass: edge terms (scattered to sorted pos) + col sums --
// 1024 rows per block, LDS-staged with coalesced float4 loads.
__global__ void __launch_bounds__(256) k_eterm(const float* __restrict__ ea,
                                               float* consts,
                                               const int* __restrict__ invp,
                                               float* __restrict__ alpha1,
                                               float* __restrict__ et2s) {
    __shared__ float sh[11264];          // 1024 rows * 11 cols, 44 KB
    int t = threadIdx.x, b = blockIdx.x;
    size_t gbase = (size_t)b * 11264;
#pragma unroll
    for (int j = 0; j < 11; ++j) {
        float4 v = *(const float4*)(ea + gbase + j * 1024 + t * 4);
        *(float4*)(sh + j * 1024 + t * 4) = v;
    }
    // Be consts into registers (wave-uniform)
    float Bx[ED], By[ED], Bz[ED], Bw[ED], Bt[ED];
#pragma unroll
    for (int k = 0; k < ED; ++k) {
        Bx[k] = consts[16 + k * 4 + 0];
        By[k] = consts[16 + k * 4 + 1];
        Bz[k] = consts[16 + k * 4 + 2];
        Bw[k] = consts[16 + k * 4 + 3];
        Bt[k] = consts[64 + k];
    }
    int4 ip = *(const int4*)(invp + b * 1024 + t * 4);
    float cs[ED];
#pragma unroll
    for (int k = 0; k < ED; ++k) cs[k] = 0.f;
    __syncthreads();
#pragma unroll
    for (int rr = 0; rr < 4; ++rr) {
        const float* row = sh + t * 44 + rr * 11;
        float e0 = 0.f, e1 = 0.f, e2 = 0.f, e3 = 0.f, et = 0.f;
#pragma unroll
        for (int k = 0; k < ED; ++k) {
            float a = row[k];
            cs[k] += a;
            e0 += a * Bx[k]; e1 += a * By[k]; e2 += a * Bz[k]; e3 += a * Bw[k];
            et += a * Bt[k];
        }
        int pos = (rr == 0) ? ip.x : (rr == 1) ? ip.y : (rr == 2) ? ip.z : ip.w;
        *(float4*)(alpha1 + (size_t)pos * 4) = make_float4(e0, e1, e2, e3);
        et2s[pos] = et;
    }
    __syncthreads();                      // done with staging; reuse sh for reduce
#pragma unroll
    for (int k = 0; k < ED; ++k) cs[k] = wsum(cs[k]);
    int wv = t >> 6;
    if ((t & 63) == 0) {
#pragma unroll
        for (int k = 0; k < ED; ++k) sh[wv * ED + k] = cs[k];
    }
    __syncthreads();
    if (t < ED)
        atomicAdd(&consts[t], sh[t] + sh[ED + t] + sh[2 * ED + t] + sh[3 * ED + t]);
}

// ---------------- self-loop slots: e-terms from mean attr ----------------
__global__ void k_selffill(const int* __restrict__ invp,
                           const float* __restrict__ consts,
                           float* __restrict__ alpha1, float* __restrict__ et2s) {
    int n = blockIdx.x * blockDim.x + threadIdx.x;
    if (n >= NN) return;
    int pos = invp[EE + n];
    *(float4*)(alpha1 + (size_t)pos * 4) =
        make_float4(consts[80], consts[81], consts[82], consts[83]);
    et2s[pos] = consts[96];
}

// ---------------- layer 1: a_src/a_dst dots only (xh1 never materialized) --------
__global__ void __launch_bounds__(64) k_xh1(const float* __restrict__ x,
                                            const float* __restrict__ W1,
                                            const float* __restrict__ as1,
                                            const float* __restrict__ ad1,
                                            float* __restrict__ aS1,
                                            float* __restrict__ aD1) {
    int n = blockIdx.x, t = threadIdx.x;
    int c0 = t * 8, h = t >> 4;
    const float* xp = x + (size_t)n * IND;
    float x0 = xp[0], x1 = xp[1], x2 = xp[2], x3 = xp[3], x4 = xp[4];
    float p = 0.f, q = 0.f;
#pragma unroll
    for (int j = 0; j < 8; ++j) {
        int c = c0 + j;
        float v = x0 * W1[0 * F1 + c] + x1 * W1[1 * F1 + c] + x2 * W1[2 * F1 + c]
                + x3 * W1[3 * F1 + c] + x4 * W1[4 * F1 + c];
        p += v * as1[c];
        q += v * ad1[c];
    }
#pragma unroll
    for (int o = 1; o <= 8; o <<= 1) {     // reduce within 16-lane head group
        p += __shfl_xor(p, o, 64);
        q += __shfl_xor(q, o, 64);
    }
    if ((t & 15) == 0) {
        aS1[n * 4 + h] = p;
        aD1[n * 4 + h] = q;
    }
}

// ---------------- layer 1 scores: in-place alpha1 += src/dst terms, leaky --------
__global__ void k_score1(const int* __restrict__ ssrc, const int* __restrict__ sdst,
                         const float* __restrict__ aS1, const float* __restrict__ aD1,
                         float* __restrict__ alpha1) {
    int i = blockIdx.x * blockDim.x + threadIdx.x;
    if (i >= EE2) return;
    int s = ssrc[i], d = sdst[i];
    float4 ev = *(const float4*)(alpha1 + (size_t)i * 4);
    float4 vs = *(const float4*)(aS1 + (size_t)s * 4);
    float4 vd = *(const float4*)(aD1 + (size_t)d * 4);
    float t0 = vs.x + vd.x + ev.x, t1 = vs.y + vd.y + ev.y;
    float t2 = vs.z + vd.z + ev.z, t3 = vs.w + vd.w + ev.w;
    t0 = t0 > 0.f ? t0 : 0.2f * t0;
    t1 = t1 > 0.f ? t1 : 0.2f * t1;
    t2 = t2 > 0.f ? t2 : 0.2f * t2;
    t3 = t3 > 0.f ? t3 : 0.2f * t3;
    *(float4*)(alpha1 + (size_t)i * 4) = make_float4(t0, t1, t2, t3);
}

// ---------------- layer 1 aggregate: softmax + 5-dim input-space aggregation ------
__global__ void __launch_bounds__(64) k_agg1(const int* __restrict__ row_off,
                                             const int* __restrict__ ssrc,
                                             const float* __restrict__ alpha1,
                                             const float* __restrict__ x,
                                             const float* __restrict__ W1,
                                             const float* __restrict__ b1,
                                             u16* __restrict__ h1) {
    int n = blockIdx.x, t = threadIdx.x;
    int c0 = t * 8, h = t >> 4;
    int s0 = row_off[n], s1 = row_off[n + 1];
    float m0 = -1e30f, m1 = -1e30f, m2 = -1e30f, m3 = -1e30f;
    for (int i = s0 + t; i < s1; i += 64) {
        float4 a = *(const float4*)(alpha1 + (size_t)i * 4);
        m0 = fmaxf(m0, a.x); m1 = fmaxf(m1, a.y);
        m2 = fmaxf(m2, a.z); m3 = fmaxf(m3, a.w);
    }
    m0 = wmaxr(m0); m1 = wmaxr(m1); m2 = wmaxr(m2); m3 = wmaxr(m3);
    float z0 = 0.f, z1 = 0.f, z2 = 0.f, z3 = 0.f;
    for (int i = s0 + t; i < s1; i += 64) {
        float4 a = *(const float4*)(alpha1 + (size_t)i * 4);
        z0 += __expf(a.x - m0); z1 += __expf(a.y - m1);
        z2 += __expf(a.z - m2); z3 += __expf(a.w - m3);
    }
    z0 = wsum(z0); z1 = wsum(z1); z2 = wsum(z2); z3 = wsum(z3);
    float mh = (h == 0) ? m0 : (h == 1) ? m1 : (h == 2) ? m2 : m3;
    float zh = (h == 0) ? z0 : (h == 1) ? z1 : (h == 2) ? z2 : z3;
    float ih = 1.f / (zh + 1e-16f);
    float xa0 = 0.f, xa1 = 0.f, xa2 = 0.f, xa3 = 0.f, xa4 = 0.f;
    for (int i = s0; i < s1; ++i) {
        int s = ssrc[i];
        float w = __expf(alpha1[(size_t)i * 4 + h] - mh) * ih;
        const float* xp = x + (size_t)s * IND;
        xa0 += w * xp[0]; xa1 += w * xp[1]; xa2 += w * xp[2];
        xa3 += w * xp[3]; xa4 += w * xp[4];
    }
#pragma unroll
    for (int j = 0; j < 8; ++j) {
        int c = c0 + j;
        float v = xa0 * W1[0 * F1 + c] + xa1 * W1[1 * F1 + c] + xa2 * W1[2 * F1 + c]
                + xa3 * W1[3 * F1 + c] + xa4 * W1[4 * F1 + c];
        h1[(size_t)n * F1 + c] = f2bf(fmaxf(v + b1[c], 0.f));
    }
}

// ---------------- layer 2 GEMM (MFMA): xh2(bf16) = h1(bf16) @ W2, fused sd2 ------
__global__ void __launch_bounds__(256) k_gemm2(const u16* __restrict__ h1,
                                               const u16* __restrict__ bhi,
                                               const u16* __restrict__ blo,
                                               const float* __restrict__ as2,
                                               const float* __restrict__ ad2,
                                               u16* __restrict__ xh2,
                                               float* __restrict__ aS2,
                                               float* __restrict__ aD2) {
    int tid = threadIdx.x;
    int wv = tid >> 6, lane = tid & 63;
    int tile = blockIdx.x * 4 + wv;
    if (tile >= 2500) return;
    int n0 = tile * 16;
    int mrow = lane & 15, quad = lane >> 4;
    const u16* aptr = h1 + (size_t)(n0 + mrow) * F1 + quad * 8;
    f32x4 acc[8];
#pragma unroll
    for (int nt = 0; nt < 8; ++nt) acc[nt] = (f32x4){0.f, 0.f, 0.f, 0.f};

    for (int ks = 0; ks < 16; ++ks) {
        bf16x8 af = *(const bf16x8*)(aptr + ks * 32);
#pragma unroll
        for (int nt = 0; nt < 8; ++nt) {
            size_t o = (size_t)nt * 8192 + ks * 512 + lane * 8;
            bf16x8 bh = *(const bf16x8*)(bhi + o);
            bf16x8 bl = *(const bf16x8*)(blo + o);
            acc[nt] = __builtin_amdgcn_mfma_f32_16x16x32_bf16(af, bh, acc[nt], 0, 0, 0);
            acc[nt] = __builtin_amdgcn_mfma_f32_16x16x32_bf16(af, bl, acc[nt], 0, 0, 0);
        }
    }
    // C layout: col = nt*16 + mrow, row = quad*4 + r   (m89-verified)
    float ps[4] = {0.f, 0.f, 0.f, 0.f}, pd[4] = {0.f, 0.f, 0.f, 0.f};
#pragma unroll
    for (int nt = 0; nt < 8; ++nt) {
        int col = nt * 16 + mrow;
        float sa = as2[col], da = ad2[col];
#pragma unroll
        for (int r = 0; r < 4; ++r) {
            float v = acc[nt][r];
            xh2[(size_t)(n0 + quad * 4 + r) * HIDD + col] = f2bf(v);
            ps[r] += v * sa; pd[r] += v * da;
        }
    }
#pragma unroll
    for (int r = 0; r < 4; ++r) {
#pragma unroll
        for (int o = 1; o <= 8; o <<= 1) {
            ps[r] += __shfl_xor(ps[r], o, 64);
            pd[r] += __shfl_xor(pd[r], o, 64);
        }
        if (mrow == 0) {
            aS2[n0 + quad * 4 + r] = ps[r];
            aD2[n0 + quad * 4 + r] = pd[r];
        }
    }
}

// ---------------- layer 2: per-edge scores (all-sequential reads) ----------------
__global__ void k_score2(const int* __restrict__ ssrc, const int* __restrict__ sdst,
                         const float* __restrict__ et2s,
                         const float* __restrict__ aS2, const float* __restrict__ aD2,
                         float* __restrict__ alpha2) {
    int i = blockIdx.x * blockDim.x + threadIdx.x;
    if (i >= EE2) return;
    float t0 = aS2[ssrc[i]] + aD2[sdst[i]] + et2s[i];
    alpha2[i] = t0 > 0.f ? t0 : 0.2f * t0;
}

// ---------------- layer 2: softmax + aggregate + FC + sigmoid (fused final) ------
__global__ void __launch_bounds__(64) k_agg2(const int* __restrict__ row_off,
                                             const int* __restrict__ ssrc,
                                             const float* __restrict__ alpha2,
                                             const u16* __restrict__ xh2,
                                             const float* __restrict__ bias2,
                                             const float* __restrict__ Wfc,
                                             const float* __restrict__ bfc,
                                             float* __restrict__ out) {
    int n = blockIdx.x, t = threadIdx.x;
    int s0 = row_off[n], s1 = row_off[n + 1];
    float m = -1e30f;
    for (int i = s0 + t; i < s1; i += 64) m = fmaxf(m, alpha2[i]);
    m = wmaxr(m);
    float z = 0.f;
    for (int i = s0 + t; i < s1; i += 64) z += __expf(alpha2[i] - m);
    z = wsum(z);
    float inv = 1.f / (z + 1e-16f);
    int c0 = t * 2;
    float a0 = 0.f, a1 = 0.f;
    for (int i = s0; i < s1; ++i) {
        float w = __expf(alpha2[i] - m) * inv;
        u32 q = *(const u32*)(xh2 + (size_t)ssrc[i] * HIDD + c0);   // 2 bf16
        a0 += w * bf2f((u16)(q & 0xFFFF));
        a1 += w * bf2f((u16)(q >> 16));
    }
    float o0 = fmaxf(a0 + bias2[c0], 0.f);
    float o1 = fmaxf(a1 + bias2[c0 + 1], 0.f);
    float p = o0 * Wfc[c0] + o1 * Wfc[c0 + 1];
    p = wsum(p);
    if (t == 0) {
        float logit = p + bfc[0];
        out[n] = 1.f / (1.f + __expf(-logit));
    }
}

extern "C" void kernel_launch(void* const* d_in, const int* in_sizes, int n_in,
                              void* d_out, int out_size, void* d_ws, size_t ws_size,
                              hipStream_t stream) {
    (void)in_sizes; (void)n_in; (void)out_size; (void)ws_size;
    const float* x   = (const float*)d_in[0];
    const int*   ei  = (const int*)d_in[1];
    const float* ea  = (const float*)d_in[2];
    const float* W1  = (const float*)d_in[3];
    const float* We1 = (const float*)d_in[4];
    const float* as1 = (const float*)d_in[5];
    const float* ad1 = (const float*)d_in[6];
    const float* ae1 = (const float*)d_in[7];
    const float* b1  = (const float*)d_in[8];
    const float* W2  = (const float*)d_in[9];
    const float* We2 = (const float*)d_in[10];
    const float* as2 = (const float*)d_in[11];
    const float* ad2 = (const float*)d_in[12];
    const float* ae2 = (const float*)d_in[13];
    const float* b2v = (const float*)d_in[14];
    const float* Wfc = (const float*)d_in[15];
    const float* bfc = (const float*)d_in[16];
    float* out = (float*)d_out;

    char* ws = (char*)d_ws;
    size_t off = 0;
    auto take = [&](size_t nb) {
        size_t r = off;
        off += (nb + 255) & ~(size_t)255;
        return r;
    };
    float* consts = (float*)(ws + take(1024));
    int* row_off  = (int*)(ws + take((size_t)(NN + 1) * 4));
    int* cursor   = (int*)(ws + take((size_t)NN * 4));
    int* local_ex = (int*)(ws + take((size_t)NN * 4));
    int* bsum     = (int*)(ws + take(1024));
    int* boff     = (int*)(ws + take(1024));
    int* invp     = (int*)(ws + take((size_t)EE2 * 4));
    int* ssrc     = (int*)(ws + take((size_t)EE2 * 4));
    int* sdst     = (int*)(ws + take((size_t)EE2 * 4));
    float* alpha1 = (float*)(ws + take((size_t)EE2 * 16));
    float* alpha2 = (float*)(ws + take((size_t)EE2 * 4));
    float* et2s   = (float*)(ws + take((size_t)EE2 * 4));
    float* aS1    = (float*)(ws + take((size_t)NN * 16));
    float* aD1    = (float*)(ws + take((size_t)NN * 16));
    float* aS2    = (float*)(ws + take((size_t)NN * 4));
    float* aD2    = (float*)(ws + take((size_t)NN * 4));
    u16* h1       = (u16*)(ws + take((size_t)NN * F1 * 2));
    u16* xh2      = (u16*)(ws + take((size_t)NN * HIDD * 2));
    u16* w2hi     = (u16*)(ws + take((size_t)65536 * 2));
    u16* w2lo     = (u16*)(ws + take((size_t)65536 * 2));

    k_init<<<(NN + 255) / 256, 256, 0, stream>>>(consts, cursor);
    k_constsA<<<1, 64, 0, stream>>>(consts, We1, ae1, We2, ae2);
    k_wswz<<<32, 256, 0, stream>>>(W2, w2hi, w2lo);
    k_count<<<(EE2 + 255) / 256, 256, 0, stream>>>(ei, cursor);
    k_scanA<<<SGRID, SBLK, 0, stream>>>(cursor, local_ex, bsum);
    k_scanB<<<1, SBLK, 0, stream>>>(bsum, boff);
    k_scanC<<<SGRID, SBLK, 0, stream>>>(local_ex, boff, row_off, cursor);
    k_scatter<<<(EE2 + 255) / 256, 256, 0, stream>>>(ei, cursor, ssrc, sdst, invp);

    k_eterm<<<EE / 1024, 256, 0, stream>>>(ea, consts, invp, alpha1, et2s);
    k_constsB<<<1, 64, 0, stream>>>(consts);
    k_selffill<<<(NN + 255) / 256, 256, 0, stream>>>(invp, consts, alpha1, et2s);

    k_xh1<<<NN, 64, 0, stream>>>(x, W1, as1, ad1, aS1, aD1);
    k_score1<<<(EE2 + 255) / 256, 256, 0, stream>>>(ssrc, sdst, aS1, aD1, alpha1);
    k_agg1<<<NN, 64, 0, stream>>>(row_off, ssrc, alpha1, x, W1, b1, h1);

    k_gemm2<<<625, 256, 0, stream>>>(h1, w2hi, w2lo, as2, ad2, xh2, aS2, aD2);
    k_score2<<<(EE2 + 255) / 256, 256, 0, stream>>>(ssrc, sdst, et2s, aS2, aD2, alpha2);
    k_agg2<<<NN, 64, 0, stream>>>(row_off, ssrc, alpha2, xh2, b2v, Wfc, bfc, out);
}

// Round 7
// 362.635 us; speedup vs baseline: 2.1661x; 1.1141x over previous
//
#include <hip/hip_runtime.h>

#define NN   40000
#define EE   640000
#define EE2  680000    // EE + NN self loops
#define IND  5
#define ED   11
#define HIDD 128
#define F1   512       // 4 heads * 128

typedef unsigned short u16;
typedef unsigned int   u32;
typedef __attribute__((ext_vector_type(8))) short bf16x8;
typedef __attribute__((ext_vector_type(4))) float f32x4;

__device__ __forceinline__ float bf2f(u16 u) { return __uint_as_float(((u32)u) << 16); }
__device__ __forceinline__ u16 f2bf(float f) {
    u32 u = __float_as_uint(f);
    return (u16)((u + 0x7FFFu + ((u >> 16) & 1u)) >> 16);   // RNE
}

__device__ __forceinline__ float wsum(float v) {
#pragma unroll
    for (int o = 32; o; o >>= 1) v += __shfl_xor(v, o, 64);
    return v;
}
__device__ __forceinline__ float wmaxr(float v) {
#pragma unroll
    for (int o = 32; o; o >>= 1) v = fmaxf(v, __shfl_xor(v, o, 64));
    return v;
}

// ---------------- init: zero consts + per-dst counters ----------------
__global__ void k_init(float* __restrict__ consts, int* __restrict__ cursor) {
    int i = blockIdx.x * blockDim.x + threadIdx.x;
    if (i < 256) consts[i] = 0.f;
    if (i < NN) cursor[i] = 0;
}

// consts layout (floats): [0..10] ea col-sums -> means, [16..59] Be1[k*4+h],
//                         [64..74] Be2[k], [80..83] self1[h], [96] self2
__global__ void k_constsA(float* __restrict__ consts,
                          const float* __restrict__ We1, const float* __restrict__ ae1,
                          const float* __restrict__ We2, const float* __restrict__ ae2) {
    int t = threadIdx.x;  // 64 threads
    if (t < 44) {
        int k = t >> 2, h = t & 3;
        float s = 0.f;
        for (int c = 0; c < HIDD; ++c)
            s += We1[k * F1 + h * HIDD + c] * ae1[h * HIDD + c];
        consts[16 + t] = s;
    }
    if (t >= 48 && t < 48 + ED) {
        int k = t - 48;
        float s = 0.f;
        for (int c = 0; c < HIDD; ++c)
            s += We2[k * HIDD + c] * ae2[c];
        consts[64 + k] = s;
    }
}

__global__ void k_constsB(float* __restrict__ consts) {
    int t = threadIdx.x;  // 64 threads
    if (t < ED) consts[t] *= (1.0f / (float)EE);
    __syncthreads();
    if (t < 4) {
        float s = 0.f;
        for (int k = 0; k < ED; ++k) s += consts[k] * consts[16 + k * 4 + t];
        consts[80 + t] = s;
    }
    if (t == 8) {
        float s = 0.f;
        for (int k = 0; k < ED; ++k) s += consts[k] * consts[64 + k];
        consts[96] = s;
    }
}

// ---------------- W2 pre-swizzle into MFMA B-fragment order, split hi/lo bf16 ----
__global__ void k_wswz(const float* __restrict__ W2,
                       u16* __restrict__ bhi, u16* __restrict__ blo) {
    int t = blockIdx.x * blockDim.x + threadIdx.x;   // 8192 = 8nt * 16ks * 64lane
    if (t >= 8192) return;
    int lane = t & 63, ks = (t >> 6) & 15, nt = t >> 10;
    int kbase = ks * 32 + (lane >> 4) * 8;
    int n = nt * 16 + (lane & 15);
    size_t dst = (size_t)t * 8;
#pragma unroll
    for (int j = 0; j < 8; ++j) {
        float v = W2[(size_t)(kbase + j) * HIDD + n];
        u16 h = f2bf(v);
        float resid = v - bf2f(h);
        bhi[dst + j] = h;
        blo[dst + j] = f2bf(resid);
    }
}

// ---------------- CSR build (sorted by dst), shared by both layers ----------------
__global__ void k_count(const int* __restrict__ ei, int* __restrict__ counts) {
    int i = blockIdx.x * blockDim.x + threadIdx.x;
    if (i >= EE2) return;
    int dst = (i < EE) ? ei[EE + i] : (i - EE);
    atomicAdd(&counts[dst], 1);
}

// 3-phase hierarchical exclusive scan of counts[NN] -> row_off/cursor
#define SBLK 256
#define SGRID ((NN + SBLK - 1) / SBLK)   // 157
__global__ void __launch_bounds__(SBLK) k_scanA(const int* __restrict__ counts,
                                                int* __restrict__ local_ex,
                                                int* __restrict__ bsum) {
    __shared__ int sh[SBLK];
    int t = threadIdx.x;
    int i = blockIdx.x * SBLK + t;
    int v = (i < NN) ? counts[i] : 0;
    sh[t] = v;
    __syncthreads();
    for (int o = 1; o < SBLK; o <<= 1) {
        int u = (t >= o) ? sh[t - o] : 0;
        __syncthreads();
        sh[t] += u;
        __syncthreads();
    }
    if (i < NN) local_ex[i] = sh[t] - v;
    if (t == SBLK - 1) bsum[blockIdx.x] = sh[t];
}

__global__ void __launch_bounds__(SBLK) k_scanB(int* __restrict__ bsum,
                                                int* __restrict__ boff) {
    __shared__ int sh[SBLK];
    int t = threadIdx.x;
    int v = (t < SGRID) ? bsum[t] : 0;
    sh[t] = v;
    __syncthreads();
    for (int o = 1; o < SBLK; o <<= 1) {
        int u = (t >= o) ? sh[t - o] : 0;
        __syncthreads();
        sh[t] += u;
        __syncthreads();
    }
    if (t < SGRID) boff[t] = sh[t] - v;
}

__global__ void __launch_bounds__(SBLK) k_scanC(const int* __restrict__ local_ex,
                                                const int* __restrict__ boff,
                                                int* __restrict__ row_off,
                                                int* __restrict__ cur) {
    int t = threadIdx.x;
    int i = blockIdx.x * SBLK + t;
    if (i < NN) {
        int v = local_ex[i] + boff[blockIdx.x];
        row_off[i] = v;
        cur[i] = v;
    }
    if (i == 0) row_off[NN] = EE2;
}

__global__ void k_scatter(const int* __restrict__ ei, int* __restrict__ cur,
                          int* __restrict__ ssrc, int* __restrict__ sdst,
                          int* __restrict__ invp) {
    int i = blockIdx.x * blockDim.x + threadIdx.x;
    if (i >= EE2) return;
    int s, d;
    if (i < EE) { s = ei[i]; d = ei[EE + i]; }
    else        { s = d = i - EE; }
    int pos = atomicAdd(&cur[d], 1);
    ssrc[pos] = s;
    sdst[pos] = d;
    invp[i] = pos;     // sequential write (i natural order)
}

// ---------------- fused ea pass: edge terms (scattered to sorted pos) + col sums --
__global__ void __launch_bounds__(256) k_eterm(const float* __restrict__ ea,
                                               float* consts,
                                               const int* __restrict__ invp,
                                               float* __restrict__ alpha1,
                                               float* __restrict__ et2s) {
    __shared__ float sh[11264];          // 1024 rows * 11 cols, 44 KB
    int t = threadIdx.x, b = blockIdx.x;
    size_t gbase = (size_t)b * 11264;
#pragma unroll
    for (int j = 0; j < 11; ++j) {
        float4 v = *(const float4*)(ea + gbase + j * 1024 + t * 4);
        *(float4*)(sh + j * 1024 + t * 4) = v;
    }
    // Be consts into registers (wave-uniform)
    float Bx[ED], By[ED], Bz[ED], Bw[ED], Bt[ED];
#pragma unroll
    for (int k = 0; k < ED; ++k) {
        Bx[k] = consts[16 + k * 4 + 0];
        By[k] = consts[16 + k * 4 + 1];
        Bz[k] = consts[16 + k * 4 + 2];
        Bw[k] = consts[16 + k * 4 + 3];
        Bt[k] = consts[64 + k];
    }
    int4 ip = *(const int4*)(invp + b * 1024 + t * 4);
    float cs[ED];
#pragma unroll
    for (int k = 0; k < ED; ++k) cs[k] = 0.f;
    __syncthreads();
#pragma unroll
    for (int rr = 0; rr < 4; ++rr) {
        const float* row = sh + t * 44 + rr * 11;
        float e0 = 0.f, e1 = 0.f, e2 = 0.f, e3 = 0.f, et = 0.f;
#pragma unroll
        for (int k = 0; k < ED; ++k) {
            float a = row[k];
            cs[k] += a;
            e0 += a * Bx[k]; e1 += a * By[k]; e2 += a * Bz[k]; e3 += a * Bw[k];
            et += a * Bt[k];
        }
        int pos = (rr == 0) ? ip.x : (rr == 1) ? ip.y : (rr == 2) ? ip.z : ip.w;
        *(float4*)(alpha1 + (size_t)pos * 4) = make_float4(e0, e1, e2, e3);
        et2s[pos] = et;
    }
    __syncthreads();                      // done with staging; reuse sh for reduce
#pragma unroll
    for (int k = 0; k < ED; ++k) cs[k] = wsum(cs[k]);
    int wv = t >> 6;
    if ((t & 63) == 0) {
#pragma unroll
        for (int k = 0; k < ED; ++k) sh[wv * ED + k] = cs[k];
    }
    __syncthreads();
    if (t < ED)
        atomicAdd(&consts[t], sh[t] + sh[ED + t] + sh[2 * ED + t] + sh[3 * ED + t]);
}

// ---------------- self-loop slots: e-terms from mean attr ----------------
__global__ void k_selffill(const int* __restrict__ invp,
                           const float* __restrict__ consts,
                           float* __restrict__ alpha1, float* __restrict__ et2s) {
    int n = blockIdx.x * blockDim.x + threadIdx.x;
    if (n >= NN) return;
    int pos = invp[EE + n];
    *(float4*)(alpha1 + (size_t)pos * 4) =
        make_float4(consts[80], consts[81], consts[82], consts[83]);
    et2s[pos] = consts[96];
}

// ---------------- layer 1: a_src/a_dst dots only (xh1 never materialized) --------
__global__ void __launch_bounds__(64) k_xh1(const float* __restrict__ x,
                                            const float* __restrict__ W1,
                                            const float* __restrict__ as1,
                                            const float* __restrict__ ad1,
                                            float* __restrict__ aS1,
                                            float* __restrict__ aD1) {
    int n = blockIdx.x, t = threadIdx.x;
    int c0 = t * 8, h = t >> 4;
    const float* xp = x + (size_t)n * IND;
    float x0 = xp[0], x1 = xp[1], x2 = xp[2], x3 = xp[3], x4 = xp[4];
    float p = 0.f, q = 0.f;
#pragma unroll
    for (int j = 0; j < 8; ++j) {
        int c = c0 + j;
        float v = x0 * W1[0 * F1 + c] + x1 * W1[1 * F1 + c] + x2 * W1[2 * F1 + c]
                + x3 * W1[3 * F1 + c] + x4 * W1[4 * F1 + c];
        p += v * as1[c];
        q += v * ad1[c];
    }
#pragma unroll
    for (int o = 1; o <= 8; o <<= 1) {     // reduce within 16-lane head group
        p += __shfl_xor(p, o, 64);
        q += __shfl_xor(q, o, 64);
    }
    if ((t & 15) == 0) {
        aS1[n * 4 + h] = p;
        aD1[n * 4 + h] = q;
    }
}

// ---------------- layer 1 scores: in-place alpha1 += src/dst terms, leaky --------
__global__ void k_score1(const int* __restrict__ ssrc, const int* __restrict__ sdst,
                         const float* __restrict__ aS1, const float* __restrict__ aD1,
                         float* __restrict__ alpha1) {
    int i = blockIdx.x * blockDim.x + threadIdx.x;
    if (i >= EE2) return;
    int s = ssrc[i], d = sdst[i];
    float4 ev = *(const float4*)(alpha1 + (size_t)i * 4);
    float4 vs = *(const float4*)(aS1 + (size_t)s * 4);
    float4 vd = *(const float4*)(aD1 + (size_t)d * 4);
    float t0 = vs.x + vd.x + ev.x, t1 = vs.y + vd.y + ev.y;
    float t2 = vs.z + vd.z + ev.z, t3 = vs.w + vd.w + ev.w;
    t0 = t0 > 0.f ? t0 : 0.2f * t0;
    t1 = t1 > 0.f ? t1 : 0.2f * t1;
    t2 = t2 > 0.f ? t2 : 0.2f * t2;
    t3 = t3 > 0.f ? t3 : 0.2f * t3;
    *(float4*)(alpha1 + (size_t)i * 4) = make_float4(t0, t1, t2, t3);
}

// ---------------- layer 1 aggregate: softmax + 5-dim input-space aggregation ------
__global__ void __launch_bounds__(64) k_agg1(const int* __restrict__ row_off,
                                             const int* __restrict__ ssrc,
                                             const float* __restrict__ alpha1,
                                             const float* __restrict__ x,
                                             const float* __restrict__ W1,
                                             const float* __restrict__ b1,
                                             u16* __restrict__ h1) {
    int n = blockIdx.x, t = threadIdx.x;
    int c0 = t * 8, h = t >> 4;
    int s0 = row_off[n], s1 = row_off[n + 1];
    float m0 = -1e30f, m1 = -1e30f, m2 = -1e30f, m3 = -1e30f;
    for (int i = s0 + t; i < s1; i += 64) {
        float4 a = *(const float4*)(alpha1 + (size_t)i * 4);
        m0 = fmaxf(m0, a.x); m1 = fmaxf(m1, a.y);
        m2 = fmaxf(m2, a.z); m3 = fmaxf(m3, a.w);
    }
    m0 = wmaxr(m0); m1 = wmaxr(m1); m2 = wmaxr(m2); m3 = wmaxr(m3);
    float z0 = 0.f, z1 = 0.f, z2 = 0.f, z3 = 0.f;
    for (int i = s0 + t; i < s1; i += 64) {
        float4 a = *(const float4*)(alpha1 + (size_t)i * 4);
        z0 += __expf(a.x - m0); z1 += __expf(a.y - m1);
        z2 += __expf(a.z - m2); z3 += __expf(a.w - m3);
    }
    z0 = wsum(z0); z1 = wsum(z1); z2 = wsum(z2); z3 = wsum(z3);
    float mh = (h == 0) ? m0 : (h == 1) ? m1 : (h == 2) ? m2 : m3;
    float zh = (h == 0) ? z0 : (h == 1) ? z1 : (h == 2) ? z2 : z3;
    float ih = 1.f / (zh + 1e-16f);
    float xa0 = 0.f, xa1 = 0.f, xa2 = 0.f, xa3 = 0.f, xa4 = 0.f;
    for (int i = s0; i < s1; ++i) {
        int s = ssrc[i];
        float w = __expf(alpha1[(size_t)i * 4 + h] - mh) * ih;
        const float* xp = x + (size_t)s * IND;
        xa0 += w * xp[0]; xa1 += w * xp[1]; xa2 += w * xp[2];
        xa3 += w * xp[3]; xa4 += w * xp[4];
    }
#pragma unroll
    for (int j = 0; j < 8; ++j) {
        int c = c0 + j;
        float v = xa0 * W1[0 * F1 + c] + xa1 * W1[1 * F1 + c] + xa2 * W1[2 * F1 + c]
                + xa3 * W1[3 * F1 + c] + xa4 * W1[4 * F1 + c];
        h1[(size_t)n * F1 + c] = f2bf(fmaxf(v + b1[c], 0.f));
    }
}

// ---------------- layer 2 GEMM (MFMA): xh2(bf16) = h1(bf16) @ W2, fused sd2 ------
// Register-double-buffered K-loop: all 16 B-fragments + next A prefetched into
// named register arrays while MFMAs consume the previous set. launch_bounds
// (256,2) raises the VGPR cap to 256 (round-6 version compiled at 52 VGPRs and
// serialized on L2 latency: MfmaUtil 5%, ~640 cyc/load).
__global__ void __launch_bounds__(256, 2) k_gemm2(const u16* __restrict__ h1,
                                                  const u16* __restrict__ bhi,
                                                  const u16* __restrict__ blo,
                                                  const float* __restrict__ as2,
                                                  const float* __restrict__ ad2,
                                                  u16* __restrict__ xh2,
                                                  float* __restrict__ aS2,
                                                  float* __restrict__ aD2) {
    int tid = threadIdx.x;
    int wv = tid >> 6, lane = tid & 63;
    int tile = blockIdx.x * 4 + wv;
    if (tile >= 2500) return;
    int n0 = tile * 16;
    int mrow = lane & 15, quad = lane >> 4;
    const u16* aptr = h1 + (size_t)(n0 + mrow) * F1 + quad * 8;
    const u16* bbase_hi = bhi + lane * 8;
    const u16* bbase_lo = blo + lane * 8;
    f32x4 acc[8];
#pragma unroll
    for (int nt = 0; nt < 8; ++nt) acc[nt] = (f32x4){0.f, 0.f, 0.f, 0.f};

    bf16x8 bh0[8], bl0[8], bh1[8], bl1[8];
    bf16x8 af0, af1;
    af0 = *(const bf16x8*)(aptr);
#pragma unroll
    for (int nt = 0; nt < 8; ++nt) {
        bh0[nt] = *(const bf16x8*)(bbase_hi + nt * 8192);
        bl0[nt] = *(const bf16x8*)(bbase_lo + nt * 8192);
    }
#pragma unroll
    for (int ks = 0; ks < 16; ++ks) {
        if (ks < 15) {
            af1 = *(const bf16x8*)(aptr + (ks + 1) * 32);
#pragma unroll
            for (int nt = 0; nt < 8; ++nt) {
                bh1[nt] = *(const bf16x8*)(bbase_hi + nt * 8192 + (ks + 1) * 512);
                bl1[nt] = *(const bf16x8*)(bbase_lo + nt * 8192 + (ks + 1) * 512);
            }
        }
#pragma unroll
        for (int nt = 0; nt < 8; ++nt) {
            acc[nt] = __builtin_amdgcn_mfma_f32_16x16x32_bf16(af0, bh0[nt], acc[nt], 0, 0, 0);
            acc[nt] = __builtin_amdgcn_mfma_f32_16x16x32_bf16(af0, bl0[nt], acc[nt], 0, 0, 0);
        }
        af0 = af1;
#pragma unroll
        for (int nt = 0; nt < 8; ++nt) { bh0[nt] = bh1[nt]; bl0[nt] = bl1[nt]; }
    }
    // C layout: col = nt*16 + mrow, row = quad*4 + r   (m89-verified)
    float ps[4] = {0.f, 0.f, 0.f, 0.f}, pd[4] = {0.f, 0.f, 0.f, 0.f};
#pragma unroll
    for (int nt = 0; nt < 8; ++nt) {
        int col = nt * 16 + mrow;
        float sa = as2[col], da = ad2[col];
#pragma unroll
        for (int r = 0; r < 4; ++r) {
            float v = acc[nt][r];
            xh2[(size_t)(n0 + quad * 4 + r) * HIDD + col] = f2bf(v);
            ps[r] += v * sa; pd[r] += v * da;
        }
    }
#pragma unroll
    for (int r = 0; r < 4; ++r) {
#pragma unroll
        for (int o = 1; o <= 8; o <<= 1) {
            ps[r] += __shfl_xor(ps[r], o, 64);
            pd[r] += __shfl_xor(pd[r], o, 64);
        }
        if (mrow == 0) {
            aS2[n0 + quad * 4 + r] = ps[r];
            aD2[n0 + quad * 4 + r] = pd[r];
        }
    }
}

// ---------------- layer 2: per-edge scores (all-sequential reads) ----------------
__global__ void k_score2(const int* __restrict__ ssrc, const int* __restrict__ sdst,
                         const float* __restrict__ et2s,
                         const float* __restrict__ aS2, const float* __restrict__ aD2,
                         float* __restrict__ alpha2) {
    int i = blockIdx.x * blockDim.x + threadIdx.x;
    if (i >= EE2) return;
    float t0 = aS2[ssrc[i]] + aD2[sdst[i]] + et2s[i];
    alpha2[i] = t0 > 0.f ? t0 : 0.2f * t0;
}

// ---------------- layer 2: softmax + aggregate + FC + sigmoid (fused final) ------
__global__ void __launch_bounds__(64) k_agg2(const int* __restrict__ row_off,
                                             const int* __restrict__ ssrc,
                                             const float* __restrict__ alpha2,
                                             const u16* __restrict__ xh2,
                                             const float* __restrict__ bias2,
                                             const float* __restrict__ Wfc,
                                             const float* __restrict__ bfc,
                                             float* __restrict__ out) {
    int n = blockIdx.x, t = threadIdx.x;
    int s0 = row_off[n], s1 = row_off[n + 1];
    float m = -1e30f;
    for (int i = s0 + t; i < s1; i += 64) m = fmaxf(m, alpha2[i]);
    m = wmaxr(m);
    float z = 0.f;
    for (int i = s0 + t; i < s1; i += 64) z += __expf(alpha2[i] - m);
    z = wsum(z);
    float inv = 1.f / (z + 1e-16f);
    int c0 = t * 2;
    float a0 = 0.f, a1 = 0.f;
    for (int i = s0; i < s1; ++i) {
        float w = __expf(alpha2[i] - m) * inv;
        u32 q = *(const u32*)(xh2 + (size_t)ssrc[i] * HIDD + c0);   // 2 bf16
        a0 += w * bf2f((u16)(q & 0xFFFF));
        a1 += w * bf2f((u16)(q >> 16));
    }
    float o0 = fmaxf(a0 + bias2[c0], 0.f);
    float o1 = fmaxf(a1 + bias2[c0 + 1], 0.f);
    float p = o0 * Wfc[c0] + o1 * Wfc[c0 + 1];
    p = wsum(p);
    if (t == 0) {
        float logit = p + bfc[0];
        out[n] = 1.f / (1.f + __expf(-logit));
    }
}

extern "C" void kernel_launch(void* const* d_in, const int* in_sizes, int n_in,
                              void* d_out, int out_size, void* d_ws, size_t ws_size,
                              hipStream_t stream) {
    (void)in_sizes; (void)n_in; (void)out_size; (void)ws_size;
    const float* x   = (const float*)d_in[0];
    const int*   ei  = (const int*)d_in[1];
    const float* ea  = (const float*)d_in[2];
    const float* W1  = (const float*)d_in[3];
    const float* We1 = (const float*)d_in[4];
    const float* as1 = (const float*)d_in[5];
    const float* ad1 = (const float*)d_in[6];
    const float* ae1 = (const float*)d_in[7];
    const float* b1  = (const float*)d_in[8];
    const float* W2  = (const float*)d_in[9];
    const float* We2 = (const float*)d_in[10];
    const float* as2 = (const float*)d_in[11];
    const float* ad2 = (const float*)d_in[12];
    const float* ae2 = (const float*)d_in[13];
    const float* b2v = (const float*)d_in[14];
    const float* Wfc = (const float*)d_in[15];
    const float* bfc = (const float*)d_in[16];
    float* out = (float*)d_out;

    char* ws = (char*)d_ws;
    size_t off = 0;
    auto take = [&](size_t nb) {
        size_t r = off;
        off += (nb + 255) & ~(size_t)255;
        return r;
    };
    float* consts = (float*)(ws + take(1024));
    int* row_off  = (int*)(ws + take((size_t)(NN + 1) * 4));
    int* cursor   = (int*)(ws + take((size_t)NN * 4));
    int* local_ex = (int*)(ws + take((size_t)NN * 4));
    int* bsum     = (int*)(ws + take(1024));
    int* boff     = (int*)(ws + take(1024));
    int* invp     = (int*)(ws + take((size_t)EE2 * 4));
    int* ssrc     = (int*)(ws + take((size_t)EE2 * 4));
    int* sdst     = (int*)(ws + take((size_t)EE2 * 4));
    float* alpha1 = (float*)(ws + take((size_t)EE2 * 16));
    float* alpha2 = (float*)(ws + take((size_t)EE2 * 4));
    float* et2s   = (float*)(ws + take((size_t)EE2 * 4));
    float* aS1    = (float*)(ws + take((size_t)NN * 16));
    float* aD1    = (float*)(ws + take((size_t)NN * 16));
    float* aS2    = (float*)(ws + take((size_t)NN * 4));
    float* aD2    = (float*)(ws + take((size_t)NN * 4));
    u16* h1       = (u16*)(ws + take((size_t)NN * F1 * 2));
    u16* xh2      = (u16*)(ws + take((size_t)NN * HIDD * 2));
    u16* w2hi     = (u16*)(ws + take((size_t)65536 * 2));
    u16* w2lo     = (u16*)(ws + take((size_t)65536 * 2));

    k_init<<<(NN + 255) / 256, 256, 0, stream>>>(consts, cursor);
    k_constsA<<<1, 64, 0, stream>>>(consts, We1, ae1, We2, ae2);
    k_wswz<<<32, 256, 0, stream>>>(W2, w2hi, w2lo);
    k_count<<<(EE2 + 255) / 256, 256, 0, stream>>>(ei, cursor);
    k_scanA<<<SGRID, SBLK, 0, stream>>>(cursor, local_ex, bsum);
    k_scanB<<<1, SBLK, 0, stream>>>(bsum, boff);
    k_scanC<<<SGRID, SBLK, 0, stream>>>(local_ex, boff, row_off, cursor);
    k_scatter<<<(EE2 + 255) / 256, 256, 0, stream>>>(ei, cursor, ssrc, sdst, invp);

    k_eterm<<<EE / 1024, 256, 0, stream>>>(ea, consts, invp, alpha1, et2s);
    k_constsB<<<1, 64, 0, stream>>>(consts);
    k_selffill<<<(NN + 255) / 256, 256, 0, stream>>>(invp, consts, alpha1, et2s);

    k_xh1<<<NN, 64, 0, stream>>>(x, W1, as1, ad1, aS1, aD1);
    k_score1<<<(EE2 + 255) / 256, 256, 0, stream>>>(ssrc, sdst, aS1, aD1, alpha1);
    k_agg1<<<NN, 64, 0, stream>>>(row_off, ssrc, alpha1, x, W1, b1, h1);

    k_gemm2<<<625, 256, 0, stream>>>(h1, w2hi, w2lo, as2, ad2, xh2, aS2, aD2);
    k_score2<<<(EE2 + 255) / 256, 256, 0, stream>>>(ssrc, sdst, et2s, aS2, aD2, alpha2);
    k_agg2<<<NN, 64, 0, stream>>>(row_off, ssrc, alpha2, xh2, b2v, Wfc, bfc, out);
}

// Round 8
// 347.904 us; speedup vs baseline: 2.2578x; 1.0423x over previous
//
#include <hip/hip_runtime.h>

#define NN   40000
#define EE   640000
#define EE2  680000    // EE + NN self loops
#define IND  5
#define ED   11
#define HIDD 128
#define F1   512       // 4 heads * 128

typedef unsigned short u16;
typedef unsigned int   u32;
typedef __attribute__((ext_vector_type(8))) short bf16x8;
typedef __attribute__((ext_vector_type(4))) float f32x4;

__device__ __forceinline__ float bf2f(u16 u) { return __uint_as_float(((u32)u) << 16); }
__device__ __forceinline__ u16 f2bf(float f) {
    u32 u = __float_as_uint(f);
    return (u16)((u + 0x7FFFu + ((u >> 16) & 1u)) >> 16);   // RNE
}

__device__ __forceinline__ float wsum(float v) {
#pragma unroll
    for (int o = 32; o; o >>= 1) v += __shfl_xor(v, o, 64);
    return v;
}
__device__ __forceinline__ float wmaxr(float v) {
#pragma unroll
    for (int o = 32; o; o >>= 1) v = fmaxf(v, __shfl_xor(v, o, 64));
    return v;
}

// ---------------- init: zero consts + per-dst counters ----------------
__global__ void k_init(float* __restrict__ consts, int* __restrict__ cursor) {
    int i = blockIdx.x * blockDim.x + threadIdx.x;
    if (i < 256) consts[i] = 0.f;
    if (i < NN) cursor[i] = 0;
}

// consts layout (floats): [0..10] ea col-sums -> means, [16..59] Be1[k*4+h],
//                         [64..74] Be2[k], [80..83] self1[h], [96] self2
__global__ void k_constsA(float* __restrict__ consts,
                          const float* __restrict__ We1, const float* __restrict__ ae1,
                          const float* __restrict__ We2, const float* __restrict__ ae2) {
    int t = threadIdx.x;  // 64 threads
    if (t < 44) {
        int k = t >> 2, h = t & 3;
        float s = 0.f;
        for (int c = 0; c < HIDD; ++c)
            s += We1[k * F1 + h * HIDD + c] * ae1[h * HIDD + c];
        consts[16 + t] = s;
    }
    if (t >= 48 && t < 48 + ED) {
        int k = t - 48;
        float s = 0.f;
        for (int c = 0; c < HIDD; ++c)
            s += We2[k * HIDD + c] * ae2[c];
        consts[64 + k] = s;
    }
}

__global__ void k_constsB(float* __restrict__ consts) {
    int t = threadIdx.x;  // 64 threads
    if (t < ED) consts[t] *= (1.0f / (float)EE);
    __syncthreads();
    if (t < 4) {
        float s = 0.f;
        for (int k = 0; k < ED; ++k) s += consts[k] * consts[16 + k * 4 + t];
        consts[80 + t] = s;
    }
    if (t == 8) {
        float s = 0.f;
        for (int k = 0; k < ED; ++k) s += consts[k] * consts[64 + k];
        consts[96] = s;
    }
}

// ---------------- W2 pre-swizzle into MFMA B-fragment order, split hi/lo bf16 ----
__global__ void k_wswz(const float* __restrict__ W2,
                       u16* __restrict__ bhi, u16* __restrict__ blo) {
    int t = blockIdx.x * blockDim.x + threadIdx.x;   // 8192 = 8nt * 16ks * 64lane
    if (t >= 8192) return;
    int lane = t & 63, ks = (t >> 6) & 15, nt = t >> 10;
    int kbase = ks * 32 + (lane >> 4) * 8;
    int n = nt * 16 + (lane & 15);
    size_t dst = (size_t)t * 8;
#pragma unroll
    for (int j = 0; j < 8; ++j) {
        float v = W2[(size_t)(kbase + j) * HIDD + n];
        u16 h = f2bf(v);
        float resid = v - bf2f(h);
        bhi[dst + j] = h;
        blo[dst + j] = f2bf(resid);
    }
}

// ---------------- CSR build (sorted by dst), shared by both layers ----------------
__global__ void k_count(const int* __restrict__ ei, int* __restrict__ counts) {
    int i = blockIdx.x * blockDim.x + threadIdx.x;
    if (i >= EE2) return;
    int dst = (i < EE) ? ei[EE + i] : (i - EE);
    atomicAdd(&counts[dst], 1);
}

// 3-phase hierarchical exclusive scan of counts[NN] -> row_off/cursor
#define SBLK 256
#define SGRID ((NN + SBLK - 1) / SBLK)   // 157
__global__ void __launch_bounds__(SBLK) k_scanA(const int* __restrict__ counts,
                                                int* __restrict__ local_ex,
                                                int* __restrict__ bsum) {
    __shared__ int sh[SBLK];
    int t = threadIdx.x;
    int i = blockIdx.x * SBLK + t;
    int v = (i < NN) ? counts[i] : 0;
    sh[t] = v;
    __syncthreads();
    for (int o = 1; o < SBLK; o <<= 1) {
        int u = (t >= o) ? sh[t - o] : 0;
        __syncthreads();
        sh[t] += u;
        __syncthreads();
    }
    if (i < NN) local_ex[i] = sh[t] - v;
    if (t == SBLK - 1) bsum[blockIdx.x] = sh[t];
}

__global__ void __launch_bounds__(SBLK) k_scanB(int* __restrict__ bsum,
                                                int* __restrict__ boff) {
    __shared__ int sh[SBLK];
    int t = threadIdx.x;
    int v = (t < SGRID) ? bsum[t] : 0;
    sh[t] = v;
    __syncthreads();
    for (int o = 1; o < SBLK; o <<= 1) {
        int u = (t >= o) ? sh[t - o] : 0;
        __syncthreads();
        sh[t] += u;
        __syncthreads();
    }
    if (t < SGRID) boff[t] = sh[t] - v;
}

__global__ void __launch_bounds__(SBLK) k_scanC(const int* __restrict__ local_ex,
                                                const int* __restrict__ boff,
                                                int* __restrict__ row_off,
                                                int* __restrict__ cur) {
    int t = threadIdx.x;
    int i = blockIdx.x * SBLK + t;
    if (i < NN) {
        int v = local_ex[i] + boff[blockIdx.x];
        row_off[i] = v;
        cur[i] = v;
    }
    if (i == 0) row_off[NN] = EE2;
}

__global__ void k_scatter(const int* __restrict__ ei, int* __restrict__ cur,
                          int* __restrict__ ssrc, int* __restrict__ sdst,
                          int* __restrict__ invp) {
    int i = blockIdx.x * blockDim.x + threadIdx.x;
    if (i >= EE2) return;
    int s, d;
    if (i < EE) { s = ei[i]; d = ei[EE + i]; }
    else        { s = d = i - EE; }
    int pos = atomicAdd(&cur[d], 1);
    ssrc[pos] = s;
    sdst[pos] = d;
    invp[i] = pos;     // sequential write (i natural order)
}

// ---------------- fused ea pass: edge terms (scattered to sorted pos) + col sums --
__global__ void __launch_bounds__(256) k_eterm(const float* __restrict__ ea,
                                               float* consts,
                                               const int* __restrict__ invp,
                                               float* __restrict__ alpha1,
                                               float* __restrict__ et2s) {
    __shared__ float sh[11264];          // 1024 rows * 11 cols, 44 KB
    int t = threadIdx.x, b = blockIdx.x;
    size_t gbase = (size_t)b * 11264;
#pragma unroll
    for (int j = 0; j < 11; ++j) {
        float4 v = *(const float4*)(ea + gbase + j * 1024 + t * 4);
        *(float4*)(sh + j * 1024 + t * 4) = v;
    }
    // Be consts into registers (wave-uniform)
    float Bx[ED], By[ED], Bz[ED], Bw[ED], Bt[ED];
#pragma unroll
    for (int k = 0; k < ED; ++k) {
        Bx[k] = consts[16 + k * 4 + 0];
        By[k] = consts[16 + k * 4 + 1];
        Bz[k] = consts[16 + k * 4 + 2];
        Bw[k] = consts[16 + k * 4 + 3];
        Bt[k] = consts[64 + k];
    }
    int4 ip = *(const int4*)(invp + b * 1024 + t * 4);
    float cs[ED];
#pragma unroll
    for (int k = 0; k < ED; ++k) cs[k] = 0.f;
    __syncthreads();
#pragma unroll
    for (int rr = 0; rr < 4; ++rr) {
        const float* row = sh + t * 44 + rr * 11;
        float e0 = 0.f, e1 = 0.f, e2 = 0.f, e3 = 0.f, et = 0.f;
#pragma unroll
        for (int k = 0; k < ED; ++k) {
            float a = row[k];
            cs[k] += a;
            e0 += a * Bx[k]; e1 += a * By[k]; e2 += a * Bz[k]; e3 += a * Bw[k];
            et += a * Bt[k];
        }
        int pos = (rr == 0) ? ip.x : (rr == 1) ? ip.y : (rr == 2) ? ip.z : ip.w;
        *(float4*)(alpha1 + (size_t)pos * 4) = make_float4(e0, e1, e2, e3);
        et2s[pos] = et;
    }
    __syncthreads();                      // done with staging; reuse sh for reduce
#pragma unroll
    for (int k = 0; k < ED; ++k) cs[k] = wsum(cs[k]);
    int wv = t >> 6;
    if ((t & 63) == 0) {
#pragma unroll
        for (int k = 0; k < ED; ++k) sh[wv * ED + k] = cs[k];
    }
    __syncthreads();
    if (t < ED)
        atomicAdd(&consts[t], sh[t] + sh[ED + t] + sh[2 * ED + t] + sh[3 * ED + t]);
}

// ---------------- self-loop slots: e-terms from mean attr ----------------
__global__ void k_selffill(const int* __restrict__ invp,
                           const float* __restrict__ consts,
                           float* __restrict__ alpha1, float* __restrict__ et2s) {
    int n = blockIdx.x * blockDim.x + threadIdx.x;
    if (n >= NN) return;
    int pos = invp[EE + n];
    *(float4*)(alpha1 + (size_t)pos * 4) =
        make_float4(consts[80], consts[81], consts[82], consts[83]);
    et2s[pos] = consts[96];
}

// ---------------- layer 1: a_src/a_dst dots only (xh1 never materialized) --------
__global__ void __launch_bounds__(64) k_xh1(const float* __restrict__ x,
                                            const float* __restrict__ W1,
                                            const float* __restrict__ as1,
                                            const float* __restrict__ ad1,
                                            float* __restrict__ aS1,
                                            float* __restrict__ aD1) {
    int n = blockIdx.x, t = threadIdx.x;
    int c0 = t * 8, h = t >> 4;
    const float* xp = x + (size_t)n * IND;
    float x0 = xp[0], x1 = xp[1], x2 = xp[2], x3 = xp[3], x4 = xp[4];
    float p = 0.f, q = 0.f;
#pragma unroll
    for (int j = 0; j < 8; ++j) {
        int c = c0 + j;
        float v = x0 * W1[0 * F1 + c] + x1 * W1[1 * F1 + c] + x2 * W1[2 * F1 + c]
                + x3 * W1[3 * F1 + c] + x4 * W1[4 * F1 + c];
        p += v * as1[c];
        q += v * ad1[c];
    }
#pragma unroll
    for (int o = 1; o <= 8; o <<= 1) {     // reduce within 16-lane head group
        p += __shfl_xor(p, o, 64);
        q += __shfl_xor(q, o, 64);
    }
    if ((t & 15) == 0) {
        aS1[n * 4 + h] = p;
        aD1[n * 4 + h] = q;
    }
}

// ---------------- layer 1 scores: in-place alpha1 += src/dst terms, leaky --------
__global__ void k_score1(const int* __restrict__ ssrc, const int* __restrict__ sdst,
                         const float* __restrict__ aS1, const float* __restrict__ aD1,
                         float* __restrict__ alpha1) {
    int i = blockIdx.x * blockDim.x + threadIdx.x;
    if (i >= EE2) return;
    int s = ssrc[i], d = sdst[i];
    float4 ev = *(const float4*)(alpha1 + (size_t)i * 4);
    float4 vs = *(const float4*)(aS1 + (size_t)s * 4);
    float4 vd = *(const float4*)(aD1 + (size_t)d * 4);
    float t0 = vs.x + vd.x + ev.x, t1 = vs.y + vd.y + ev.y;
    float t2 = vs.z + vd.z + ev.z, t3 = vs.w + vd.w + ev.w;
    t0 = t0 > 0.f ? t0 : 0.2f * t0;
    t1 = t1 > 0.f ? t1 : 0.2f * t1;
    t2 = t2 > 0.f ? t2 : 0.2f * t2;
    t3 = t3 > 0.f ? t3 : 0.2f * t3;
    *(float4*)(alpha1 + (size_t)i * 4) = make_float4(t0, t1, t2, t3);
}

// ---------------- layer 1 aggregate: edge-parallel softmax + 5-dim aggregation ----
// Lane t: head h=t&3, edge stream s0+(t>>2) step 16. One exp per (edge,head),
// contiguous alpha reads, 16-lane xor-reduce, shfl redistribution to output heads.
// (Round-7 version iterated edges serially with 64 lanes computing 4 distinct
// exps -> 16x redundant transcendental work, VALUBusy 57%.)
__global__ void __launch_bounds__(64) k_agg1(const int* __restrict__ row_off,
                                             const int* __restrict__ ssrc,
                                             const float* __restrict__ alpha1,
                                             const float* __restrict__ x,
                                             const float* __restrict__ W1,
                                             const float* __restrict__ b1,
                                             u16* __restrict__ h1) {
    int n = blockIdx.x, t = threadIdx.x;
    int s0 = row_off[n], s1 = row_off[n + 1];
    // pass 1: per-head max (strided float4, all 64 lanes)
    float m0 = -1e30f, m1 = -1e30f, m2 = -1e30f, m3 = -1e30f;
    for (int i = s0 + t; i < s1; i += 64) {
        float4 a = *(const float4*)(alpha1 + (size_t)i * 4);
        m0 = fmaxf(m0, a.x); m1 = fmaxf(m1, a.y);
        m2 = fmaxf(m2, a.z); m3 = fmaxf(m3, a.w);
    }
    m0 = wmaxr(m0); m1 = wmaxr(m1); m2 = wmaxr(m2); m3 = wmaxr(m3);
    // pass 2 (fused exp-sum + x-aggregation), edge-parallel
    int h = t & 3;
    float mh = (h == 0) ? m0 : (h == 1) ? m1 : (h == 2) ? m2 : m3;
    float z = 0.f, xa0 = 0.f, xa1 = 0.f, xa2 = 0.f, xa3 = 0.f, xa4 = 0.f;
    for (int i = s0 + (t >> 2); i < s1; i += 16) {
        float ex = __expf(alpha1[(size_t)i * 4 + h] - mh);
        z += ex;
        const float* xp = x + (size_t)ssrc[i] * IND;
        xa0 += ex * xp[0]; xa1 += ex * xp[1]; xa2 += ex * xp[2];
        xa3 += ex * xp[3]; xa4 += ex * xp[4];
    }
#pragma unroll
    for (int o = 4; o <= 32; o <<= 1) {    // reduce 16 lanes sharing h
        z   += __shfl_xor(z, o, 64);
        xa0 += __shfl_xor(xa0, o, 64); xa1 += __shfl_xor(xa1, o, 64);
        xa2 += __shfl_xor(xa2, o, 64); xa3 += __shfl_xor(xa3, o, 64);
        xa4 += __shfl_xor(xa4, o, 64);
    }
    // redistribute: output head ho = t>>4; lane ho holds head ho's totals (ho&3==ho)
    int ho = t >> 4;
    float zz = __shfl(z, ho);
    float y0 = __shfl(xa0, ho), y1 = __shfl(xa1, ho), y2 = __shfl(xa2, ho);
    float y3 = __shfl(xa3, ho), y4 = __shfl(xa4, ho);
    float ih = 1.f / (zz + 1e-16f);
    int c0 = t * 8;
#pragma unroll
    for (int j = 0; j < 8; ++j) {
        int c = c0 + j;
        float v = (y0 * W1[0 * F1 + c] + y1 * W1[1 * F1 + c] + y2 * W1[2 * F1 + c]
                 + y3 * W1[3 * F1 + c] + y4 * W1[4 * F1 + c]) * ih;
        h1[(size_t)n * F1 + c] = f2bf(fmaxf(v + b1[c], 0.f));
    }
}

// ---------------- layer 2 GEMM (MFMA): xh2(bf16) = h1(bf16) @ W2, fused sd2 ------
__global__ void __launch_bounds__(256, 2) k_gemm2(const u16* __restrict__ h1,
                                                  const u16* __restrict__ bhi,
                                                  const u16* __restrict__ blo,
                                                  const float* __restrict__ as2,
                                                  const float* __restrict__ ad2,
                                                  u16* __restrict__ xh2,
                                                  float* __restrict__ aS2,
                                                  float* __restrict__ aD2) {
    int tid = threadIdx.x;
    int wv = tid >> 6, lane = tid & 63;
    int tile = blockIdx.x * 4 + wv;
    if (tile >= 2500) return;
    int n0 = tile * 16;
    int mrow = lane & 15, quad = lane >> 4;
    const u16* aptr = h1 + (size_t)(n0 + mrow) * F1 + quad * 8;
    const u16* bbase_hi = bhi + lane * 8;
    const u16* bbase_lo = blo + lane * 8;
    f32x4 acc[8];
#pragma unroll
    for (int nt = 0; nt < 8; ++nt) acc[nt] = (f32x4){0.f, 0.f, 0.f, 0.f};

    bf16x8 bh0[8], bl0[8], bh1[8], bl1[8];
    bf16x8 af0, af1;
    af0 = *(const bf16x8*)(aptr);
#pragma unroll
    for (int nt = 0; nt < 8; ++nt) {
        bh0[nt] = *(const bf16x8*)(bbase_hi + nt * 8192);
        bl0[nt] = *(const bf16x8*)(bbase_lo + nt * 8192);
    }
#pragma unroll
    for (int ks = 0; ks < 16; ++ks) {
        if (ks < 15) {
            af1 = *(const bf16x8*)(aptr + (ks + 1) * 32);
#pragma unroll
            for (int nt = 0; nt < 8; ++nt) {
                bh1[nt] = *(const bf16x8*)(bbase_hi + nt * 8192 + (ks + 1) * 512);
                bl1[nt] = *(const bf16x8*)(bbase_lo + nt * 8192 + (ks + 1) * 512);
            }
        }
#pragma unroll
        for (int nt = 0; nt < 8; ++nt) {
            acc[nt] = __builtin_amdgcn_mfma_f32_16x16x32_bf16(af0, bh0[nt], acc[nt], 0, 0, 0);
            acc[nt] = __builtin_amdgcn_mfma_f32_16x16x32_bf16(af0, bl0[nt], acc[nt], 0, 0, 0);
        }
        af0 = af1;
#pragma unroll
        for (int nt = 0; nt < 8; ++nt) { bh0[nt] = bh1[nt]; bl0[nt] = bl1[nt]; }
    }
    // C layout: col = nt*16 + mrow, row = quad*4 + r   (m89-verified)
    float ps[4] = {0.f, 0.f, 0.f, 0.f}, pd[4] = {0.f, 0.f, 0.f, 0.f};
#pragma unroll
    for (int nt = 0; nt < 8; ++nt) {
        int col = nt * 16 + mrow;
        float sa = as2[col], da = ad2[col];
#pragma unroll
        for (int r = 0; r < 4; ++r) {
            float v = acc[nt][r];
            xh2[(size_t)(n0 + quad * 4 + r) * HIDD + col] = f2bf(v);
            ps[r] += v * sa; pd[r] += v * da;
        }
    }
#pragma unroll
    for (int r = 0; r < 4; ++r) {
#pragma unroll
        for (int o = 1; o <= 8; o <<= 1) {
            ps[r] += __shfl_xor(ps[r], o, 64);
            pd[r] += __shfl_xor(pd[r], o, 64);
        }
        if (mrow == 0) {
            aS2[n0 + quad * 4 + r] = ps[r];
            aD2[n0 + quad * 4 + r] = pd[r];
        }
    }
}

// ---------------- layer 2: per-edge scores (all-sequential reads) ----------------
__global__ void k_score2(const int* __restrict__ ssrc, const int* __restrict__ sdst,
                         const float* __restrict__ et2s,
                         const float* __restrict__ aS2, const float* __restrict__ aD2,
                         float* __restrict__ alpha2) {
    int i = blockIdx.x * blockDim.x + threadIdx.x;
    if (i >= EE2) return;
    float t0 = aS2[ssrc[i]] + aD2[sdst[i]] + et2s[i];
    alpha2[i] = t0 > 0.f ? t0 : 0.2f * t0;
}

// ---------------- layer 2: softmax + aggregate + FC + sigmoid (fused final) ------
__global__ void __launch_bounds__(64) k_agg2(const int* __restrict__ row_off,
                                             const int* __restrict__ ssrc,
                                             const float* __restrict__ alpha2,
                                             const u16* __restrict__ xh2,
                                             const float* __restrict__ bias2,
                                             const float* __restrict__ Wfc,
                                             const float* __restrict__ bfc,
                                             float* __restrict__ out) {
    int n = blockIdx.x, t = threadIdx.x;
    int s0 = row_off[n], s1 = row_off[n + 1];
    float m = -1e30f;
    for (int i = s0 + t; i < s1; i += 64) m = fmaxf(m, alpha2[i]);
    m = wmaxr(m);
    float z = 0.f;
    for (int i = s0 + t; i < s1; i += 64) z += __expf(alpha2[i] - m);
    z = wsum(z);
    float inv = 1.f / (z + 1e-16f);
    int c0 = t * 2;
    float a0 = 0.f, a1 = 0.f;
    for (int i = s0; i < s1; ++i) {
        float w = __expf(alpha2[i] - m) * inv;
        u32 q = *(const u32*)(xh2 + (size_t)ssrc[i] * HIDD + c0);   // 2 bf16
        a0 += w * bf2f((u16)(q & 0xFFFF));
        a1 += w * bf2f((u16)(q >> 16));
    }
    float o0 = fmaxf(a0 + bias2[c0], 0.f);
    float o1 = fmaxf(a1 + bias2[c0 + 1], 0.f);
    float p = o0 * Wfc[c0] + o1 * Wfc[c0 + 1];
    p = wsum(p);
    if (t == 0) {
        float logit = p + bfc[0];
        out[n] = 1.f / (1.f + __expf(-logit));
    }
}

extern "C" void kernel_launch(void* const* d_in, const int* in_sizes, int n_in,
                              void* d_out, int out_size, void* d_ws, size_t ws_size,
                              hipStream_t stream) {
    (void)in_sizes; (void)n_in; (void)out_size; (void)ws_size;
    const float* x   = (const float*)d_in[0];
    const int*   ei  = (const int*)d_in[1];
    const float* ea  = (const float*)d_in[2];
    const float* W1  = (const float*)d_in[3];
    const float* We1 = (const float*)d_in[4];
    const float* as1 = (const float*)d_in[5];
    const float* ad1 = (const float*)d_in[6];
    const float* ae1 = (const float*)d_in[7];
    const float* b1  = (const float*)d_in[8];
    const float* W2  = (const float*)d_in[9];
    const float* We2 = (const float*)d_in[10];
    const float* as2 = (const float*)d_in[11];
    const float* ad2 = (const float*)d_in[12];
    const float* ae2 = (const float*)d_in[13];
    const float* b2v = (const float*)d_in[14];
    const float* Wfc = (const float*)d_in[15];
    const float* bfc = (const float*)d_in[16];
    float* out = (float*)d_out;

    char* ws = (char*)d_ws;
    size_t off = 0;
    auto take = [&](size_t nb) {
        size_t r = off;
        off += (nb + 255) & ~(size_t)255;
        return r;
    };
    float* consts = (float*)(ws + take(1024));
    int* row_off  = (int*)(ws + take((size_t)(NN + 1) * 4));
    int* cursor   = (int*)(ws + take((size_t)NN * 4));
    int* local_ex = (int*)(ws + take((size_t)NN * 4));
    int* bsum     = (int*)(ws + take(1024));
    int* boff     = (int*)(ws + take(1024));
    int* invp     = (int*)(ws + take((size_t)EE2 * 4));
    int* ssrc     = (int*)(ws + take((size_t)EE2 * 4));
    int* sdst     = (int*)(ws + take((size_t)EE2 * 4));
    float* alpha1 = (float*)(ws + take((size_t)EE2 * 16));
    float* alpha2 = (float*)(ws + take((size_t)EE2 * 4));
    float* et2s   = (float*)(ws + take((size_t)EE2 * 4));
    float* aS1    = (float*)(ws + take((size_t)NN * 16));
    float* aD1    = (float*)(ws + take((size_t)NN * 16));
    float* aS2    = (float*)(ws + take((size_t)NN * 4));
    float* aD2    = (float*)(ws + take((size_t)NN * 4));
    u16* h1       = (u16*)(ws + take((size_t)NN * F1 * 2));
    u16* xh2      = (u16*)(ws + take((size_t)NN * HIDD * 2));
    u16* w2hi     = (u16*)(ws + take((size_t)65536 * 2));
    u16* w2lo     = (u16*)(ws + take((size_t)65536 * 2));

    k_init<<<(NN + 255) / 256, 256, 0, stream>>>(consts, cursor);
    k_constsA<<<1, 64, 0, stream>>>(consts, We1, ae1, We2, ae2);
    k_wswz<<<32, 256, 0, stream>>>(W2, w2hi, w2lo);
    k_count<<<(EE2 + 255) / 256, 256, 0, stream>>>(ei, cursor);
    k_scanA<<<SGRID, SBLK, 0, stream>>>(cursor, local_ex, bsum);
    k_scanB<<<1, SBLK, 0, stream>>>(bsum, boff);
    k_scanC<<<SGRID, SBLK, 0, stream>>>(local_ex, boff, row_off, cursor);
    k_scatter<<<(EE2 + 255) / 256, 256, 0, stream>>>(ei, cursor, ssrc, sdst, invp);

    k_eterm<<<EE / 1024, 256, 0, stream>>>(ea, consts, invp, alpha1, et2s);
    k_constsB<<<1, 64, 0, stream>>>(consts);
    k_selffill<<<(NN + 255) / 256, 256, 0, stream>>>(invp, consts, alpha1, et2s);

    k_xh1<<<NN, 64, 0, stream>>>(x, W1, as1, ad1, aS1, aD1);
    k_score1<<<(EE2 + 255) / 256, 256, 0, stream>>>(ssrc, sdst, aS1, aD1, alpha1);
    k_agg1<<<NN, 64, 0, stream>>>(row_off, ssrc, alpha1, x, W1, b1, h1);

    k_gemm2<<<625, 256, 0, stream>>>(h1, w2hi, w2lo, as2, ad2, xh2, aS2, aD2);
    k_score2<<<(EE2 + 255) / 256, 256, 0, stream>>>(ssrc, sdst, et2s, aS2, aD2, alpha2);
    k_agg2<<<NN, 64, 0, stream>>>(row_off, ssrc, alpha2, xh2, b2v, Wfc, bfc, out);
}

// Round 9
// 330.204 us; speedup vs baseline: 2.3788x; 1.0536x over previous
//
#include <hip/hip_runtime.h>

#define NN   40000
#define EE   640000
#define EE2  680000    // EE + NN self loops
#define IND  5
#define ED   11
#define HIDD 128
#define F1   512       // 4 heads * 128

typedef unsigned short u16;
typedef unsigned int   u32;
typedef __attribute__((ext_vector_type(8))) short bf16x8;
typedef __attribute__((ext_vector_type(4))) float f32x4;

__device__ __forceinline__ float bf2f(u16 u) { return __uint_as_float(((u32)u) << 16); }
__device__ __forceinline__ u16 f2bf(float f) {
    u32 u = __float_as_uint(f);
    return (u16)((u + 0x7FFFu + ((u >> 16) & 1u)) >> 16);   // RNE
}

__device__ __forceinline__ float wsum(float v) {
#pragma unroll
    for (int o = 32; o; o >>= 1) v += __shfl_xor(v, o, 64);
    return v;
}
__device__ __forceinline__ float wmaxr(float v) {
#pragma unroll
    for (int o = 32; o; o >>= 1) v = fmaxf(v, __shfl_xor(v, o, 64));
    return v;
}

// ---------------- init: zero consts + per-dst counters ----------------
__global__ void k_init(float* __restrict__ consts, int* __restrict__ cursor) {
    int i = blockIdx.x * blockDim.x + threadIdx.x;
    if (i < 256) consts[i] = 0.f;
    if (i < NN) cursor[i] = 0;
}

// consts layout (floats): [0..10] ea col-sums -> means, [16..59] Be1[k*4+h],
//                         [64..74] Be2[k], [80..83] self1[h], [96] self2
__global__ void k_constsA(float* __restrict__ consts,
                          const float* __restrict__ We1, const float* __restrict__ ae1,
                          const float* __restrict__ We2, const float* __restrict__ ae2) {
    int t = threadIdx.x;  // 64 threads
    if (t < 44) {
        int k = t >> 2, h = t & 3;
        float s = 0.f;
        for (int c = 0; c < HIDD; ++c)
            s += We1[k * F1 + h * HIDD + c] * ae1[h * HIDD + c];
        consts[16 + t] = s;
    }
    if (t >= 48 && t < 48 + ED) {
        int k = t - 48;
        float s = 0.f;
        for (int c = 0; c < HIDD; ++c)
            s += We2[k * HIDD + c] * ae2[c];
        consts[64 + k] = s;
    }
}

__global__ void k_constsB(float* __restrict__ consts) {
    int t = threadIdx.x;  // 64 threads
    if (t < ED) consts[t] *= (1.0f / (float)EE);
    __syncthreads();
    if (t < 4) {
        float s = 0.f;
        for (int k = 0; k < ED; ++k) s += consts[k] * consts[16 + k * 4 + t];
        consts[80 + t] = s;
    }
    if (t == 8) {
        float s = 0.f;
        for (int k = 0; k < ED; ++k) s += consts[k] * consts[64 + k];
        consts[96] = s;
    }
}

// ---------------- W2 pre-swizzle into MFMA B-fragment order, split hi/lo bf16 ----
__global__ void k_wswz(const float* __restrict__ W2,
                       u16* __restrict__ bhi, u16* __restrict__ blo) {
    int t = blockIdx.x * blockDim.x + threadIdx.x;   // 8192 = 8nt * 16ks * 64lane
    if (t >= 8192) return;
    int lane = t & 63, ks = (t >> 6) & 15, nt = t >> 10;
    int kbase = ks * 32 + (lane >> 4) * 8;
    int n = nt * 16 + (lane & 15);
    size_t dst = (size_t)t * 8;
#pragma unroll
    for (int j = 0; j < 8; ++j) {
        float v = W2[(size_t)(kbase + j) * HIDD + n];
        u16 h = f2bf(v);
        float resid = v - bf2f(h);
        bhi[dst + j] = h;
        blo[dst + j] = f2bf(resid);
    }
}

// ---------------- CSR build (sorted by dst), shared by both layers ----------------
__global__ void k_count(const int* __restrict__ ei, int* __restrict__ counts) {
    int i = blockIdx.x * blockDim.x + threadIdx.x;
    if (i >= EE2) return;
    int dst = (i < EE) ? ei[EE + i] : (i - EE);
    atomicAdd(&counts[dst], 1);
}

// 3-phase hierarchical exclusive scan of counts[NN] -> row_off/cursor
#define SBLK 256
#define SGRID ((NN + SBLK - 1) / SBLK)   // 157
__global__ void __launch_bounds__(SBLK) k_scanA(const int* __restrict__ counts,
                                                int* __restrict__ local_ex,
                                                int* __restrict__ bsum) {
    __shared__ int sh[SBLK];
    int t = threadIdx.x;
    int i = blockIdx.x * SBLK + t;
    int v = (i < NN) ? counts[i] : 0;
    sh[t] = v;
    __syncthreads();
    for (int o = 1; o < SBLK; o <<= 1) {
        int u = (t >= o) ? sh[t - o] : 0;
        __syncthreads();
        sh[t] += u;
        __syncthreads();
    }
    if (i < NN) local_ex[i] = sh[t] - v;
    if (t == SBLK - 1) bsum[blockIdx.x] = sh[t];
}

__global__ void __launch_bounds__(SBLK) k_scanB(int* __restrict__ bsum,
                                                int* __restrict__ boff) {
    __shared__ int sh[SBLK];
    int t = threadIdx.x;
    int v = (t < SGRID) ? bsum[t] : 0;
    sh[t] = v;
    __syncthreads();
    for (int o = 1; o < SBLK; o <<= 1) {
        int u = (t >= o) ? sh[t - o] : 0;
        __syncthreads();
        sh[t] += u;
        __syncthreads();
    }
    if (t < SGRID) boff[t] = sh[t] - v;
}

__global__ void __launch_bounds__(SBLK) k_scanC(const int* __restrict__ local_ex,
                                                const int* __restrict__ boff,
                                                int* __restrict__ row_off,
                                                int* __restrict__ cur) {
    int t = threadIdx.x;
    int i = blockIdx.x * SBLK + t;
    if (i < NN) {
        int v = local_ex[i] + boff[blockIdx.x];
        row_off[i] = v;
        cur[i] = v;
    }
    if (i == 0) row_off[NN] = EE2;
}

__global__ void k_scatter(const int* __restrict__ ei, int* __restrict__ cur,
                          int* __restrict__ ssrc, int* __restrict__ sdst,
                          int* __restrict__ invp) {
    int i = blockIdx.x * blockDim.x + threadIdx.x;
    if (i >= EE2) return;
    int s, d;
    if (i < EE) { s = ei[i]; d = ei[EE + i]; }
    else        { s = d = i - EE; }
    int pos = atomicAdd(&cur[d], 1);
    ssrc[pos] = s;
    sdst[pos] = d;
    invp[i] = pos;     // sequential write (i natural order)
}

// ---------------- fused ea pass: edge terms (scattered to sorted pos) + col sums --
__global__ void __launch_bounds__(256) k_eterm(const float* __restrict__ ea,
                                               float* consts,
                                               const int* __restrict__ invp,
                                               float* __restrict__ alpha1,
                                               float* __restrict__ et2s) {
    __shared__ float sh[11264];          // 1024 rows * 11 cols, 44 KB
    int t = threadIdx.x, b = blockIdx.x;
    size_t gbase = (size_t)b * 11264;
#pragma unroll
    for (int j = 0; j < 11; ++j) {
        float4 v = *(const float4*)(ea + gbase + j * 1024 + t * 4);
        *(float4*)(sh + j * 1024 + t * 4) = v;
    }
    // Be consts into registers (wave-uniform)
    float Bx[ED], By[ED], Bz[ED], Bw[ED], Bt[ED];
#pragma unroll
    for (int k = 0; k < ED; ++k) {
        Bx[k] = consts[16 + k * 4 + 0];
        By[k] = consts[16 + k * 4 + 1];
        Bz[k] = consts[16 + k * 4 + 2];
        Bw[k] = consts[16 + k * 4 + 3];
        Bt[k] = consts[64 + k];
    }
    int4 ip = *(const int4*)(invp + b * 1024 + t * 4);
    float cs[ED];
#pragma unroll
    for (int k = 0; k < ED; ++k) cs[k] = 0.f;
    __syncthreads();
#pragma unroll
    for (int rr = 0; rr < 4; ++rr) {
        const float* row = sh + t * 44 + rr * 11;
        float e0 = 0.f, e1 = 0.f, e2 = 0.f, e3 = 0.f, et = 0.f;
#pragma unroll
        for (int k = 0; k < ED; ++k) {
            float a = row[k];
            cs[k] += a;
            e0 += a * Bx[k]; e1 += a * By[k]; e2 += a * Bz[k]; e3 += a * Bw[k];
            et += a * Bt[k];
        }
        int pos = (rr == 0) ? ip.x : (rr == 1) ? ip.y : (rr == 2) ? ip.z : ip.w;
        *(float4*)(alpha1 + (size_t)pos * 4) = make_float4(e0, e1, e2, e3);
        et2s[pos] = et;
    }
    __syncthreads();                      // done with staging; reuse sh for reduce
#pragma unroll
    for (int k = 0; k < ED; ++k) cs[k] = wsum(cs[k]);
    int wv = t >> 6;
    if ((t & 63) == 0) {
#pragma unroll
        for (int k = 0; k < ED; ++k) sh[wv * ED + k] = cs[k];
    }
    __syncthreads();
    if (t < ED)
        atomicAdd(&consts[t], sh[t] + sh[ED + t] + sh[2 * ED + t] + sh[3 * ED + t]);
}

// ---------------- self-loop slots: e-terms from mean attr ----------------
__global__ void k_selffill(const int* __restrict__ invp,
                           const float* __restrict__ consts,
                           float* __restrict__ alpha1, float* __restrict__ et2s) {
    int n = blockIdx.x * blockDim.x + threadIdx.x;
    if (n >= NN) return;
    int pos = invp[EE + n];
    *(float4*)(alpha1 + (size_t)pos * 4) =
        make_float4(consts[80], consts[81], consts[82], consts[83]);
    et2s[pos] = consts[96];
}

// ---------------- layer 1: a_src/a_dst dots only (xh1 never materialized) --------
__global__ void __launch_bounds__(64) k_xh1(const float* __restrict__ x,
                                            const float* __restrict__ W1,
                                            const float* __restrict__ as1,
                                            const float* __restrict__ ad1,
                                            float* __restrict__ aS1,
                                            float* __restrict__ aD1) {
    int n = blockIdx.x, t = threadIdx.x;
    int c0 = t * 8, h = t >> 4;
    const float* xp = x + (size_t)n * IND;
    float x0 = xp[0], x1 = xp[1], x2 = xp[2], x3 = xp[3], x4 = xp[4];
    float p = 0.f, q = 0.f;
#pragma unroll
    for (int j = 0; j < 8; ++j) {
        int c = c0 + j;
        float v = x0 * W1[0 * F1 + c] + x1 * W1[1 * F1 + c] + x2 * W1[2 * F1 + c]
                + x3 * W1[3 * F1 + c] + x4 * W1[4 * F1 + c];
        p += v * as1[c];
        q += v * ad1[c];
    }
#pragma unroll
    for (int o = 1; o <= 8; o <<= 1) {     // reduce within 16-lane head group
        p += __shfl_xor(p, o, 64);
        q += __shfl_xor(q, o, 64);
    }
    if ((t & 15) == 0) {
        aS1[n * 4 + h] = p;
        aD1[n * 4 + h] = q;
    }
}

// ---------------- layer 1 scores: in-place alpha1 += src/dst terms, leaky --------
__global__ void k_score1(const int* __restrict__ ssrc, const int* __restrict__ sdst,
                         const float* __restrict__ aS1, const float* __restrict__ aD1,
                         float* __restrict__ alpha1) {
    int i = blockIdx.x * blockDim.x + threadIdx.x;
    if (i >= EE2) return;
    int s = ssrc[i], d = sdst[i];
    float4 ev = *(const float4*)(alpha1 + (size_t)i * 4);
    float4 vs = *(const float4*)(aS1 + (size_t)s * 4);
    float4 vd = *(const float4*)(aD1 + (size_t)d * 4);
    float t0 = vs.x + vd.x + ev.x, t1 = vs.y + vd.y + ev.y;
    float t2 = vs.z + vd.z + ev.z, t3 = vs.w + vd.w + ev.w;
    t0 = t0 > 0.f ? t0 : 0.2f * t0;
    t1 = t1 > 0.f ? t1 : 0.2f * t1;
    t2 = t2 > 0.f ? t2 : 0.2f * t2;
    t3 = t3 > 0.f ? t3 : 0.2f * t3;
    *(float4*)(alpha1 + (size_t)i * 4) = make_float4(t0, t1, t2, t3);
}

// ---------------- layer 1 aggregate: edge-parallel softmax + 5-dim aggregation ----
__global__ void __launch_bounds__(64) k_agg1(const int* __restrict__ row_off,
                                             const int* __restrict__ ssrc,
                                             const float* __restrict__ alpha1,
                                             const float* __restrict__ x,
                                             const float* __restrict__ W1,
                                             const float* __restrict__ b1,
                                             u16* __restrict__ h1) {
    int n = blockIdx.x, t = threadIdx.x;
    int s0 = row_off[n], s1 = row_off[n + 1];
    // pass 1: per-head max (strided float4, all 64 lanes)
    float m0 = -1e30f, m1 = -1e30f, m2 = -1e30f, m3 = -1e30f;
    for (int i = s0 + t; i < s1; i += 64) {
        float4 a = *(const float4*)(alpha1 + (size_t)i * 4);
        m0 = fmaxf(m0, a.x); m1 = fmaxf(m1, a.y);
        m2 = fmaxf(m2, a.z); m3 = fmaxf(m3, a.w);
    }
    m0 = wmaxr(m0); m1 = wmaxr(m1); m2 = wmaxr(m2); m3 = wmaxr(m3);
    // pass 2 (fused exp-sum + x-aggregation), edge-parallel
    int h = t & 3;
    float mh = (h == 0) ? m0 : (h == 1) ? m1 : (h == 2) ? m2 : m3;
    float z = 0.f, xa0 = 0.f, xa1 = 0.f, xa2 = 0.f, xa3 = 0.f, xa4 = 0.f;
    for (int i = s0 + (t >> 2); i < s1; i += 16) {
        float ex = __expf(alpha1[(size_t)i * 4 + h] - mh);
        z += ex;
        const float* xp = x + (size_t)ssrc[i] * IND;
        xa0 += ex * xp[0]; xa1 += ex * xp[1]; xa2 += ex * xp[2];
        xa3 += ex * xp[3]; xa4 += ex * xp[4];
    }
#pragma unroll
    for (int o = 4; o <= 32; o <<= 1) {    // reduce 16 lanes sharing h
        z   += __shfl_xor(z, o, 64);
        xa0 += __shfl_xor(xa0, o, 64); xa1 += __shfl_xor(xa1, o, 64);
        xa2 += __shfl_xor(xa2, o, 64); xa3 += __shfl_xor(xa3, o, 64);
        xa4 += __shfl_xor(xa4, o, 64);
    }
    // redistribute: output head ho = t>>4; lane ho holds head ho's totals (ho&3==ho)
    int ho = t >> 4;
    float zz = __shfl(z, ho);
    float y0 = __shfl(xa0, ho), y1 = __shfl(xa1, ho), y2 = __shfl(xa2, ho);
    float y3 = __shfl(xa3, ho), y4 = __shfl(xa4, ho);
    float ih = 1.f / (zz + 1e-16f);
    int c0 = t * 8;
#pragma unroll
    for (int j = 0; j < 8; ++j) {
        int c = c0 + j;
        float v = (y0 * W1[0 * F1 + c] + y1 * W1[1 * F1 + c] + y2 * W1[2 * F1 + c]
                 + y3 * W1[3 * F1 + c] + y4 * W1[4 * F1 + c]) * ih;
        h1[(size_t)n * F1 + c] = f2bf(fmaxf(v + b1[c], 0.f));
    }
}

// ---------------- layer 2 GEMM (MFMA): xh2(bf16) = h1(bf16) @ W2, fused sd2 ------
__global__ void __launch_bounds__(256, 2) k_gemm2(const u16* __restrict__ h1,
                                                  const u16* __restrict__ bhi,
                                                  const u16* __restrict__ blo,
                                                  const float* __restrict__ as2,
                                                  const float* __restrict__ ad2,
                                                  u16* __restrict__ xh2,
                                                  float* __restrict__ aS2,
                                                  float* __restrict__ aD2) {
    int tid = threadIdx.x;
    int wv = tid >> 6, lane = tid & 63;
    int tile = blockIdx.x * 4 + wv;
    if (tile >= 2500) return;
    int n0 = tile * 16;
    int mrow = lane & 15, quad = lane >> 4;
    const u16* aptr = h1 + (size_t)(n0 + mrow) * F1 + quad * 8;
    const u16* bbase_hi = bhi + lane * 8;
    const u16* bbase_lo = blo + lane * 8;
    f32x4 acc[8];
#pragma unroll
    for (int nt = 0; nt < 8; ++nt) acc[nt] = (f32x4){0.f, 0.f, 0.f, 0.f};

    bf16x8 bh0[8], bl0[8], bh1[8], bl1[8];
    bf16x8 af0, af1;
    af0 = *(const bf16x8*)(aptr);
#pragma unroll
    for (int nt = 0; nt < 8; ++nt) {
        bh0[nt] = *(const bf16x8*)(bbase_hi + nt * 8192);
        bl0[nt] = *(const bf16x8*)(bbase_lo + nt * 8192);
    }
#pragma unroll
    for (int ks = 0; ks < 16; ++ks) {
        if (ks < 15) {
            af1 = *(const bf16x8*)(aptr + (ks + 1) * 32);
#pragma unroll
            for (int nt = 0; nt < 8; ++nt) {
                bh1[nt] = *(const bf16x8*)(bbase_hi + nt * 8192 + (ks + 1) * 512);
                bl1[nt] = *(const bf16x8*)(bbase_lo + nt * 8192 + (ks + 1) * 512);
            }
        }
#pragma unroll
        for (int nt = 0; nt < 8; ++nt) {
            acc[nt] = __builtin_amdgcn_mfma_f32_16x16x32_bf16(af0, bh0[nt], acc[nt], 0, 0, 0);
            acc[nt] = __builtin_amdgcn_mfma_f32_16x16x32_bf16(af0, bl0[nt], acc[nt], 0, 0, 0);
        }
        af0 = af1;
#pragma unroll
        for (int nt = 0; nt < 8; ++nt) { bh0[nt] = bh1[nt]; bl0[nt] = bl1[nt]; }
    }
    // C layout: col = nt*16 + mrow, row = quad*4 + r   (m89-verified)
    float ps[4] = {0.f, 0.f, 0.f, 0.f}, pd[4] = {0.f, 0.f, 0.f, 0.f};
#pragma unroll
    for (int nt = 0; nt < 8; ++nt) {
        int col = nt * 16 + mrow;
        float sa = as2[col], da = ad2[col];
#pragma unroll
        for (int r = 0; r < 4; ++r) {
            float v = acc[nt][r];
            xh2[(size_t)(n0 + quad * 4 + r) * HIDD + col] = f2bf(v);
            ps[r] += v * sa; pd[r] += v * da;
        }
    }
#pragma unroll
    for (int r = 0; r < 4; ++r) {
#pragma unroll
        for (int o = 1; o <= 8; o <<= 1) {
            ps[r] += __shfl_xor(ps[r], o, 64);
            pd[r] += __shfl_xor(pd[r], o, 64);
        }
        if (mrow == 0) {
            aS2[n0 + quad * 4 + r] = ps[r];
            aD2[n0 + quad * 4 + r] = pd[r];
        }
    }
}

// ---------------- layer 2: per-edge scores (all-sequential reads) ----------------
__global__ void k_score2(const int* __restrict__ ssrc, const int* __restrict__ sdst,
                         const float* __restrict__ et2s,
                         const float* __restrict__ aS2, const float* __restrict__ aD2,
                         float* __restrict__ alpha2) {
    int i = blockIdx.x * blockDim.x + threadIdx.x;
    if (i >= EE2) return;
    float t0 = aS2[ssrc[i]] + aD2[sdst[i]] + et2s[i];
    alpha2[i] = t0 > 0.f ? t0 : 0.2f * t0;
}

// ---------------- layer 2: edge-parallel softmax + aggregate + FC + sigmoid ------
// Lane t = 16*g + l: subgroup g handles edges s0+g step 4; lane covers cols
// l*8..l*8+7 via one uint4 (8 bf16, 16B). 4 row-gathers in flight per iter.
// (Round-8 version iterated edges serially: 1 row / 1 exp per iter, 50 us.)
__global__ void __launch_bounds__(64) k_agg2(const int* __restrict__ row_off,
                                             const int* __restrict__ ssrc,
                                             const float* __restrict__ alpha2,
                                             const u16* __restrict__ xh2,
                                             const float* __restrict__ bias2,
                                             const float* __restrict__ Wfc,
                                             const float* __restrict__ bfc,
                                             float* __restrict__ out) {
    int n = blockIdx.x, t = threadIdx.x;
    int s0 = row_off[n], s1 = row_off[n + 1];
    float m = -1e30f;
    for (int i = s0 + t; i < s1; i += 64) m = fmaxf(m, alpha2[i]);
    m = wmaxr(m);
    float z = 0.f;
    for (int i = s0 + t; i < s1; i += 64) z += __expf(alpha2[i] - m);
    z = wsum(z);
    float inv = 1.f / (z + 1e-16f);
    int g = t >> 4, l = t & 15;
    int c0 = l * 8;
    float acc[8];
#pragma unroll
    for (int j = 0; j < 8; ++j) acc[j] = 0.f;
    for (int i = s0 + g; i < s1; i += 4) {
        float w = __expf(alpha2[i] - m) * inv;
        uint4 q = *(const uint4*)(xh2 + (size_t)ssrc[i] * HIDD + c0);   // 8 bf16
        acc[0] += w * bf2f((u16)(q.x & 0xFFFF)); acc[1] += w * bf2f((u16)(q.x >> 16));
        acc[2] += w * bf2f((u16)(q.y & 0xFFFF)); acc[3] += w * bf2f((u16)(q.y >> 16));
        acc[4] += w * bf2f((u16)(q.z & 0xFFFF)); acc[5] += w * bf2f((u16)(q.z >> 16));
        acc[6] += w * bf2f((u16)(q.w & 0xFFFF)); acc[7] += w * bf2f((u16)(q.w >> 16));
    }
    // reduce across the 4 edge subgroups (lanes differing in bits 4,5)
#pragma unroll
    for (int o = 16; o <= 32; o <<= 1) {
#pragma unroll
        for (int j = 0; j < 8; ++j) acc[j] += __shfl_xor(acc[j], o, 64);
    }
    // bias + relu + FC partial over this lane's 8 cols
    float p = 0.f;
#pragma unroll
    for (int j = 0; j < 8; ++j) {
        float o = fmaxf(acc[j] + bias2[c0 + j], 0.f);
        p += o * Wfc[c0 + j];
    }
#pragma unroll
    for (int o = 1; o <= 8; o <<= 1) p += __shfl_xor(p, o, 64);
    if (t == 0) {
        float logit = p + bfc[0];
        out[n] = 1.f / (1.f + __expf(-logit));
    }
}

extern "C" void kernel_launch(void* const* d_in, const int* in_sizes, int n_in,
                              void* d_out, int out_size, void* d_ws, size_t ws_size,
                              hipStream_t stream) {
    (void)in_sizes; (void)n_in; (void)out_size; (void)ws_size;
    const float* x   = (const float*)d_in[0];
    const int*   ei  = (const int*)d_in[1];
    const float* ea  = (const float*)d_in[2];
    const float* W1  = (const float*)d_in[3];
    const float* We1 = (const float*)d_in[4];
    const float* as1 = (const float*)d_in[5];
    const float* ad1 = (const float*)d_in[6];
    const float* ae1 = (const float*)d_in[7];
    const float* b1  = (const float*)d_in[8];
    const float* W2  = (const float*)d_in[9];
    const float* We2 = (const float*)d_in[10];
    const float* as2 = (const float*)d_in[11];
    const float* ad2 = (const float*)d_in[12];
    const float* ae2 = (const float*)d_in[13];
    const float* b2v = (const float*)d_in[14];
    const float* Wfc = (const float*)d_in[15];
    const float* bfc = (const float*)d_in[16];
    float* out = (float*)d_out;

    char* ws = (char*)d_ws;
    size_t off = 0;
    auto take = [&](size_t nb) {
        size_t r = off;
        off += (nb + 255) & ~(size_t)255;
        return r;
    };
    float* consts = (float*)(ws + take(1024));
    int* row_off  = (int*)(ws + take((size_t)(NN + 1) * 4));
    int* cursor   = (int*)(ws + take((size_t)NN * 4));
    int* local_ex = (int*)(ws + take((size_t)NN * 4));
    int* bsum     = (int*)(ws + take(1024));
    int* boff     = (int*)(ws + take(1024));
    int* invp     = (int*)(ws + take((size_t)EE2 * 4));
    int* ssrc     = (int*)(ws + take((size_t)EE2 * 4));
    int* sdst     = (int*)(ws + take((size_t)EE2 * 4));
    float* alpha1 = (float*)(ws + take((size_t)EE2 * 16));
    float* alpha2 = (float*)(ws + take((size_t)EE2 * 4));
    float* et2s   = (float*)(ws + take((size_t)EE2 * 4));
    float* aS1    = (float*)(ws + take((size_t)NN * 16));
    float* aD1    = (float*)(ws + take((size_t)NN * 16));
    float* aS2    = (float*)(ws + take((size_t)NN * 4));
    float* aD2    = (float*)(ws + take((size_t)NN * 4));
    u16* h1       = (u16*)(ws + take((size_t)NN * F1 * 2));
    u16* xh2      = (u16*)(ws + take((size_t)NN * HIDD * 2));
    u16* w2hi     = (u16*)(ws + take((size_t)65536 * 2));
    u16* w2lo     = (u16*)(ws + take((size_t)65536 * 2));

    k_init<<<(NN + 255) / 256, 256, 0, stream>>>(consts, cursor);
    k_constsA<<<1, 64, 0, stream>>>(consts, We1, ae1, We2, ae2);
    k_wswz<<<32, 256, 0, stream>>>(W2, w2hi, w2lo);
    k_count<<<(EE2 + 255) / 256, 256, 0, stream>>>(ei, cursor);
    k_scanA<<<SGRID, SBLK, 0, stream>>>(cursor, local_ex, bsum);
    k_scanB<<<1, SBLK, 0, stream>>>(bsum, boff);
    k_scanC<<<SGRID, SBLK, 0, stream>>>(local_ex, boff, row_off, cursor);
    k_scatter<<<(EE2 + 255) / 256, 256, 0, stream>>>(ei, cursor, ssrc, sdst, invp);

    k_eterm<<<EE / 1024, 256, 0, stream>>>(ea, consts, invp, alpha1, et2s);
    k_constsB<<<1, 64, 0, stream>>>(consts);
    k_selffill<<<(NN + 255) / 256, 256, 0, stream>>>(invp, consts, alpha1, et2s);

    k_xh1<<<NN, 64, 0, stream>>>(x, W1, as1, ad1, aS1, aD1);
    k_score1<<<(EE2 + 255) / 256, 256, 0, stream>>>(ssrc, sdst, aS1, aD1, alpha1);
    k_agg1<<<NN, 64, 0, stream>>>(row_off, ssrc, alpha1, x, W1, b1, h1);

    k_gemm2<<<625, 256, 0, stream>>>(h1, w2hi, w2lo, as2, ad2, xh2, aS2, aD2);
    k_score2<<<(EE2 + 255) / 256, 256, 0, stream>>>(ssrc, sdst, et2s, aS2, aD2, alpha2);
    k_agg2<<<NN, 64, 0, stream>>>(row_off, ssrc, alpha2, xh2, b2v, Wfc, bfc, out);
}

// Round 10
// 313.917 us; speedup vs baseline: 2.5022x; 1.0519x over previous
//
#include <hip/hip_runtime.h>

#define NN   40000
#define EE   640000
#define EE2  680000    // EE + NN self loops
#define IND  5
#define ED   11
#define HIDD 128
#define F1   512       // 4 heads * 128

typedef unsigned short u16;
typedef unsigned int   u32;
typedef __attribute__((ext_vector_type(8))) short bf16x8;
typedef __attribute__((ext_vector_type(4))) float f32x4;

__device__ __forceinline__ float bf2f(u16 u) { return __uint_as_float(((u32)u) << 16); }
__device__ __forceinline__ u16 f2bf(float f) {
    u32 u = __float_as_uint(f);
    return (u16)((u + 0x7FFFu + ((u >> 16) & 1u)) >> 16);   // RNE
}

__device__ __forceinline__ float wsum(float v) {
#pragma unroll
    for (int o = 32; o; o >>= 1) v += __shfl_xor(v, o, 64);
    return v;
}
__device__ __forceinline__ float wmaxr(float v) {
#pragma unroll
    for (int o = 32; o; o >>= 1) v = fmaxf(v, __shfl_xor(v, o, 64));
    return v;
}

// edge record (32B, float[8]): [0..3]=e-terms->alpha1, [4]=src(int), [5]=dst(int),
//                              [6]=et2, [7]=pad

// ---------------- init: zero consts + per-dst counters ----------------
__global__ void k_init(float* __restrict__ consts, int* __restrict__ cursor) {
    int i = blockIdx.x * blockDim.x + threadIdx.x;
    if (i < 256) consts[i] = 0.f;
    if (i < NN) cursor[i] = 0;
}

// consts layout (floats): [0..10] ea col-sums -> means, [16..59] Be1[k*4+h],
//                         [64..74] Be2[k], [80..83] self1[h], [96] self2
__global__ void k_constsA(float* __restrict__ consts,
                          const float* __restrict__ We1, const float* __restrict__ ae1,
                          const float* __restrict__ We2, const float* __restrict__ ae2) {
    int t = threadIdx.x;  // 64 threads
    if (t < 44) {
        int k = t >> 2, h = t & 3;
        float s = 0.f;
        for (int c = 0; c < HIDD; ++c)
            s += We1[k * F1 + h * HIDD + c] * ae1[h * HIDD + c];
        consts[16 + t] = s;
    }
    if (t >= 48 && t < 48 + ED) {
        int k = t - 48;
        float s = 0.f;
        for (int c = 0; c < HIDD; ++c)
            s += We2[k * HIDD + c] * ae2[c];
        consts[64 + k] = s;
    }
}

__global__ void k_constsB(float* __restrict__ consts) {
    int t = threadIdx.x;  // 64 threads
    if (t < ED) consts[t] *= (1.0f / (float)EE);
    __syncthreads();
    if (t < 4) {
        float s = 0.f;
        for (int k = 0; k < ED; ++k) s += consts[k] * consts[16 + k * 4 + t];
        consts[80 + t] = s;
    }
    if (t == 8) {
        float s = 0.f;
        for (int k = 0; k < ED; ++k) s += consts[k] * consts[64 + k];
        consts[96] = s;
    }
}

// ---------------- W2 pre-swizzle into MFMA B-fragment order, split hi/lo bf16 ----
__global__ void k_wswz(const float* __restrict__ W2,
                       u16* __restrict__ bhi, u16* __restrict__ blo) {
    int t = blockIdx.x * blockDim.x + threadIdx.x;   // 8192 = 8nt * 16ks * 64lane
    if (t >= 8192) return;
    int lane = t & 63, ks = (t >> 6) & 15, nt = t >> 10;
    int kbase = ks * 32 + (lane >> 4) * 8;
    int n = nt * 16 + (lane & 15);
    size_t dst = (size_t)t * 8;
#pragma unroll
    for (int j = 0; j < 8; ++j) {
        float v = W2[(size_t)(kbase + j) * HIDD + n];
        u16 h = f2bf(v);
        float resid = v - bf2f(h);
        bhi[dst + j] = h;
        blo[dst + j] = f2bf(resid);
    }
}

// ---------------- CSR build (sorted by dst), shared by both layers ----------------
__global__ void k_count(const int* __restrict__ ei, int* __restrict__ counts) {
    int i = blockIdx.x * blockDim.x + threadIdx.x;
    if (i >= EE2) return;
    int dst = (i < EE) ? ei[EE + i] : (i - EE);
    atomicAdd(&counts[dst], 1);
}

// 3-phase hierarchical exclusive scan of counts[NN] -> row_off/cursor
#define SBLK 256
#define SGRID ((NN + SBLK - 1) / SBLK)   // 157
__global__ void __launch_bounds__(SBLK) k_scanA(const int* __restrict__ counts,
                                                int* __restrict__ local_ex,
                                                int* __restrict__ bsum) {
    __shared__ int sh[SBLK];
    int t = threadIdx.x;
    int i = blockIdx.x * SBLK + t;
    int v = (i < NN) ? counts[i] : 0;
    sh[t] = v;
    __syncthreads();
    for (int o = 1; o < SBLK; o <<= 1) {
        int u = (t >= o) ? sh[t - o] : 0;
        __syncthreads();
        sh[t] += u;
        __syncthreads();
    }
    if (i < NN) local_ex[i] = sh[t] - v;
    if (t == SBLK - 1) bsum[blockIdx.x] = sh[t];
}

__global__ void __launch_bounds__(SBLK) k_scanB(int* __restrict__ bsum,
                                                int* __restrict__ boff) {
    __shared__ int sh[SBLK];
    int t = threadIdx.x;
    int v = (t < SGRID) ? bsum[t] : 0;
    sh[t] = v;
    __syncthreads();
    for (int o = 1; o < SBLK; o <<= 1) {
        int u = (t >= o) ? sh[t - o] : 0;
        __syncthreads();
        sh[t] += u;
        __syncthreads();
    }
    if (t < SGRID) boff[t] = sh[t] - v;
}

__global__ void __launch_bounds__(SBLK) k_scanC(const int* __restrict__ local_ex,
                                                const int* __restrict__ boff,
                                                int* __restrict__ row_off,
                                                int* __restrict__ cur) {
    int t = threadIdx.x;
    int i = blockIdx.x * SBLK + t;
    if (i < NN) {
        int v = local_ex[i] + boff[blockIdx.x];
        row_off[i] = v;
        cur[i] = v;
    }
    if (i == 0) row_off[NN] = EE2;
}

// ---------------- fused scatter + ea pass: full 32B record per edge + col sums ----
// 1024 rows/block (EE = 625*1024 exactly), LDS-staged float4 loads.
__global__ void __launch_bounds__(256) k_build(const float* __restrict__ ea,
                                               const int* __restrict__ ei,
                                               float* consts,
                                               int* __restrict__ cursor,
                                               float* __restrict__ rec) {
    __shared__ float sh[11264];          // 1024 rows * 11 cols, 44 KB
    int t = threadIdx.x, b = blockIdx.x;
    size_t gbase = (size_t)b * 11264;
#pragma unroll
    for (int j = 0; j < 11; ++j) {
        float4 v = *(const float4*)(ea + gbase + j * 1024 + t * 4);
        *(float4*)(sh + j * 1024 + t * 4) = v;
    }
    float Bx[ED], By[ED], Bz[ED], Bw[ED], Bt[ED];
#pragma unroll
    for (int k = 0; k < ED; ++k) {
        Bx[k] = consts[16 + k * 4 + 0];
        By[k] = consts[16 + k * 4 + 1];
        Bz[k] = consts[16 + k * 4 + 2];
        Bw[k] = consts[16 + k * 4 + 3];
        Bt[k] = consts[64 + k];
    }
    int i0 = b * 1024 + t * 4;
    int4 sv = *(const int4*)(ei + i0);        // src of 4 edges
    int4 dv = *(const int4*)(ei + EE + i0);   // dst of 4 edges
    float cs[ED];
#pragma unroll
    for (int k = 0; k < ED; ++k) cs[k] = 0.f;
    __syncthreads();
#pragma unroll
    for (int rr = 0; rr < 4; ++rr) {
        const float* row = sh + t * 44 + rr * 11;
        float e0 = 0.f, e1 = 0.f, e2 = 0.f, e3 = 0.f, et = 0.f;
#pragma unroll
        for (int k = 0; k < ED; ++k) {
            float a = row[k];
            cs[k] += a;
            e0 += a * Bx[k]; e1 += a * By[k]; e2 += a * Bz[k]; e3 += a * Bw[k];
            et += a * Bt[k];
        }
        int s = (rr == 0) ? sv.x : (rr == 1) ? sv.y : (rr == 2) ? sv.z : sv.w;
        int d = (rr == 0) ? dv.x : (rr == 1) ? dv.y : (rr == 2) ? dv.z : dv.w;
        int pos = atomicAdd(&cursor[d], 1);
        float* rp = rec + (size_t)pos * 8;
        *(float4*)rp = make_float4(e0, e1, e2, e3);
        *(float4*)(rp + 4) = make_float4(__int_as_float(s), __int_as_float(d), et, 0.f);
    }
    __syncthreads();                      // done with staging; reuse sh for reduce
#pragma unroll
    for (int k = 0; k < ED; ++k) cs[k] = wsum(cs[k]);
    int wv = t >> 6;
    if ((t & 63) == 0) {
#pragma unroll
        for (int k = 0; k < ED; ++k) sh[wv * ED + k] = cs[k];
    }
    __syncthreads();
    if (t < ED)
        atomicAdd(&consts[t], sh[t] + sh[ED + t] + sh[2 * ED + t] + sh[3 * ED + t]);
}

// ---------------- self-loop records: src/dst + remember position ----------------
__global__ void k_selfbuild(int* __restrict__ cursor, float* __restrict__ rec,
                            int* __restrict__ selfpos) {
    int n = blockIdx.x * blockDim.x + threadIdx.x;
    if (n >= NN) return;
    int pos = atomicAdd(&cursor[n], 1);
    selfpos[n] = pos;
    float* rp = rec + (size_t)pos * 8;
    rp[4] = __int_as_float(n);
    rp[5] = __int_as_float(n);
}

// ---------------- self-loop e-terms from finalized means ----------------
__global__ void k_selffill(const int* __restrict__ selfpos,
                           const float* __restrict__ consts,
                           float* __restrict__ rec) {
    int n = blockIdx.x * blockDim.x + threadIdx.x;
    if (n >= NN) return;
    float* rp = rec + (size_t)selfpos[n] * 8;
    *(float4*)rp = make_float4(consts[80], consts[81], consts[82], consts[83]);
    rp[6] = consts[96];
}

// ---------------- layer 1: a_src/a_dst dots only (xh1 never materialized) --------
__global__ void __launch_bounds__(64) k_xh1(const float* __restrict__ x,
                                            const float* __restrict__ W1,
                                            const float* __restrict__ as1,
                                            const float* __restrict__ ad1,
                                            float* __restrict__ aS1,
                                            float* __restrict__ aD1) {
    int n = blockIdx.x, t = threadIdx.x;
    int c0 = t * 8, h = t >> 4;
    const float* xp = x + (size_t)n * IND;
    float x0 = xp[0], x1 = xp[1], x2 = xp[2], x3 = xp[3], x4 = xp[4];
    float p = 0.f, q = 0.f;
#pragma unroll
    for (int j = 0; j < 8; ++j) {
        int c = c0 + j;
        float v = x0 * W1[0 * F1 + c] + x1 * W1[1 * F1 + c] + x2 * W1[2 * F1 + c]
                + x3 * W1[3 * F1 + c] + x4 * W1[4 * F1 + c];
        p += v * as1[c];
        q += v * ad1[c];
    }
#pragma unroll
    for (int o = 1; o <= 8; o <<= 1) {     // reduce within 16-lane head group
        p += __shfl_xor(p, o, 64);
        q += __shfl_xor(q, o, 64);
    }
    if ((t & 15) == 0) {
        aS1[n * 4 + h] = p;
        aD1[n * 4 + h] = q;
    }
}

// ---------------- layer 1 scores: in-place rec[0..3] += src/dst terms, leaky -----
__global__ void k_score1(float* __restrict__ rec,
                         const float* __restrict__ aS1, const float* __restrict__ aD1) {
    int i = blockIdx.x * blockDim.x + threadIdx.x;
    if (i >= EE2) return;
    float* rp = rec + (size_t)i * 8;
    float4 ev = *(const float4*)rp;
    float4 sd = *(const float4*)(rp + 4);
    int s = __float_as_int(sd.x), d = __float_as_int(sd.y);
    float4 vs = *(const float4*)(aS1 + (size_t)s * 4);
    float4 vd = *(const float4*)(aD1 + (size_t)d * 4);
    float t0 = vs.x + vd.x + ev.x, t1 = vs.y + vd.y + ev.y;
    float t2 = vs.z + vd.z + ev.z, t3 = vs.w + vd.w + ev.w;
    t0 = t0 > 0.f ? t0 : 0.2f * t0;
    t1 = t1 > 0.f ? t1 : 0.2f * t1;
    t2 = t2 > 0.f ? t2 : 0.2f * t2;
    t3 = t3 > 0.f ? t3 : 0.2f * t3;
    *(float4*)rp = make_float4(t0, t1, t2, t3);
}

// ---------------- layer 1 aggregate: edge-parallel softmax + 5-dim aggregation ----
__global__ void __launch_bounds__(64) k_agg1(const int* __restrict__ row_off,
                                             const float* __restrict__ rec,
                                             const float* __restrict__ x,
                                             const float* __restrict__ W1,
                                             const float* __restrict__ b1,
                                             u16* __restrict__ h1) {
    int n = blockIdx.x, t = threadIdx.x;
    int s0 = row_off[n], s1 = row_off[n + 1];
    // pass 1: per-head max (strided float4, all 64 lanes)
    float m0 = -1e30f, m1 = -1e30f, m2 = -1e30f, m3 = -1e30f;
    for (int i = s0 + t; i < s1; i += 64) {
        float4 a = *(const float4*)(rec + (size_t)i * 8);
        m0 = fmaxf(m0, a.x); m1 = fmaxf(m1, a.y);
        m2 = fmaxf(m2, a.z); m3 = fmaxf(m3, a.w);
    }
    m0 = wmaxr(m0); m1 = wmaxr(m1); m2 = wmaxr(m2); m3 = wmaxr(m3);
    // pass 2 (fused exp-sum + x-aggregation), edge-parallel
    int h = t & 3;
    float mh = (h == 0) ? m0 : (h == 1) ? m1 : (h == 2) ? m2 : m3;
    float z = 0.f, xa0 = 0.f, xa1 = 0.f, xa2 = 0.f, xa3 = 0.f, xa4 = 0.f;
    for (int i = s0 + (t >> 2); i < s1; i += 16) {
        const float* rp = rec + (size_t)i * 8;
        float ex = __expf(rp[h] - mh);
        z += ex;
        int s = __float_as_int(rp[4]);
        const float* xp = x + (size_t)s * IND;
        xa0 += ex * xp[0]; xa1 += ex * xp[1]; xa2 += ex * xp[2];
        xa3 += ex * xp[3]; xa4 += ex * xp[4];
    }
#pragma unroll
    for (int o = 4; o <= 32; o <<= 1) {    // reduce 16 lanes sharing h
        z   += __shfl_xor(z, o, 64);
        xa0 += __shfl_xor(xa0, o, 64); xa1 += __shfl_xor(xa1, o, 64);
        xa2 += __shfl_xor(xa2, o, 64); xa3 += __shfl_xor(xa3, o, 64);
        xa4 += __shfl_xor(xa4, o, 64);
    }
    // redistribute: output head ho = t>>4; lane ho holds head ho's totals (ho&3==ho)
    int ho = t >> 4;
    float zz = __shfl(z, ho);
    float y0 = __shfl(xa0, ho), y1 = __shfl(xa1, ho), y2 = __shfl(xa2, ho);
    float y3 = __shfl(xa3, ho), y4 = __shfl(xa4, ho);
    float ih = 1.f / (zz + 1e-16f);
    int c0 = t * 8;
#pragma unroll
    for (int j = 0; j < 8; ++j) {
        int c = c0 + j;
        float v = (y0 * W1[0 * F1 + c] + y1 * W1[1 * F1 + c] + y2 * W1[2 * F1 + c]
                 + y3 * W1[3 * F1 + c] + y4 * W1[4 * F1 + c]) * ih;
        h1[(size_t)n * F1 + c] = f2bf(fmaxf(v + b1[c], 0.f));
    }
}

// ---------------- layer 2 GEMM (MFMA): xh2(bf16) = h1(bf16) @ W2, fused sd2 ------
__global__ void __launch_bounds__(256, 2) k_gemm2(const u16* __restrict__ h1,
                                                  const u16* __restrict__ bhi,
                                                  const u16* __restrict__ blo,
                                                  const float* __restrict__ as2,
                                                  const float* __restrict__ ad2,
                                                  u16* __restrict__ xh2,
                                                  float* __restrict__ aS2,
                                                  float* __restrict__ aD2) {
    int tid = threadIdx.x;
    int wv = tid >> 6, lane = tid & 63;
    int tile = blockIdx.x * 4 + wv;
    if (tile >= 2500) return;
    int n0 = tile * 16;
    int mrow = lane & 15, quad = lane >> 4;
    const u16* aptr = h1 + (size_t)(n0 + mrow) * F1 + quad * 8;
    const u16* bbase_hi = bhi + lane * 8;
    const u16* bbase_lo = blo + lane * 8;
    f32x4 acc[8];
#pragma unroll
    for (int nt = 0; nt < 8; ++nt) acc[nt] = (f32x4){0.f, 0.f, 0.f, 0.f};

    bf16x8 bh0[8], bl0[8], bh1[8], bl1[8];
    bf16x8 af0, af1;
    af0 = *(const bf16x8*)(aptr);
#pragma unroll
    for (int nt = 0; nt < 8; ++nt) {
        bh0[nt] = *(const bf16x8*)(bbase_hi + nt * 8192);
        bl0[nt] = *(const bf16x8*)(bbase_lo + nt * 8192);
    }
#pragma unroll
    for (int ks = 0; ks < 16; ++ks) {
        if (ks < 15) {
            af1 = *(const bf16x8*)(aptr + (ks + 1) * 32);
#pragma unroll
            for (int nt = 0; nt < 8; ++nt) {
                bh1[nt] = *(const bf16x8*)(bbase_hi + nt * 8192 + (ks + 1) * 512);
                bl1[nt] = *(const bf16x8*)(bbase_lo + nt * 8192 + (ks + 1) * 512);
            }
        }
#pragma unroll
        for (int nt = 0; nt < 8; ++nt) {
            acc[nt] = __builtin_amdgcn_mfma_f32_16x16x32_bf16(af0, bh0[nt], acc[nt], 0, 0, 0);
            acc[nt] = __builtin_amdgcn_mfma_f32_16x16x32_bf16(af0, bl0[nt], acc[nt], 0, 0, 0);
        }
        af0 = af1;
#pragma unroll
        for (int nt = 0; nt < 8; ++nt) { bh0[nt] = bh1[nt]; bl0[nt] = bl1[nt]; }
    }
    // C layout: col = nt*16 + mrow, row = quad*4 + r   (m89-verified)
    float ps[4] = {0.f, 0.f, 0.f, 0.f}, pd[4] = {0.f, 0.f, 0.f, 0.f};
#pragma unroll
    for (int nt = 0; nt < 8; ++nt) {
        int col = nt * 16 + mrow;
        float sa = as2[col], da = ad2[col];
#pragma unroll
        for (int r = 0; r < 4; ++r) {
            float v = acc[nt][r];
            xh2[(size_t)(n0 + quad * 4 + r) * HIDD + col] = f2bf(v);
            ps[r] += v * sa; pd[r] += v * da;
        }
    }
#pragma unroll
    for (int r = 0; r < 4; ++r) {
#pragma unroll
        for (int o = 1; o <= 8; o <<= 1) {
            ps[r] += __shfl_xor(ps[r], o, 64);
            pd[r] += __shfl_xor(pd[r], o, 64);
        }
        if (mrow == 0) {
            aS2[n0 + quad * 4 + r] = ps[r];
            aD2[n0 + quad * 4 + r] = pd[r];
        }
    }
}

// ---------------- layer 2: per-edge scores (sequential record reads) ------------
__global__ void k_score2(const float* __restrict__ rec,
                         const float* __restrict__ aS2, const float* __restrict__ aD2,
                         float* __restrict__ alpha2) {
    int i = blockIdx.x * blockDim.x + threadIdx.x;
    if (i >= EE2) return;
    float4 sd = *(const float4*)(rec + (size_t)i * 8 + 4);
    int s = __float_as_int(sd.x), d = __float_as_int(sd.y);
    float t0 = aS2[s] + aD2[d] + sd.z;
    alpha2[i] = t0 > 0.f ? t0 : 0.2f * t0;
}

// ---------------- layer 2: edge-parallel softmax + aggregate + FC + sigmoid ------
__global__ void __launch_bounds__(64) k_agg2(const int* __restrict__ row_off,
                                             const float* __restrict__ rec,
                                             const float* __restrict__ alpha2,
                                             const u16* __restrict__ xh2,
                                             const float* __restrict__ bias2,
                                             const float* __restrict__ Wfc,
                                             const float* __restrict__ bfc,
                                             float* __restrict__ out) {
    int n = blockIdx.x, t = threadIdx.x;
    int s0 = row_off[n], s1 = row_off[n + 1];
    float m = -1e30f;
    for (int i = s0 + t; i < s1; i += 64) m = fmaxf(m, alpha2[i]);
    m = wmaxr(m);
    float z = 0.f;
    for (int i = s0 + t; i < s1; i += 64) z += __expf(alpha2[i] - m);
    z = wsum(z);
    float inv = 1.f / (z + 1e-16f);
    int g = t >> 4, l = t & 15;
    int c0 = l * 8;
    float acc[8];
#pragma unroll
    for (int j = 0; j < 8; ++j) acc[j] = 0.f;
    for (int i = s0 + g; i < s1; i += 4) {
        float w = __expf(alpha2[i] - m) * inv;
        int s = __float_as_int(rec[(size_t)i * 8 + 4]);
        uint4 q = *(const uint4*)(xh2 + (size_t)s * HIDD + c0);   // 8 bf16
        acc[0] += w * bf2f((u16)(q.x & 0xFFFF)); acc[1] += w * bf2f((u16)(q.x >> 16));
        acc[2] += w * bf2f((u16)(q.y & 0xFFFF)); acc[3] += w * bf2f((u16)(q.y >> 16));
        acc[4] += w * bf2f((u16)(q.z & 0xFFFF)); acc[5] += w * bf2f((u16)(q.z >> 16));
        acc[6] += w * bf2f((u16)(q.w & 0xFFFF)); acc[7] += w * bf2f((u16)(q.w >> 16));
    }
    // reduce across the 4 edge subgroups (lanes differing in bits 4,5)
#pragma unroll
    for (int o = 16; o <= 32; o <<= 1) {
#pragma unroll
        for (int j = 0; j < 8; ++j) acc[j] += __shfl_xor(acc[j], o, 64);
    }
    // bias + relu + FC partial over this lane's 8 cols
    float p = 0.f;
#pragma unroll
    for (int j = 0; j < 8; ++j) {
        float o = fmaxf(acc[j] + bias2[c0 + j], 0.f);
        p += o * Wfc[c0 + j];
    }
#pragma unroll
    for (int o = 1; o <= 8; o <<= 1) p += __shfl_xor(p, o, 64);
    if (t == 0) {
        float logit = p + bfc[0];
        out[n] = 1.f / (1.f + __expf(-logit));
    }
}

extern "C" void kernel_launch(void* const* d_in, const int* in_sizes, int n_in,
                              void* d_out, int out_size, void* d_ws, size_t ws_size,
                              hipStream_t stream) {
    (void)in_sizes; (void)n_in; (void)out_size; (void)ws_size;
    const float* x   = (const float*)d_in[0];
    const int*   ei  = (const int*)d_in[1];
    const float* ea  = (const float*)d_in[2];
    const float* W1  = (const float*)d_in[3];
    const float* We1 = (const float*)d_in[4];
    const float* as1 = (const float*)d_in[5];
    const float* ad1 = (const float*)d_in[6];
    const float* ae1 = (const float*)d_in[7];
    const float* b1  = (const float*)d_in[8];
    const float* W2  = (const float*)d_in[9];
    const float* We2 = (const float*)d_in[10];
    const float* as2 = (const float*)d_in[11];
    const float* ad2 = (const float*)d_in[12];
    const float* ae2 = (const float*)d_in[13];
    const float* b2v = (const float*)d_in[14];
    const float* Wfc = (const float*)d_in[15];
    const float* bfc = (const float*)d_in[16];
    float* out = (float*)d_out;

    char* ws = (char*)d_ws;
    size_t off = 0;
    auto take = [&](size_t nb) {
        size_t r = off;
        off += (nb + 255) & ~(size_t)255;
        return r;
    };
    float* consts = (float*)(ws + take(1024));
    int* row_off  = (int*)(ws + take((size_t)(NN + 1) * 4));
    int* cursor   = (int*)(ws + take((size_t)NN * 4));
    int* local_ex = (int*)(ws + take((size_t)NN * 4));
    int* bsum     = (int*)(ws + take(1024));
    int* boff     = (int*)(ws + take(1024));
    int* selfpos  = (int*)(ws + take((size_t)NN * 4));
    float* rec    = (float*)(ws + take((size_t)EE2 * 32));
    float* alpha2 = (float*)(ws + take((size_t)EE2 * 4));
    float* aS1    = (float*)(ws + take((size_t)NN * 16));
    float* aD1    = (float*)(ws + take((size_t)NN * 16));
    float* aS2    = (float*)(ws + take((size_t)NN * 4));
    float* aD2    = (float*)(ws + take((size_t)NN * 4));
    u16* h1       = (u16*)(ws + take((size_t)NN * F1 * 2));
    u16* xh2      = (u16*)(ws + take((size_t)NN * HIDD * 2));
    u16* w2hi     = (u16*)(ws + take((size_t)65536 * 2));
    u16* w2lo     = (u16*)(ws + take((size_t)65536 * 2));

    k_init<<<(NN + 255) / 256, 256, 0, stream>>>(consts, cursor);
    k_constsA<<<1, 64, 0, stream>>>(consts, We1, ae1, We2, ae2);
    k_wswz<<<32, 256, 0, stream>>>(W2, w2hi, w2lo);
    k_count<<<(EE2 + 255) / 256, 256, 0, stream>>>(ei, cursor);
    k_scanA<<<SGRID, SBLK, 0, stream>>>(cursor, local_ex, bsum);
    k_scanB<<<1, SBLK, 0, stream>>>(bsum, boff);
    k_scanC<<<SGRID, SBLK, 0, stream>>>(local_ex, boff, row_off, cursor);

    k_build<<<EE / 1024, 256, 0, stream>>>(ea, ei, consts, cursor, rec);
    k_selfbuild<<<(NN + 255) / 256, 256, 0, stream>>>(cursor, rec, selfpos);
    k_constsB<<<1, 64, 0, stream>>>(consts);
    k_selffill<<<(NN + 255) / 256, 256, 0, stream>>>(selfpos, consts, rec);

    k_xh1<<<NN, 64, 0, stream>>>(x, W1, as1, ad1, aS1, aD1);
    k_score1<<<(EE2 + 255) / 256, 256, 0, stream>>>(rec, aS1, aD1);
    k_agg1<<<NN, 64, 0, stream>>>(row_off, rec, x, W1, b1, h1);

    k_gemm2<<<625, 256, 0, stream>>>(h1, w2hi, w2lo, as2, ad2, xh2, aS2, aD2);
    k_score2<<<(EE2 + 255) / 256, 256, 0, stream>>>(rec, aS2, aD2, alpha2);
    k_agg2<<<NN, 64, 0, stream>>>(row_off, rec, alpha2, xh2, b2v, Wfc, bfc, out);
}

// Round 11
// 307.059 us; speedup vs baseline: 2.5581x; 1.0223x over previous
//
#include <hip/hip_runtime.h>

#define NN   40000
#define EE   640000
#define EE2  680000    // EE + NN self loops
#define IND  5
#define ED   11
#define HIDD 128
#define F1   512       // 4 heads * 128

typedef unsigned short u16;
typedef unsigned int   u32;
typedef __attribute__((ext_vector_type(8))) short bf16x8;
typedef __attribute__((ext_vector_type(4))) float f32x4;

__device__ __forceinline__ float bf2f(u16 u) { return __uint_as_float(((u32)u) << 16); }
__device__ __forceinline__ u16 f2bf(float f) {
    u32 u = __float_as_uint(f);
    return (u16)((u + 0x7FFFu + ((u >> 16) & 1u)) >> 16);   // RNE
}

__device__ __forceinline__ float wsum(float v) {
#pragma unroll
    for (int o = 32; o; o >>= 1) v += __shfl_xor(v, o, 64);
    return v;
}
__device__ __forceinline__ float wmaxr(float v) {
#pragma unroll
    for (int o = 32; o; o >>= 1) v = fmaxf(v, __shfl_xor(v, o, 64));
    return v;
}
__device__ __forceinline__ float lrelu(float v) { return v > 0.f ? v : 0.2f * v; }

// edge record (32B, float[8]): [0..3]=e-terms (layer-1), [4]=src(int), [5]=et2,
//                              [6,7]=pad.  dst is implicit (records dst-sorted).

// ---------------- init: zero consts + per-dst counters ----------------
__global__ void k_init(float* __restrict__ consts, int* __restrict__ cursor) {
    int i = blockIdx.x * blockDim.x + threadIdx.x;
    if (i < 256) consts[i] = 0.f;
    if (i < NN) cursor[i] = 0;
}

// consts layout (floats): [0..10] ea col-sums -> means, [16..59] Be1[k*4+h],
//                         [64..74] Be2[k], [80..83] self1[h], [96] self2
__global__ void k_constsA(float* __restrict__ consts,
                          const float* __restrict__ We1, const float* __restrict__ ae1,
                          const float* __restrict__ We2, const float* __restrict__ ae2) {
    int t = threadIdx.x;  // 64 threads
    if (t < 44) {
        int k = t >> 2, h = t & 3;
        float s = 0.f;
        for (int c = 0; c < HIDD; ++c)
            s += We1[k * F1 + h * HIDD + c] * ae1[h * HIDD + c];
        consts[16 + t] = s;
    }
    if (t >= 48 && t < 48 + ED) {
        int k = t - 48;
        float s = 0.f;
        for (int c = 0; c < HIDD; ++c)
            s += We2[k * HIDD + c] * ae2[c];
        consts[64 + k] = s;
    }
}

__global__ void k_constsB(float* __restrict__ consts) {
    int t = threadIdx.x;  // 64 threads
    if (t < ED) consts[t] *= (1.0f / (float)EE);
    __syncthreads();
    if (t < 4) {
        float s = 0.f;
        for (int k = 0; k < ED; ++k) s += consts[k] * consts[16 + k * 4 + t];
        consts[80 + t] = s;
    }
    if (t == 8) {
        float s = 0.f;
        for (int k = 0; k < ED; ++k) s += consts[k] * consts[64 + k];
        consts[96] = s;
    }
}

// ---------------- W2 pre-swizzle into MFMA B-fragment order, split hi/lo bf16 ----
__global__ void k_wswz(const float* __restrict__ W2,
                       u16* __restrict__ bhi, u16* __restrict__ blo) {
    int t = blockIdx.x * blockDim.x + threadIdx.x;   // 8192 = 8nt * 16ks * 64lane
    if (t >= 8192) return;
    int lane = t & 63, ks = (t >> 6) & 15, nt = t >> 10;
    int kbase = ks * 32 + (lane >> 4) * 8;
    int n = nt * 16 + (lane & 15);
    size_t dst = (size_t)t * 8;
#pragma unroll
    for (int j = 0; j < 8; ++j) {
        float v = W2[(size_t)(kbase + j) * HIDD + n];
        u16 h = f2bf(v);
        float resid = v - bf2f(h);
        bhi[dst + j] = h;
        blo[dst + j] = f2bf(resid);
    }
}

// ---------------- CSR build (sorted by dst), shared by both layers ----------------
__global__ void k_count(const int* __restrict__ ei, int* __restrict__ counts) {
    int i = blockIdx.x * blockDim.x + threadIdx.x;
    if (i >= EE2) return;
    int dst = (i < EE) ? ei[EE + i] : (i - EE);
    atomicAdd(&counts[dst], 1);
}

// 3-phase hierarchical exclusive scan of counts[NN] -> row_off/cursor
#define SBLK 256
#define SGRID ((NN + SBLK - 1) / SBLK)   // 157
__global__ void __launch_bounds__(SBLK) k_scanA(const int* __restrict__ counts,
                                                int* __restrict__ local_ex,
                                                int* __restrict__ bsum) {
    __shared__ int sh[SBLK];
    int t = threadIdx.x;
    int i = blockIdx.x * SBLK + t;
    int v = (i < NN) ? counts[i] : 0;
    sh[t] = v;
    __syncthreads();
    for (int o = 1; o < SBLK; o <<= 1) {
        int u = (t >= o) ? sh[t - o] : 0;
        __syncthreads();
        sh[t] += u;
        __syncthreads();
    }
    if (i < NN) local_ex[i] = sh[t] - v;
    if (t == SBLK - 1) bsum[blockIdx.x] = sh[t];
}

__global__ void __launch_bounds__(SBLK) k_scanB(int* __restrict__ bsum,
                                                int* __restrict__ boff) {
    __shared__ int sh[SBLK];
    int t = threadIdx.x;
    int v = (t < SGRID) ? bsum[t] : 0;
    sh[t] = v;
    __syncthreads();
    for (int o = 1; o < SBLK; o <<= 1) {
        int u = (t >= o) ? sh[t - o] : 0;
        __syncthreads();
        sh[t] += u;
        __syncthreads();
    }
    if (t < SGRID) boff[t] = sh[t] - v;
}

__global__ void __launch_bounds__(SBLK) k_scanC(const int* __restrict__ local_ex,
                                                const int* __restrict__ boff,
                                                int* __restrict__ row_off,
                                                int* __restrict__ cur) {
    int t = threadIdx.x;
    int i = blockIdx.x * SBLK + t;
    if (i < NN) {
        int v = local_ex[i] + boff[blockIdx.x];
        row_off[i] = v;
        cur[i] = v;
    }
    if (i == 0) row_off[NN] = EE2;
}

// ---------------- fused scatter + ea pass, no LDS staging --------------------------
// Thread handles 4 edges = 176B contiguous ea (16B aligned); records scattered as
// two float4 stores. (Round-10 LDS version: 44KB LDS capped occupancy at 16%,
// 345K bank conflicts from the stride-44 reads; scatter latency unhidden -> 44us.)
__global__ void __launch_bounds__(256) k_build(const float* __restrict__ ea,
                                               const int* __restrict__ ei,
                                               float* consts,
                                               int* __restrict__ cursor,
                                               float* __restrict__ rec) {
    int t = blockIdx.x * 256 + threadIdx.x;   // 160000 threads, 4 edges each
    int e0i = t * 4;
    float Bx[ED], By[ED], Bz[ED], Bw[ED], Bt[ED];
#pragma unroll
    for (int k = 0; k < ED; ++k) {
        Bx[k] = consts[16 + k * 4 + 0];
        By[k] = consts[16 + k * 4 + 1];
        Bz[k] = consts[16 + k * 4 + 2];
        Bw[k] = consts[16 + k * 4 + 3];
        Bt[k] = consts[64 + k];
    }
    int4 sv = *(const int4*)(ei + e0i);
    int4 dv = *(const int4*)(ei + EE + e0i);
    float r[44];
    const float* base = ea + (size_t)e0i * ED;
#pragma unroll
    for (int j = 0; j < 11; ++j)
        *(float4*)(r + j * 4) = *(const float4*)(base + j * 4);
    float cs[ED];
#pragma unroll
    for (int k = 0; k < ED; ++k) cs[k] = 0.f;
#pragma unroll
    for (int rr = 0; rr < 4; ++rr) {
        const float* row = r + rr * 11;
        float e0 = 0.f, e1 = 0.f, e2 = 0.f, e3 = 0.f, et = 0.f;
#pragma unroll
        for (int k = 0; k < ED; ++k) {
            float a = row[k];
            cs[k] += a;
            e0 += a * Bx[k]; e1 += a * By[k]; e2 += a * Bz[k]; e3 += a * Bw[k];
            et += a * Bt[k];
        }
        int s = (rr == 0) ? sv.x : (rr == 1) ? sv.y : (rr == 2) ? sv.z : sv.w;
        int d = (rr == 0) ? dv.x : (rr == 1) ? dv.y : (rr == 2) ? dv.z : dv.w;
        int pos = atomicAdd(&cursor[d], 1);
        float* rp = rec + (size_t)pos * 8;
        *(float4*)rp = make_float4(e0, e1, e2, e3);
        *(float4*)(rp + 4) = make_float4(__int_as_float(s), et, 0.f, 0.f);
    }
    // column-sum reduce: wave, then block (tiny LDS), then one atomic set
    __shared__ float ls[4 * ED];
#pragma unroll
    for (int k = 0; k < ED; ++k) cs[k] = wsum(cs[k]);
    int wv = threadIdx.x >> 6;
    if ((threadIdx.x & 63) == 0) {
#pragma unroll
        for (int k = 0; k < ED; ++k) ls[wv * ED + k] = cs[k];
    }
    __syncthreads();
    int tt = threadIdx.x;
    if (tt < ED)
        atomicAdd(&consts[tt], ls[tt] + ls[ED + tt] + ls[2 * ED + tt] + ls[3 * ED + tt]);
}

// ---------------- self-loop records: src + remember position ----------------
__global__ void k_selfbuild(int* __restrict__ cursor, float* __restrict__ rec,
                            int* __restrict__ selfpos) {
    int n = blockIdx.x * blockDim.x + threadIdx.x;
    if (n >= NN) return;
    int pos = atomicAdd(&cursor[n], 1);
    selfpos[n] = pos;
    rec[(size_t)pos * 8 + 4] = __int_as_float(n);
}

// ---------------- self-loop e-terms from finalized means ----------------
__global__ void k_selffill(const int* __restrict__ selfpos,
                           const float* __restrict__ consts,
                           float* __restrict__ rec) {
    int n = blockIdx.x * blockDim.x + threadIdx.x;
    if (n >= NN) return;
    float* rp = rec + (size_t)selfpos[n] * 8;
    *(float4*)rp = make_float4(consts[80], consts[81], consts[82], consts[83]);
    rp[5] = consts[96];
}

// ---------------- layer 1: a_src/a_dst dots only ----------------
__global__ void __launch_bounds__(64) k_xh1(const float* __restrict__ x,
                                            const float* __restrict__ W1,
                                            const float* __restrict__ as1,
                                            const float* __restrict__ ad1,
                                            float* __restrict__ aS1,
                                            float* __restrict__ aD1) {
    int n = blockIdx.x, t = threadIdx.x;
    int c0 = t * 8, h = t >> 4;
    const float* xp = x + (size_t)n * IND;
    float x0 = xp[0], x1 = xp[1], x2 = xp[2], x3 = xp[3], x4 = xp[4];
    float p = 0.f, q = 0.f;
#pragma unroll
    for (int j = 0; j < 8; ++j) {
        int c = c0 + j;
        float v = x0 * W1[0 * F1 + c] + x1 * W1[1 * F1 + c] + x2 * W1[2 * F1 + c]
                + x3 * W1[3 * F1 + c] + x4 * W1[4 * F1 + c];
        p += v * as1[c];
        q += v * ad1[c];
    }
#pragma unroll
    for (int o = 1; o <= 8; o <<= 1) {     // reduce within 16-lane head group
        p += __shfl_xor(p, o, 64);
        q += __shfl_xor(q, o, 64);
    }
    if ((t & 15) == 0) {
        aS1[n * 4 + h] = p;
        aD1[n * 4 + h] = q;
    }
}

// ---------------- layer 1: fused score + softmax + 5-dim aggregation -------------
// alpha computed on the fly: leaky(e + aS1[src] + aD1[n]); aD1[n] wave-uniform,
// aS1 gather is L2-resident (640KB). k_score1 kernel eliminated.
__global__ void __launch_bounds__(64) k_agg1(const int* __restrict__ row_off,
                                             const float* __restrict__ rec,
                                             const float* __restrict__ aS1,
                                             const float* __restrict__ aD1,
                                             const float* __restrict__ x,
                                             const float* __restrict__ W1,
                                             const float* __restrict__ b1,
                                             u16* __restrict__ h1) {
    int n = blockIdx.x, t = threadIdx.x;
    int s0 = row_off[n], s1 = row_off[n + 1];
    float4 adv = *(const float4*)(aD1 + (size_t)n * 4);   // uniform
    // pass 1: per-head max
    float m0 = -1e30f, m1 = -1e30f, m2 = -1e30f, m3 = -1e30f;
    for (int i = s0 + t; i < s1; i += 64) {
        const float* rp = rec + (size_t)i * 8;
        float4 ev = *(const float4*)rp;
        int s = __float_as_int(rp[4]);
        float4 sv = *(const float4*)(aS1 + (size_t)s * 4);
        m0 = fmaxf(m0, lrelu(ev.x + sv.x + adv.x));
        m1 = fmaxf(m1, lrelu(ev.y + sv.y + adv.y));
        m2 = fmaxf(m2, lrelu(ev.z + sv.z + adv.z));
        m3 = fmaxf(m3, lrelu(ev.w + sv.w + adv.w));
    }
    m0 = wmaxr(m0); m1 = wmaxr(m1); m2 = wmaxr(m2); m3 = wmaxr(m3);
    // pass 2: edge-parallel exp-sum + x-aggregation (head h = t&3)
    int h = t & 3;
    float mh = (h == 0) ? m0 : (h == 1) ? m1 : (h == 2) ? m2 : m3;
    float adh = (h == 0) ? adv.x : (h == 1) ? adv.y : (h == 2) ? adv.z : adv.w;
    float z = 0.f, xa0 = 0.f, xa1 = 0.f, xa2 = 0.f, xa3 = 0.f, xa4 = 0.f;
    for (int i = s0 + (t >> 2); i < s1; i += 16) {
        const float* rp = rec + (size_t)i * 8;
        float eh = rp[h];
        int s = __float_as_int(rp[4]);
        float a = lrelu(eh + aS1[(size_t)s * 4 + h] + adh);
        float ex = __expf(a - mh);
        z += ex;
        const float* xp = x + (size_t)s * IND;
        xa0 += ex * xp[0]; xa1 += ex * xp[1]; xa2 += ex * xp[2];
        xa3 += ex * xp[3]; xa4 += ex * xp[4];
    }
#pragma unroll
    for (int o = 4; o <= 32; o <<= 1) {    // reduce 16 lanes sharing h
        z   += __shfl_xor(z, o, 64);
        xa0 += __shfl_xor(xa0, o, 64); xa1 += __shfl_xor(xa1, o, 64);
        xa2 += __shfl_xor(xa2, o, 64); xa3 += __shfl_xor(xa3, o, 64);
        xa4 += __shfl_xor(xa4, o, 64);
    }
    // redistribute: output head ho = t>>4; lane ho holds head ho's totals (ho&3==ho)
    int ho = t >> 4;
    float zz = __shfl(z, ho);
    float y0 = __shfl(xa0, ho), y1 = __shfl(xa1, ho), y2 = __shfl(xa2, ho);
    float y3 = __shfl(xa3, ho), y4 = __shfl(xa4, ho);
    float ih = 1.f / (zz + 1e-16f);
    int c0 = t * 8;
#pragma unroll
    for (int j = 0; j < 8; ++j) {
        int c = c0 + j;
        float v = (y0 * W1[0 * F1 + c] + y1 * W1[1 * F1 + c] + y2 * W1[2 * F1 + c]
                 + y3 * W1[3 * F1 + c] + y4 * W1[4 * F1 + c]) * ih;
        h1[(size_t)n * F1 + c] = f2bf(fmaxf(v + b1[c], 0.f));
    }
}

// ---------------- layer 2 GEMM (MFMA): xh2(bf16) = h1(bf16) @ W2, fused sd2 ------
__global__ void __launch_bounds__(256, 2) k_gemm2(const u16* __restrict__ h1,
                                                  const u16* __restrict__ bhi,
                                                  const u16* __restrict__ blo,
                                                  const float* __restrict__ as2,
                                                  const float* __restrict__ ad2,
                                                  u16* __restrict__ xh2,
                                                  float* __restrict__ aS2,
                                                  float* __restrict__ aD2) {
    int tid = threadIdx.x;
    int wv = tid >> 6, lane = tid & 63;
    int tile = blockIdx.x * 4 + wv;
    if (tile >= 2500) return;
    int n0 = tile * 16;
    int mrow = lane & 15, quad = lane >> 4;
    const u16* aptr = h1 + (size_t)(n0 + mrow) * F1 + quad * 8;
    const u16* bbase_hi = bhi + lane * 8;
    const u16* bbase_lo = blo + lane * 8;
    f32x4 acc[8];
#pragma unroll
    for (int nt = 0; nt < 8; ++nt) acc[nt] = (f32x4){0.f, 0.f, 0.f, 0.f};

    bf16x8 bh0[8], bl0[8], bh1[8], bl1[8];
    bf16x8 af0, af1;
    af0 = *(const bf16x8*)(aptr);
#pragma unroll
    for (int nt = 0; nt < 8; ++nt) {
        bh0[nt] = *(const bf16x8*)(bbase_hi + nt * 8192);
        bl0[nt] = *(const bf16x8*)(bbase_lo + nt * 8192);
    }
#pragma unroll
    for (int ks = 0; ks < 16; ++ks) {
        if (ks < 15) {
            af1 = *(const bf16x8*)(aptr + (ks + 1) * 32);
#pragma unroll
            for (int nt = 0; nt < 8; ++nt) {
                bh1[nt] = *(const bf16x8*)(bbase_hi + nt * 8192 + (ks + 1) * 512);
                bl1[nt] = *(const bf16x8*)(bbase_lo + nt * 8192 + (ks + 1) * 512);
            }
        }
#pragma unroll
        for (int nt = 0; nt < 8; ++nt) {
            acc[nt] = __builtin_amdgcn_mfma_f32_16x16x32_bf16(af0, bh0[nt], acc[nt], 0, 0, 0);
            acc[nt] = __builtin_amdgcn_mfma_f32_16x16x32_bf16(af0, bl0[nt], acc[nt], 0, 0, 0);
        }
        af0 = af1;
#pragma unroll
        for (int nt = 0; nt < 8; ++nt) { bh0[nt] = bh1[nt]; bl0[nt] = bl1[nt]; }
    }
    // C layout: col = nt*16 + mrow, row = quad*4 + r   (m89-verified)
    float ps[4] = {0.f, 0.f, 0.f, 0.f}, pd[4] = {0.f, 0.f, 0.f, 0.f};
#pragma unroll
    for (int nt = 0; nt < 8; ++nt) {
        int col = nt * 16 + mrow;
        float sa = as2[col], da = ad2[col];
#pragma unroll
        for (int r = 0; r < 4; ++r) {
            float v = acc[nt][r];
            xh2[(size_t)(n0 + quad * 4 + r) * HIDD + col] = f2bf(v);
            ps[r] += v * sa; pd[r] += v * da;
        }
    }
#pragma unroll
    for (int r = 0; r < 4; ++r) {
#pragma unroll
        for (int o = 1; o <= 8; o <<= 1) {
            ps[r] += __shfl_xor(ps[r], o, 64);
            pd[r] += __shfl_xor(pd[r], o, 64);
        }
        if (mrow == 0) {
            aS2[n0 + quad * 4 + r] = ps[r];
            aD2[n0 + quad * 4 + r] = pd[r];
        }
    }
}

// ---------------- layer 2: fused score + softmax + aggregate + FC + sigmoid ------
// alpha2 = leaky(aS2[src] + aD2[n] + et2) computed on the fly (3 passes);
// k_score2 kernel + alpha2 buffer eliminated.
__global__ void __launch_bounds__(64) k_agg2(const int* __restrict__ row_off,
                                             const float* __restrict__ rec,
                                             const float* __restrict__ aS2,
                                             const float* __restrict__ aD2,
                                             const u16* __restrict__ xh2,
                                             const float* __restrict__ bias2,
                                             const float* __restrict__ Wfc,
                                             const float* __restrict__ bfc,
                                             float* __restrict__ out) {
    int n = blockIdx.x, t = threadIdx.x;
    int s0 = row_off[n], s1 = row_off[n + 1];
    float adn = aD2[n];                      // uniform
    float m = -1e30f;
    for (int i = s0 + t; i < s1; i += 64) {
        float2 se = *(const float2*)(rec + (size_t)i * 8 + 4);
        int s = __float_as_int(se.x);
        m = fmaxf(m, lrelu(aS2[s] + adn + se.y));
    }
    m = wmaxr(m);
    float z = 0.f;
    for (int i = s0 + t; i < s1; i += 64) {
        float2 se = *(const float2*)(rec + (size_t)i * 8 + 4);
        int s = __float_as_int(se.x);
        z += __expf(lrelu(aS2[s] + adn + se.y) - m);
    }
    z = wsum(z);
    float inv = 1.f / (z + 1e-16f);
    int g = t >> 4, l = t & 15;
    int c0 = l * 8;
    float acc[8];
#pragma unroll
    for (int j = 0; j < 8; ++j) acc[j] = 0.f;
    for (int i = s0 + g; i < s1; i += 4) {
        float2 se = *(const float2*)(rec + (size_t)i * 8 + 4);
        int s = __float_as_int(se.x);
        float w = __expf(lrelu(aS2[s] + adn + se.y) - m) * inv;
        uint4 q = *(const uint4*)(xh2 + (size_t)s * HIDD + c0);   // 8 bf16
        acc[0] += w * bf2f((u16)(q.x & 0xFFFF)); acc[1] += w * bf2f((u16)(q.x >> 16));
        acc[2] += w * bf2f((u16)(q.y & 0xFFFF)); acc[3] += w * bf2f((u16)(q.y >> 16));
        acc[4] += w * bf2f((u16)(q.z & 0xFFFF)); acc[5] += w * bf2f((u16)(q.z >> 16));
        acc[6] += w * bf2f((u16)(q.w & 0xFFFF)); acc[7] += w * bf2f((u16)(q.w >> 16));
    }
    // reduce across the 4 edge subgroups (lanes differing in bits 4,5)
#pragma unroll
    for (int o = 16; o <= 32; o <<= 1) {
#pragma unroll
        for (int j = 0; j < 8; ++j) acc[j] += __shfl_xor(acc[j], o, 64);
    }
    // bias + relu + FC partial over this lane's 8 cols
    float p = 0.f;
#pragma unroll
    for (int j = 0; j < 8; ++j) {
        float o = fmaxf(acc[j] + bias2[c0 + j], 0.f);
        p += o * Wfc[c0 + j];
    }
#pragma unroll
    for (int o = 1; o <= 8; o <<= 1) p += __shfl_xor(p, o, 64);
    if (t == 0) {
        float logit = p + bfc[0];
        out[n] = 1.f / (1.f + __expf(-logit));
    }
}

extern "C" void kernel_launch(void* const* d_in, const int* in_sizes, int n_in,
                              void* d_out, int out_size, void* d_ws, size_t ws_size,
                              hipStream_t stream) {
    (void)in_sizes; (void)n_in; (void)out_size; (void)ws_size;
    const float* x   = (const float*)d_in[0];
    const int*   ei  = (const int*)d_in[1];
    const float* ea  = (const float*)d_in[2];
    const float* W1  = (const float*)d_in[3];
    const float* We1 = (const float*)d_in[4];
    const float* as1 = (const float*)d_in[5];
    const float* ad1 = (const float*)d_in[6];
    const float* ae1 = (const float*)d_in[7];
    const float* b1  = (const float*)d_in[8];
    const float* W2  = (const float*)d_in[9];
    const float* We2 = (const float*)d_in[10];
    const float* as2 = (const float*)d_in[11];
    const float* ad2 = (const float*)d_in[12];
    const float* ae2 = (const float*)d_in[13];
    const float* b2v = (const float*)d_in[14];
    const float* Wfc = (const float*)d_in[15];
    const float* bfc = (const float*)d_in[16];
    float* out = (float*)d_out;

    char* ws = (char*)d_ws;
    size_t off = 0;
    auto take = [&](size_t nb) {
        size_t r = off;
        off += (nb + 255) & ~(size_t)255;
        return r;
    };
    float* consts = (float*)(ws + take(1024));
    int* row_off  = (int*)(ws + take((size_t)(NN + 1) * 4));
    int* cursor   = (int*)(ws + take((size_t)NN * 4));
    int* local_ex = (int*)(ws + take((size_t)NN * 4));
    int* bsum     = (int*)(ws + take(1024));
    int* boff     = (int*)(ws + take(1024));
    int* selfpos  = (int*)(ws + take((size_t)NN * 4));
    float* rec    = (float*)(ws + take((size_t)EE2 * 32));
    float* aS1    = (float*)(ws + take((size_t)NN * 16));
    float* aD1    = (float*)(ws + take((size_t)NN * 16));
    float* aS2    = (float*)(ws + take((size_t)NN * 4));
    float* aD2    = (float*)(ws + take((size_t)NN * 4));
    u16* h1       = (u16*)(ws + take((size_t)NN * F1 * 2));
    u16* xh2      = (u16*)(ws + take((size_t)NN * HIDD * 2));
    u16* w2hi     = (u16*)(ws + take((size_t)65536 * 2));
    u16* w2lo     = (u16*)(ws + take((size_t)65536 * 2));

    k_init<<<(NN + 255) / 256, 256, 0, stream>>>(consts, cursor);
    k_constsA<<<1, 64, 0, stream>>>(consts, We1, ae1, We2, ae2);
    k_wswz<<<32, 256, 0, stream>>>(W2, w2hi, w2lo);
    k_count<<<(EE2 + 255) / 256, 256, 0, stream>>>(ei, cursor);
    k_scanA<<<SGRID, SBLK, 0, stream>>>(cursor, local_ex, bsum);
    k_scanB<<<1, SBLK, 0, stream>>>(bsum, boff);
    k_scanC<<<SGRID, SBLK, 0, stream>>>(local_ex, boff, row_off, cursor);

    k_build<<<EE / 1024, 256, 0, stream>>>(ea, ei, consts, cursor, rec);
    k_selfbuild<<<(NN + 255) / 256, 256, 0, stream>>>(cursor, rec, selfpos);
    k_constsB<<<1, 64, 0, stream>>>(consts);
    k_selffill<<<(NN + 255) / 256, 256, 0, stream>>>(selfpos, consts, rec);

    k_xh1<<<NN, 64, 0, stream>>>(x, W1, as1, ad1, aS1, aD1);
    k_agg1<<<NN, 64, 0, stream>>>(row_off, rec, aS1, aD1, x, W1, b1, h1);

    k_gemm2<<<625, 256, 0, stream>>>(h1, w2hi, w2lo, as2, ad2, xh2, aS2, aD2);
    k_agg2<<<NN, 64, 0, stream>>>(row_off, rec, aS2, aD2, xh2, b2v, Wfc, bfc, out);
}